// Round 1
// baseline (2893.692 us; speedup 1.0000x reference)
//
#include <hip/hip_runtime.h>

#define D_MODEL 1024
#define NHEAD   16
#define DK      64
#define SS      2048
#define BB      4

// ---------------------------------------------------------------------------
// GEMM: C[m,n] = sum_k A[m,k] * W[n,k] + bias[n]
// A: [M,K] row-major, W: [N,K] row-major (nn.Linear weight), both K-contiguous.
// ATTN_LAYOUT==1: write C to [B, H, S, DK] layout (for attention); else [M,N].
// 128x128 tile, BK=8, 256 threads, 8x8 micro-tile per thread.
// ---------------------------------------------------------------------------
template <int ATTN_LAYOUT>
__global__ __launch_bounds__(256) void gemm_xwT(const float* __restrict__ A,
                                                const float* __restrict__ W,
                                                const float* __restrict__ bias,
                                                float* __restrict__ C,
                                                int M, int N, int K) {
    __shared__ float As[8][132];   // [k][m], padded: load-write 2-way max, read float4-aligned
    __shared__ float Bs[8][132];   // [k][n]

    const int tid = threadIdx.x;
    const int tx  = tid & 15;      // col group (n)
    const int ty  = tid >> 4;      // row group (m)
    const int m0  = blockIdx.y * 128;
    const int n0  = blockIdx.x * 128;

    const int lr = tid >> 1;           // 0..127 row within tile
    const int lk = (tid & 1) * 4;      // 0 or 4

    float acc[8][8];
#pragma unroll
    for (int i = 0; i < 8; ++i)
#pragma unroll
        for (int j = 0; j < 8; ++j) acc[i][j] = 0.f;

    for (int kt = 0; kt < K; kt += 8) {
        // global loads issued before the barrier (overlap with prev compute)
        float4 av = *(const float4*)&A[(size_t)(m0 + lr) * K + kt + lk];
        float4 wv = *(const float4*)&W[(size_t)(n0 + lr) * K + kt + lk];
        __syncthreads();   // protect previous iteration's LDS reads
        As[lk + 0][lr] = av.x; As[lk + 1][lr] = av.y;
        As[lk + 2][lr] = av.z; As[lk + 3][lr] = av.w;
        Bs[lk + 0][lr] = wv.x; Bs[lk + 1][lr] = wv.y;
        Bs[lk + 2][lr] = wv.z; Bs[lk + 3][lr] = wv.w;
        __syncthreads();
#pragma unroll
        for (int k = 0; k < 8; ++k) {
            float4 a0 = *(const float4*)&As[k][ty * 8];
            float4 a1 = *(const float4*)&As[k][ty * 8 + 4];
            float4 b0 = *(const float4*)&Bs[k][tx * 8];
            float4 b1 = *(const float4*)&Bs[k][tx * 8 + 4];
            float a[8] = {a0.x, a0.y, a0.z, a0.w, a1.x, a1.y, a1.z, a1.w};
            float b[8] = {b0.x, b0.y, b0.z, b0.w, b1.x, b1.y, b1.z, b1.w};
#pragma unroll
            for (int i = 0; i < 8; ++i)
#pragma unroll
                for (int j = 0; j < 8; ++j) acc[i][j] += a[i] * b[j];
        }
    }

    // epilogue
    float bb[8];
#pragma unroll
    for (int j = 0; j < 8; ++j) bb[j] = bias[n0 + tx * 8 + j];

#pragma unroll
    for (int i = 0; i < 8; ++i) {
        int m = m0 + ty * 8 + i;
        int n = n0 + tx * 8;
        float4 c0 = {acc[i][0] + bb[0], acc[i][1] + bb[1], acc[i][2] + bb[2], acc[i][3] + bb[3]};
        float4 c1 = {acc[i][4] + bb[4], acc[i][5] + bb[5], acc[i][6] + bb[6], acc[i][7] + bb[7]};
        if (ATTN_LAYOUT) {
            int bq = m >> 11;          // /SS
            int s  = m & (SS - 1);
            int h  = n >> 6;
            int d  = n & 63;
            float* dst = &C[(((size_t)(bq * NHEAD + h) * SS + s) << 6) + d];
            *(float4*)&dst[0] = c0;
            *(float4*)&dst[4] = c1;
        } else {
            float* dst = &C[(size_t)m * N + n];
            *(float4*)&dst[0] = c0;
            *(float4*)&dst[4] = c1;
        }
    }
}

// ---------------------------------------------------------------------------
// Flash-style attention, fp32. One thread owns one q-row (q + O in VGPRs).
// K/V staged in LDS 32x64 tiles; online softmax over 16-key sub-tiles.
// Qp/Kp/Vp in [B,H,S,DK]; ctx out in [B,S,D_MODEL].
// ---------------------------------------------------------------------------
__global__ __launch_bounds__(256) void attn_kernel(const float* __restrict__ Qp,
                                                   const float* __restrict__ Kp,
                                                   const float* __restrict__ Vp,
                                                   const int* __restrict__ mask,
                                                   float* __restrict__ ctx) {
    __shared__ float ks[32][64];
    __shared__ float vs[32][64];

    const int tid = threadIdx.x;
    const int qt  = blockIdx.x & 7;    // S / 256
    const int bh  = blockIdx.x >> 3;   // b*H + h
    const int b   = bh >> 4;
    const int h   = bh & 15;
    const int s   = qt * 256 + tid;

    // q-row into registers, pre-scaled by 1/sqrt(dk)
    const float* qrow = &Qp[((size_t)bh * SS + s) * DK];
    float q[DK];
#pragma unroll
    for (int i = 0; i < 16; ++i) {
        float4 v = *(const float4*)&qrow[i * 4];
        q[i * 4 + 0] = v.x * 0.125f;
        q[i * 4 + 1] = v.y * 0.125f;
        q[i * 4 + 2] = v.z * 0.125f;
        q[i * 4 + 3] = v.w * 0.125f;
    }
    float o[DK];
#pragma unroll
    for (int d = 0; d < DK; ++d) o[d] = 0.f;
    float m_run = -3.0e38f, l_run = 0.f;

    const float* kbase = &Kp[(size_t)bh * SS * DK];
    const float* vbase = &Vp[(size_t)bh * SS * DK];
    const int*   mrow  = &mask[b * SS];

    const int idx0 = tid * 4;
    const int idx1 = tid * 4 + 1024;
    float* ksf = &ks[0][0];
    float* vsf = &vs[0][0];

    for (int t = 0; t < SS / 32; ++t) {
        float4 ka0 = *(const float4*)&kbase[t * 2048 + idx0];
        float4 ka1 = *(const float4*)&kbase[t * 2048 + idx1];
        float4 va0 = *(const float4*)&vbase[t * 2048 + idx0];
        float4 va1 = *(const float4*)&vbase[t * 2048 + idx1];
        __syncthreads();   // previous tile fully consumed
        *(float4*)&ksf[idx0] = ka0;
        *(float4*)&ksf[idx1] = ka1;
        *(float4*)&vsf[idx0] = va0;
        *(float4*)&vsf[idx1] = va1;
        __syncthreads();

#pragma unroll
        for (int half = 0; half < 2; ++half) {
            const int j0 = half * 16;
            float sc[16];
            float tmax = -3.0e38f;
#pragma unroll
            for (int j = 0; j < 16; ++j) {
                float accd = 0.f;
#pragma unroll
                for (int d4 = 0; d4 < 16; ++d4) {
                    float4 kv = *(const float4*)&ks[j0 + j][d4 * 4];
                    accd += q[d4 * 4 + 0] * kv.x + q[d4 * 4 + 1] * kv.y +
                            q[d4 * 4 + 2] * kv.z + q[d4 * 4 + 3] * kv.w;
                }
                int mv = mrow[t * 32 + j0 + j];
                sc[j]  = mv ? accd : -1.0e9f;
                tmax   = fmaxf(tmax, sc[j]);
            }
            float m_new  = fmaxf(m_run, tmax);
            float alpha  = __expf(m_run - m_new);
            l_run *= alpha;
#pragma unroll
            for (int d = 0; d < DK; ++d) o[d] *= alpha;
#pragma unroll
            for (int j = 0; j < 16; ++j) {
                float p = __expf(sc[j] - m_new);
                l_run += p;
#pragma unroll
                for (int d4 = 0; d4 < 16; ++d4) {
                    float4 vv = *(const float4*)&vs[j0 + j][d4 * 4];
                    o[d4 * 4 + 0] += p * vv.x;
                    o[d4 * 4 + 1] += p * vv.y;
                    o[d4 * 4 + 2] += p * vv.z;
                    o[d4 * 4 + 3] += p * vv.w;
                }
            }
            m_run = m_new;
        }
    }

    float inv_l = 1.0f / l_run;
    float* dst  = &ctx[((size_t)(b * SS + s)) * D_MODEL + h * DK];
#pragma unroll
    for (int d4 = 0; d4 < 16; ++d4) {
        float4 ov = {o[d4 * 4 + 0] * inv_l, o[d4 * 4 + 1] * inv_l,
                     o[d4 * 4 + 2] * inv_l, o[d4 * 4 + 3] * inv_l};
        *(float4*)&dst[d4 * 4] = ov;
    }
}

// ---------------------------------------------------------------------------
extern "C" void kernel_launch(void* const* d_in, const int* in_sizes, int n_in,
                              void* d_out, int out_size, void* d_ws, size_t ws_size,
                              hipStream_t stream) {
    const float* q    = (const float*)d_in[0];
    const float* k    = (const float*)d_in[1];
    const float* v    = (const float*)d_in[2];
    const int*   mask = (const int*)d_in[3];
    const float* w_q  = (const float*)d_in[4];
    const float* b_q  = (const float*)d_in[5];
    const float* w_k  = (const float*)d_in[6];
    const float* b_k  = (const float*)d_in[7];
    const float* w_v  = (const float*)d_in[8];
    const float* b_v  = (const float*)d_in[9];
    const float* w_o  = (const float*)d_in[10];
    const float* b_o  = (const float*)d_in[11];
    float* out = (float*)d_out;

    const size_t PSZ = (size_t)BB * NHEAD * SS * DK;   // 8,388,608 floats
    float* qp  = (float*)d_ws;
    float* kp  = qp + PSZ;
    float* vp  = kp + PSZ;
    float* ctx = vp + PSZ;

    const int M = BB * SS;   // 8192
    dim3 grid(D_MODEL / 128, M / 128);   // 8 x 64
    dim3 block(256);

    gemm_xwT<1><<<grid, block, 0, stream>>>(q, w_q, b_q, qp, M, D_MODEL, D_MODEL);
    gemm_xwT<1><<<grid, block, 0, stream>>>(k, w_k, b_k, kp, M, D_MODEL, D_MODEL);
    gemm_xwT<1><<<grid, block, 0, stream>>>(v, w_v, b_v, vp, M, D_MODEL, D_MODEL);

    attn_kernel<<<dim3(BB * NHEAD * (SS / 256)), block, 0, stream>>>(qp, kp, vp, mask, ctx);

    gemm_xwT<0><<<grid, block, 0, stream>>>(ctx, w_o, b_o, out, M, D_MODEL, D_MODEL);
}

// Round 4
// 1315.783 us; speedup vs baseline: 2.1992x; 2.1992x over previous
//
#include <hip/hip_runtime.h>

#define D_MODEL 1024
#define NHEAD   16
#define DK      64
#define SS      2048
#define BB      4

typedef short bf16x8 __attribute__((ext_vector_type(8)));
typedef float f32x4  __attribute__((ext_vector_type(4)));

__device__ inline unsigned short f2bf(float x) {
    unsigned u = __float_as_uint(x);
    return (unsigned short)((u + 0x7fff + ((u >> 16) & 1)) >> 16);
}
__device__ inline float bf2f(unsigned short h) {
    return __uint_as_float(((unsigned)h) << 16);
}

// ---------------------------------------------------------------------------
// fp32 GEMM: C[m,n] = sum_k A[m,k] * W[n,k] + bias[n]  (unchanged)
// ---------------------------------------------------------------------------
template <int ATTN_LAYOUT>
__global__ __launch_bounds__(256) void gemm_xwT(const float* __restrict__ A,
                                                const float* __restrict__ W,
                                                const float* __restrict__ bias,
                                                float* __restrict__ C,
                                                int M, int N, int K) {
    __shared__ float As[8][132];
    __shared__ float Bs[8][132];

    const int tid = threadIdx.x;
    const int tx  = tid & 15;
    const int ty  = tid >> 4;
    const int m0  = blockIdx.y * 128;
    const int n0  = blockIdx.x * 128;

    const int lr = tid >> 1;
    const int lk = (tid & 1) * 4;

    float acc[8][8];
#pragma unroll
    for (int i = 0; i < 8; ++i)
#pragma unroll
        for (int j = 0; j < 8; ++j) acc[i][j] = 0.f;

    for (int kt = 0; kt < K; kt += 8) {
        float4 av = *(const float4*)&A[(size_t)(m0 + lr) * K + kt + lk];
        float4 wv = *(const float4*)&W[(size_t)(n0 + lr) * K + kt + lk];
        __syncthreads();
        As[lk + 0][lr] = av.x; As[lk + 1][lr] = av.y;
        As[lk + 2][lr] = av.z; As[lk + 3][lr] = av.w;
        Bs[lk + 0][lr] = wv.x; Bs[lk + 1][lr] = wv.y;
        Bs[lk + 2][lr] = wv.z; Bs[lk + 3][lr] = wv.w;
        __syncthreads();
#pragma unroll
        for (int k = 0; k < 8; ++k) {
            float4 a0 = *(const float4*)&As[k][ty * 8];
            float4 a1 = *(const float4*)&As[k][ty * 8 + 4];
            float4 b0 = *(const float4*)&Bs[k][tx * 8];
            float4 b1 = *(const float4*)&Bs[k][tx * 8 + 4];
            float a[8] = {a0.x, a0.y, a0.z, a0.w, a1.x, a1.y, a1.z, a1.w};
            float b[8] = {b0.x, b0.y, b0.z, b0.w, b1.x, b1.y, b1.z, b1.w};
#pragma unroll
            for (int i = 0; i < 8; ++i)
#pragma unroll
                for (int j = 0; j < 8; ++j) acc[i][j] += a[i] * b[j];
        }
    }

    float bb[8];
#pragma unroll
    for (int j = 0; j < 8; ++j) bb[j] = bias[n0 + tx * 8 + j];

#pragma unroll
    for (int i = 0; i < 8; ++i) {
        int m = m0 + ty * 8 + i;
        int n = n0 + tx * 8;
        float4 c0 = {acc[i][0] + bb[0], acc[i][1] + bb[1], acc[i][2] + bb[2], acc[i][3] + bb[3]};
        float4 c1 = {acc[i][4] + bb[4], acc[i][5] + bb[5], acc[i][6] + bb[6], acc[i][7] + bb[7]};
        if (ATTN_LAYOUT) {
            int bq = m >> 11;
            int s  = m & (SS - 1);
            int h  = n >> 6;
            int d  = n & 63;
            float* dst = &C[(((size_t)(bq * NHEAD + h) * SS + s) << 6) + d];
            *(float4*)&dst[0] = c0;
            *(float4*)&dst[4] = c1;
        } else {
            float* dst = &C[(size_t)m * N + n];
            *(float4*)&dst[0] = c0;
            *(float4*)&dst[4] = c1;
        }
    }
}

// ---------------------------------------------------------------------------
// MFMA flash attention, split-bf16 (hi+lo) for Q, K, V, P.
// R3 fix: __syncthreads() between P-transpose LDS writes and reads (the
// wave-synchronous write->read was the only unordered LDS channel; LGKM ops
// may complete out of order, so this must be fenced).
// ---------------------------------------------------------------------------
__global__ __launch_bounds__(256) void attn_mfma(const float* __restrict__ Qp,
                                                 const float* __restrict__ Kp,
                                                 const float* __restrict__ Vp,
                                                 const int* __restrict__ mask,
                                                 float* __restrict__ ctx) {
    __shared__ short Khi[32 * 72], Klo[32 * 72];
    __shared__ short Vhi[64 * 40], Vlo[64 * 40];
    __shared__ float Pbuf[4][16 * 36];
    __shared__ int   msk[32];

    const int tid  = threadIdx.x;
    const int lane = tid & 63;
    const int wid  = tid >> 6;

    const int bid = blockIdx.x;
    const int swz = (bid & 7) * 256 + (bid >> 3);
    const int qt  = swz & 31;
    const int bh  = swz >> 5;
    const int b   = bh >> 4;
    const int h   = bh & 15;

    const int q0  = qt * 64;
    const int wq0 = wid * 16;

    const int fr = lane & 15;
    const int fg = lane >> 4;

    const float* qbase = Qp + ((size_t)bh * SS + q0 + wq0) * DK;
    const float* kbase = Kp + (size_t)bh * SS * DK;
    const float* vbase = Vp + (size_t)bh * SS * DK;
    const int*   mrow  = mask + b * SS;

    bf16x8 qh[2], ql[2];
#pragma unroll
    for (int kb = 0; kb < 2; ++kb) {
        const float* p = qbase + (size_t)fr * DK + kb * 32 + fg * 8;
        float4 a  = *(const float4*)p;
        float4 b4 = *(const float4*)(p + 4);
        float vals[8] = {a.x, a.y, a.z, a.w, b4.x, b4.y, b4.z, b4.w};
#pragma unroll
        for (int i = 0; i < 8; ++i) {
            float s = vals[i] * 0.125f;
            unsigned short hi = f2bf(s);
            qh[kb][i] = (short)hi;
            ql[kb][i] = (short)f2bf(s - bf2f(hi));
        }
    }

    f32x4 O[4] = {};
    float m_run[4], l_run[4];
#pragma unroll
    for (int r = 0; r < 4; ++r) { m_run[r] = -3.0e38f; l_run[r] = 0.f; }

    const int sk_k = tid >> 3;
    const int sk_d = (tid & 7) * 8;
    const int sv_d = tid & 63;
    const int sv_k = (tid >> 6) * 8;

    for (int t = 0; t < SS / 32; ++t) {
        const int kv0 = t * 32;

        const float* kptr = kbase + (size_t)(kv0 + sk_k) * DK + sk_d;
        float4 ka  = *(const float4*)kptr;
        float4 kbv = *(const float4*)(kptr + 4);
        float vv[8];
#pragma unroll
        for (int j = 0; j < 8; ++j)
            vv[j] = vbase[(size_t)(kv0 + sv_k + j) * DK + sv_d];
        int mval = (tid < 32) ? mrow[kv0 + tid] : 0;

        __syncthreads();   // previous tile fully consumed
        {
            float kv8[8] = {ka.x, ka.y, ka.z, ka.w, kbv.x, kbv.y, kbv.z, kbv.w};
            bf16x8 h8, l8;
#pragma unroll
            for (int i = 0; i < 8; ++i) {
                unsigned short hi = f2bf(kv8[i]);
                h8[i] = (short)hi;
                l8[i] = (short)f2bf(kv8[i] - bf2f(hi));
            }
            *(bf16x8*)&Khi[sk_k * 72 + sk_d] = h8;
            *(bf16x8*)&Klo[sk_k * 72 + sk_d] = l8;
        }
        {
            bf16x8 h8, l8;
#pragma unroll
            for (int j = 0; j < 8; ++j) {
                unsigned short hi = f2bf(vv[j]);
                h8[j] = (short)hi;
                l8[j] = (short)f2bf(vv[j] - bf2f(hi));
            }
            *(bf16x8*)&Vhi[sv_d * 40 + sv_k] = h8;
            *(bf16x8*)&Vlo[sv_d * 40 + sv_k] = l8;
        }
        if (tid < 32) msk[tid] = mval;
        __syncthreads();

        // --- QK^T
        f32x4 acc[2] = {};
#pragma unroll
        for (int kyb = 0; kyb < 2; ++kyb) {
#pragma unroll
            for (int kb = 0; kb < 2; ++kb) {
                int idx = (kyb * 16 + fr) * 72 + kb * 32 + fg * 8;
                bf16x8 kh = *(const bf16x8*)&Khi[idx];
                bf16x8 kl = *(const bf16x8*)&Klo[idx];
                acc[kyb] = __builtin_amdgcn_mfma_f32_16x16x32_bf16(qh[kb], kh, acc[kyb], 0, 0, 0);
                acc[kyb] = __builtin_amdgcn_mfma_f32_16x16x32_bf16(qh[kb], kl, acc[kyb], 0, 0, 0);
                acc[kyb] = __builtin_amdgcn_mfma_f32_16x16x32_bf16(ql[kb], kh, acc[kyb], 0, 0, 0);
            }
        }

        // --- mask + online softmax
        float sc[2][4];
#pragma unroll
        for (int kyb = 0; kyb < 2; ++kyb) {
            int mv = msk[kyb * 16 + fr];
#pragma unroll
            for (int r = 0; r < 4; ++r)
                sc[kyb][r] = mv ? acc[kyb][r] : -1.0e9f;
        }
        float scale[4], p[2][4];
#pragma unroll
        for (int r = 0; r < 4; ++r) {
            float v = fmaxf(sc[0][r], sc[1][r]);
            v = fmaxf(v, __shfl_xor(v, 1));
            v = fmaxf(v, __shfl_xor(v, 2));
            v = fmaxf(v, __shfl_xor(v, 4));
            v = fmaxf(v, __shfl_xor(v, 8));
            float m_new = fmaxf(m_run[r], v);
            scale[r] = __expf(m_run[r] - m_new);
            m_run[r] = m_new;
            p[0][r] = __expf(sc[0][r] - m_new);
            p[1][r] = __expf(sc[1][r] - m_new);
            float s = p[0][r] + p[1][r];
            s += __shfl_xor(s, 1);
            s += __shfl_xor(s, 2);
            s += __shfl_xor(s, 4);
            s += __shfl_xor(s, 8);
            l_run[r] = l_run[r] * scale[r] + s;
        }

        // --- transpose P via per-wave LDS
        float* pw = Pbuf[wid];
#pragma unroll
        for (int r = 0; r < 4; ++r) {
            pw[(fg * 4 + r) * 36 + fr]      = p[0][r];
            pw[(fg * 4 + r) * 36 + 16 + fr] = p[1][r];
        }
        // rescale O while the writes drain
#pragma unroll
        for (int db = 0; db < 4; ++db)
#pragma unroll
            for (int r = 0; r < 4; ++r)
                O[db][r] *= scale[r];

        __syncthreads();   // R3 FIX: order Pbuf writes before reads

        float pr[8];
        {
            const float* prd = &pw[fr * 36 + fg * 8];
            *(float4*)&pr[0] = *(const float4*)&prd[0];
            *(float4*)&pr[4] = *(const float4*)&prd[4];
        }
        bf16x8 ph8, pl8;
#pragma unroll
        for (int i = 0; i < 8; ++i) {
            unsigned short hi = f2bf(pr[i]);
            ph8[i] = (short)hi;
            pl8[i] = (short)f2bf(pr[i] - bf2f(hi));
        }

        // --- PV
#pragma unroll
        for (int db = 0; db < 4; ++db) {
            int idx = (db * 16 + fr) * 40 + fg * 8;
            bf16x8 vh = *(const bf16x8*)&Vhi[idx];
            bf16x8 vl = *(const bf16x8*)&Vlo[idx];
            O[db] = __builtin_amdgcn_mfma_f32_16x16x32_bf16(ph8, vh, O[db], 0, 0, 0);
            O[db] = __builtin_amdgcn_mfma_f32_16x16x32_bf16(ph8, vl, O[db], 0, 0, 0);
            O[db] = __builtin_amdgcn_mfma_f32_16x16x32_bf16(pl8, vh, O[db], 0, 0, 0);
        }
    }

    float* cbase = ctx + ((size_t)b * SS + q0 + wq0) * D_MODEL + h * DK;
#pragma unroll
    for (int r = 0; r < 4; ++r) {
        float inv = 1.0f / l_run[r];
        int q = fg * 4 + r;
#pragma unroll
        for (int db = 0; db < 4; ++db)
            cbase[(size_t)q * D_MODEL + db * 16 + fr] = O[db][r] * inv;
    }
}

// ---------------------------------------------------------------------------
extern "C" void kernel_launch(void* const* d_in, const int* in_sizes, int n_in,
                              void* d_out, int out_size, void* d_ws, size_t ws_size,
                              hipStream_t stream) {
    const float* q    = (const float*)d_in[0];
    const float* k    = (const float*)d_in[1];
    const float* v    = (const float*)d_in[2];
    const int*   mask = (const int*)d_in[3];
    const float* w_q  = (const float*)d_in[4];
    const float* b_q  = (const float*)d_in[5];
    const float* w_k  = (const float*)d_in[6];
    const float* b_k  = (const float*)d_in[7];
    const float* w_v  = (const float*)d_in[8];
    const float* b_v  = (const float*)d_in[9];
    const float* w_o  = (const float*)d_in[10];
    const float* b_o  = (const float*)d_in[11];
    float* out = (float*)d_out;

    const size_t PSZ = (size_t)BB * NHEAD * SS * DK;
    float* qp  = (float*)d_ws;
    float* kp  = qp + PSZ;
    float* vp  = kp + PSZ;
    float* ctx = vp + PSZ;

    const int M = BB * SS;
    dim3 grid(D_MODEL / 128, M / 128);
    dim3 block(256);

    gemm_xwT<1><<<grid, block, 0, stream>>>(q, w_q, b_q, qp, M, D_MODEL, D_MODEL);
    gemm_xwT<1><<<grid, block, 0, stream>>>(k, w_k, b_k, kp, M, D_MODEL, D_MODEL);
    gemm_xwT<1><<<grid, block, 0, stream>>>(v, w_v, b_v, vp, M, D_MODEL, D_MODEL);

    attn_mfma<<<dim3(BB * NHEAD * (SS / 64)), block, 0, stream>>>(qp, kp, vp, mask, ctx);

    gemm_xwT<0><<<grid, block, 0, stream>>>(ctx, w_o, b_o, out, M, D_MODEL, D_MODEL);
}

// Round 5
// 1285.512 us; speedup vs baseline: 2.2510x; 1.0235x over previous
//
#include <hip/hip_runtime.h>

#define D_MODEL 1024
#define NHEAD   16
#define DK      64
#define SS      2048
#define BB      4

typedef short bf16x8 __attribute__((ext_vector_type(8)));
typedef unsigned short u16x8 __attribute__((ext_vector_type(8)));
typedef float f32x4  __attribute__((ext_vector_type(4)));

__device__ inline unsigned short f2bf(float x) {
    unsigned u = __float_as_uint(x);
    return (unsigned short)((u + 0x7fff + ((u >> 16) & 1)) >> 16);
}
__device__ inline float bf2f(unsigned short h) {
    return __uint_as_float(((unsigned)h) << 16);
}

// ---------------------------------------------------------------------------
// fp32 GEMM: C[m,n] = sum_k A[m,k] * W[n,k] + bias[n]
// MODE 0: fp32 out, [M,N] row-major
// MODE 1: fp32 out, [B,H,S,DK] attention layout
// MODE 2: bf16 hi/lo out (split), [B,H,S,DK] attention layout
// ---------------------------------------------------------------------------
template <int MODE>
__global__ __launch_bounds__(256) void gemm_xwT(const float* __restrict__ A,
                                                const float* __restrict__ W,
                                                const float* __restrict__ bias,
                                                float* __restrict__ C,
                                                unsigned short* __restrict__ Chi,
                                                unsigned short* __restrict__ Clo,
                                                int M, int N, int K) {
    __shared__ float As[8][132];
    __shared__ float Bs[8][132];

    const int tid = threadIdx.x;
    const int tx  = tid & 15;
    const int ty  = tid >> 4;
    const int m0  = blockIdx.y * 128;
    const int n0  = blockIdx.x * 128;

    const int lr = tid >> 1;
    const int lk = (tid & 1) * 4;

    float acc[8][8];
#pragma unroll
    for (int i = 0; i < 8; ++i)
#pragma unroll
        for (int j = 0; j < 8; ++j) acc[i][j] = 0.f;

    for (int kt = 0; kt < K; kt += 8) {
        float4 av = *(const float4*)&A[(size_t)(m0 + lr) * K + kt + lk];
        float4 wv = *(const float4*)&W[(size_t)(n0 + lr) * K + kt + lk];
        __syncthreads();
        As[lk + 0][lr] = av.x; As[lk + 1][lr] = av.y;
        As[lk + 2][lr] = av.z; As[lk + 3][lr] = av.w;
        Bs[lk + 0][lr] = wv.x; Bs[lk + 1][lr] = wv.y;
        Bs[lk + 2][lr] = wv.z; Bs[lk + 3][lr] = wv.w;
        __syncthreads();
#pragma unroll
        for (int k = 0; k < 8; ++k) {
            float4 a0 = *(const float4*)&As[k][ty * 8];
            float4 a1 = *(const float4*)&As[k][ty * 8 + 4];
            float4 b0 = *(const float4*)&Bs[k][tx * 8];
            float4 b1 = *(const float4*)&Bs[k][tx * 8 + 4];
            float a[8] = {a0.x, a0.y, a0.z, a0.w, a1.x, a1.y, a1.z, a1.w};
            float b[8] = {b0.x, b0.y, b0.z, b0.w, b1.x, b1.y, b1.z, b1.w};
#pragma unroll
            for (int i = 0; i < 8; ++i)
#pragma unroll
                for (int j = 0; j < 8; ++j) acc[i][j] += a[i] * b[j];
        }
    }

    float bb[8];
#pragma unroll
    for (int j = 0; j < 8; ++j) bb[j] = bias[n0 + tx * 8 + j];

#pragma unroll
    for (int i = 0; i < 8; ++i) {
        int m = m0 + ty * 8 + i;
        int n = n0 + tx * 8;
        float cv[8];
#pragma unroll
        for (int j = 0; j < 8; ++j) cv[j] = acc[i][j] + bb[j];

        if (MODE == 0) {
            float* dst = &C[(size_t)m * N + n];
            *(float4*)&dst[0] = {cv[0], cv[1], cv[2], cv[3]};
            *(float4*)&dst[4] = {cv[4], cv[5], cv[6], cv[7]};
        } else {
            int bq = m >> 11;
            int s  = m & (SS - 1);
            int h  = n >> 6;
            int d  = n & 63;
            size_t base = (((size_t)(bq * NHEAD + h) * SS + s) << 6) + d;
            if (MODE == 1) {
                float* dst = &C[base];
                *(float4*)&dst[0] = {cv[0], cv[1], cv[2], cv[3]};
                *(float4*)&dst[4] = {cv[4], cv[5], cv[6], cv[7]};
            } else {
                u16x8 h8, l8;
#pragma unroll
                for (int j = 0; j < 8; ++j) {
                    unsigned short hi = f2bf(cv[j]);
                    h8[j] = hi;
                    l8[j] = f2bf(cv[j] - bf2f(hi));
                }
                *(u16x8*)&Chi[base] = h8;
                *(u16x8*)&Clo[base] = l8;
            }
        }
    }
}

// ---------------------------------------------------------------------------
// MFMA flash attention. K/V arrive pre-split as bf16 hi/lo (converted once in
// the projection GEMM epilogues) -> staging is pure data movement, no VALU
// conversion per tile. Math bit-identical to R4.
// ---------------------------------------------------------------------------
__global__ __launch_bounds__(256) void attn_mfma(const float* __restrict__ Qp,
                                                 const unsigned short* __restrict__ Khig,
                                                 const unsigned short* __restrict__ Klog,
                                                 const unsigned short* __restrict__ Vhig,
                                                 const unsigned short* __restrict__ Vlog,
                                                 const int* __restrict__ mask,
                                                 float* __restrict__ ctx) {
    __shared__ short Khi[32 * 72], Klo[32 * 72];
    __shared__ short Vhi[64 * 40], Vlo[64 * 40];
    __shared__ float Pbuf[4][16 * 36];
    __shared__ int   msk[32];

    const int tid  = threadIdx.x;
    const int lane = tid & 63;
    const int wid  = tid >> 6;

    const int bid = blockIdx.x;
    const int swz = (bid & 7) * 256 + (bid >> 3);
    const int qt  = swz & 31;
    const int bh  = swz >> 5;
    const int b   = bh >> 4;
    const int h   = bh & 15;

    const int q0  = qt * 64;
    const int wq0 = wid * 16;

    const int fr = lane & 15;
    const int fg = lane >> 4;

    const float* qbase = Qp + ((size_t)bh * SS + q0 + wq0) * DK;
    const unsigned short* khbase = Khig + (size_t)bh * SS * DK;
    const unsigned short* klbase = Klog + (size_t)bh * SS * DK;
    const unsigned short* vhbase = Vhig + (size_t)bh * SS * DK;
    const unsigned short* vlbase = Vlog + (size_t)bh * SS * DK;
    const int* mrow = mask + b * SS;

    // Q fragments (fp32 -> split once per block), pre-scaled 1/8
    bf16x8 qh[2], ql[2];
#pragma unroll
    for (int kb = 0; kb < 2; ++kb) {
        const float* p = qbase + (size_t)fr * DK + kb * 32 + fg * 8;
        float4 a  = *(const float4*)p;
        float4 b4 = *(const float4*)(p + 4);
        float vals[8] = {a.x, a.y, a.z, a.w, b4.x, b4.y, b4.z, b4.w};
#pragma unroll
        for (int i = 0; i < 8; ++i) {
            float s = vals[i] * 0.125f;
            unsigned short hi = f2bf(s);
            qh[kb][i] = (short)hi;
            ql[kb][i] = (short)f2bf(s - bf2f(hi));
        }
    }

    f32x4 O[4] = {};
    float m_run[4], l_run[4];
#pragma unroll
    for (int r = 0; r < 4; ++r) { m_run[r] = -3.0e38f; l_run[r] = 0.f; }

    const int sk_k = tid >> 3;          // 0..31 key row
    const int sk_d = (tid & 7) * 8;     // d chunk
    const int sv_d = tid & 63;          // d column
    const int sv_k = (tid >> 6) * 8;    // key chunk

    for (int t = 0; t < SS / 32; ++t) {
        const int kv0 = t * 32;

        // global loads issued before the barrier
        size_t koff = (size_t)(kv0 + sk_k) * DK + sk_d;
        u16x8 kh8 = *(const u16x8*)&khbase[koff];
        u16x8 kl8 = *(const u16x8*)&klbase[koff];
        unsigned short vh[8], vl[8];
#pragma unroll
        for (int j = 0; j < 8; ++j) {
            size_t voff = (size_t)(kv0 + sv_k + j) * DK + sv_d;
            vh[j] = vhbase[voff];
            vl[j] = vlbase[voff];
        }
        int mval = (tid < 32) ? mrow[kv0 + tid] : 0;

        __syncthreads();   // previous tile fully consumed
        *(u16x8*)&Khi[sk_k * 72 + sk_d] = kh8;
        *(u16x8*)&Klo[sk_k * 72 + sk_d] = kl8;
        {
            u16x8 h8, l8;
#pragma unroll
            for (int j = 0; j < 8; ++j) { h8[j] = vh[j]; l8[j] = vl[j]; }
            *(u16x8*)&Vhi[sv_d * 40 + sv_k] = h8;
            *(u16x8*)&Vlo[sv_d * 40 + sv_k] = l8;
        }
        if (tid < 32) msk[tid] = mval;
        __syncthreads();

        // --- QK^T
        f32x4 acc[2] = {};
#pragma unroll
        for (int kyb = 0; kyb < 2; ++kyb) {
#pragma unroll
            for (int kb = 0; kb < 2; ++kb) {
                int idx = (kyb * 16 + fr) * 72 + kb * 32 + fg * 8;
                bf16x8 kh = *(const bf16x8*)&Khi[idx];
                bf16x8 kl = *(const bf16x8*)&Klo[idx];
                acc[kyb] = __builtin_amdgcn_mfma_f32_16x16x32_bf16(qh[kb], kh, acc[kyb], 0, 0, 0);
                acc[kyb] = __builtin_amdgcn_mfma_f32_16x16x32_bf16(qh[kb], kl, acc[kyb], 0, 0, 0);
                acc[kyb] = __builtin_amdgcn_mfma_f32_16x16x32_bf16(ql[kb], kh, acc[kyb], 0, 0, 0);
            }
        }

        // --- mask + online softmax
        float sc[2][4];
#pragma unroll
        for (int kyb = 0; kyb < 2; ++kyb) {
            int mv = msk[kyb * 16 + fr];
#pragma unroll
            for (int r = 0; r < 4; ++r)
                sc[kyb][r] = mv ? acc[kyb][r] : -1.0e9f;
        }
        float scale[4], p[2][4];
#pragma unroll
        for (int r = 0; r < 4; ++r) {
            float v = fmaxf(sc[0][r], sc[1][r]);
            v = fmaxf(v, __shfl_xor(v, 1));
            v = fmaxf(v, __shfl_xor(v, 2));
            v = fmaxf(v, __shfl_xor(v, 4));
            v = fmaxf(v, __shfl_xor(v, 8));
            float m_new = fmaxf(m_run[r], v);
            scale[r] = __expf(m_run[r] - m_new);
            m_run[r] = m_new;
            p[0][r] = __expf(sc[0][r] - m_new);
            p[1][r] = __expf(sc[1][r] - m_new);
            float s = p[0][r] + p[1][r];
            s += __shfl_xor(s, 1);
            s += __shfl_xor(s, 2);
            s += __shfl_xor(s, 4);
            s += __shfl_xor(s, 8);
            l_run[r] = l_run[r] * scale[r] + s;
        }

        // --- transpose P via per-wave LDS
        float* pw = Pbuf[wid];
#pragma unroll
        for (int r = 0; r < 4; ++r) {
            pw[(fg * 4 + r) * 36 + fr]      = p[0][r];
            pw[(fg * 4 + r) * 36 + 16 + fr] = p[1][r];
        }
#pragma unroll
        for (int db = 0; db < 4; ++db)
#pragma unroll
            for (int r = 0; r < 4; ++r)
                O[db][r] *= scale[r];

        __syncthreads();   // order Pbuf writes before reads

        float pr[8];
        {
            const float* prd = &pw[fr * 36 + fg * 8];
            *(float4*)&pr[0] = *(const float4*)&prd[0];
            *(float4*)&pr[4] = *(const float4*)&prd[4];
        }
        bf16x8 ph8, pl8;
#pragma unroll
        for (int i = 0; i < 8; ++i) {
            unsigned short hi = f2bf(pr[i]);
            ph8[i] = (short)hi;
            pl8[i] = (short)f2bf(pr[i] - bf2f(hi));
        }

        // --- PV
#pragma unroll
        for (int db = 0; db < 4; ++db) {
            int idx = (db * 16 + fr) * 40 + fg * 8;
            bf16x8 vh8 = *(const bf16x8*)&Vhi[idx];
            bf16x8 vl8 = *(const bf16x8*)&Vlo[idx];
            O[db] = __builtin_amdgcn_mfma_f32_16x16x32_bf16(ph8, vh8, O[db], 0, 0, 0);
            O[db] = __builtin_amdgcn_mfma_f32_16x16x32_bf16(ph8, vl8, O[db], 0, 0, 0);
            O[db] = __builtin_amdgcn_mfma_f32_16x16x32_bf16(pl8, vh8, O[db], 0, 0, 0);
        }
    }

    float* cbase = ctx + ((size_t)b * SS + q0 + wq0) * D_MODEL + h * DK;
#pragma unroll
    for (int r = 0; r < 4; ++r) {
        float inv = 1.0f / l_run[r];
        int q = fg * 4 + r;
#pragma unroll
        for (int db = 0; db < 4; ++db)
            cbase[(size_t)q * D_MODEL + db * 16 + fr] = O[db][r] * inv;
    }
}

// ---------------------------------------------------------------------------
extern "C" void kernel_launch(void* const* d_in, const int* in_sizes, int n_in,
                              void* d_out, int out_size, void* d_ws, size_t ws_size,
                              hipStream_t stream) {
    const float* q    = (const float*)d_in[0];
    const float* k    = (const float*)d_in[1];
    const float* v    = (const float*)d_in[2];
    const int*   mask = (const int*)d_in[3];
    const float* w_q  = (const float*)d_in[4];
    const float* b_q  = (const float*)d_in[5];
    const float* w_k  = (const float*)d_in[6];
    const float* b_k  = (const float*)d_in[7];
    const float* w_v  = (const float*)d_in[8];
    const float* b_v  = (const float*)d_in[9];
    const float* w_o  = (const float*)d_in[10];
    const float* b_o  = (const float*)d_in[11];
    float* out = (float*)d_out;

    const size_t PSZ = (size_t)BB * NHEAD * SS * DK;   // 8,388,608
    float* qp           = (float*)d_ws;
    unsigned short* khi = (unsigned short*)(qp + PSZ);
    unsigned short* klo = khi + PSZ;
    unsigned short* vhi = klo + PSZ;
    unsigned short* vlo = vhi + PSZ;
    float* ctx          = (float*)(vlo + PSZ);

    const int M = BB * SS;
    dim3 grid(D_MODEL / 128, M / 128);
    dim3 block(256);

    gemm_xwT<1><<<grid, block, 0, stream>>>(q, w_q, b_q, qp, nullptr, nullptr, M, D_MODEL, D_MODEL);
    gemm_xwT<2><<<grid, block, 0, stream>>>(k, w_k, b_k, nullptr, khi, klo, M, D_MODEL, D_MODEL);
    gemm_xwT<2><<<grid, block, 0, stream>>>(v, w_v, b_v, nullptr, vhi, vlo, M, D_MODEL, D_MODEL);

    attn_mfma<<<dim3(BB * NHEAD * (SS / 64)), block, 0, stream>>>(qp, khi, klo, vhi, vlo, mask, ctx);

    gemm_xwT<0><<<grid, block, 0, stream>>>(ctx, w_o, b_o, out, nullptr, nullptr, M, D_MODEL, D_MODEL);
}

// Round 6
// 683.009 us; speedup vs baseline: 4.2367x; 1.8821x over previous
//
#include <hip/hip_runtime.h>
#include <stdint.h>

#define D_MODEL 1024
#define NHEAD   16
#define DK      64
#define SS      2048
#define BB      4

typedef short bf16x8 __attribute__((ext_vector_type(8)));
typedef unsigned short u16x8 __attribute__((ext_vector_type(8)));
typedef float f32x4  __attribute__((ext_vector_type(4)));

__device__ inline unsigned short f2bf(float x) {
    unsigned u = __float_as_uint(x);
    return (unsigned short)((u + 0x7fff + ((u >> 16) & 1)) >> 16);
}
__device__ inline float bf2f(unsigned short h) {
    return __uint_as_float(((unsigned)h) << 16);
}

__device__ inline void gll16(const void* g, void* l) {
    __builtin_amdgcn_global_load_lds(
        (const __attribute__((address_space(1))) unsigned int*)(g),
        (__attribute__((address_space(3))) unsigned int*)(l),
        16, 0, 0);
}

// ---------------------------------------------------------------------------
// Pre-split: fp32 row-major [R][1024] -> bf16 hi/lo in tiled-swizzled layout.
// Tile = [128 rows][32 k] bf16 = 8KB, tiles ordered [mt][kt] (32 kt per row).
// Within a tile: row r's logical 16B chunk cc stored at slot cc ^ (r&3) ^ ((r>>2)&3)
// -> GEMM ds_read_b128 at (fr, fg) is bank-conflict-free, and global_load_lds
// staging is linear.
// ---------------------------------------------------------------------------
struct SplitJob { const float* src; unsigned short* hi; unsigned short* lo; int nchunks; };
struct SplitJobs8 { SplitJob j[8]; };

__global__ __launch_bounds__(256) void presplit(SplitJobs8 jobs) {
    const SplitJob J = jobs.j[blockIdx.y];
    int g = blockIdx.x * 256 + threadIdx.x;
    if (g >= J.nchunks) return;
    int tile = g >> 9;           // 512 chunks per 8KB tile
    int w    = g & 511;
    int r    = w >> 2;           // row in tile 0..127
    int cc   = w & 3;            // logical 16B chunk (8 bf16)
    int mt   = tile >> 5;        // K/32 = 32 k-tiles per m-tile
    int kt   = tile & 31;
    int m    = mt * 128 + r;
    int k0   = kt * 32 + cc * 8;

    const float* s = J.src + (size_t)m * 1024 + k0;
    float4 f0 = *(const float4*)s;
    float4 f1 = *(const float4*)(s + 4);
    float vals[8] = {f0.x, f0.y, f0.z, f0.w, f1.x, f1.y, f1.z, f1.w};
    u16x8 h8, l8;
#pragma unroll
    for (int i = 0; i < 8; ++i) {
        unsigned short hv = f2bf(vals[i]);
        h8[i] = hv;
        l8[i] = f2bf(vals[i] - bf2f(hv));
    }
    int slot = cc ^ (r & 3) ^ ((r >> 2) & 3);
    size_t doff = (size_t)tile * 4096 + r * 32 + slot * 8;   // ushort index
    *(u16x8*)(J.hi + doff) = h8;
    *(u16x8*)(J.lo + doff) = l8;
}

// ---------------------------------------------------------------------------
// Split-bf16 MFMA GEMM: C = A * W^T + bias, 3-mfma Markidis (hh + hl + lh).
// A: [M/128][32][8KB] tiled-swizzled hi/lo.  W: [8][32][8KB] tiled-swizzled.
// 128x128 tile, BK=32, 256 threads (4 waves, 2x2 of 64x64 wave-tiles).
// MODE 0: fp32 [M,N]; MODE 1: fp32 [B,H,S,DK]; MODE 2: bf16 hi/lo [B,H,S,DK].
// ---------------------------------------------------------------------------
template <int MODE>
__global__ __launch_bounds__(256) void gemm_mfma(const unsigned short* __restrict__ Ahi,
                                                 const unsigned short* __restrict__ Alo,
                                                 const unsigned short* __restrict__ Bhi,
                                                 const unsigned short* __restrict__ Blo,
                                                 const float* __restrict__ bias,
                                                 float* __restrict__ C,
                                                 unsigned short* __restrict__ Chi,
                                                 unsigned short* __restrict__ Clo) {
    __shared__ unsigned short As_hi[4096], As_lo[4096], Bs_hi[4096], Bs_lo[4096];

    const int tid  = threadIdx.x;
    const int lane = tid & 63;
    const int wid  = tid >> 6;
    const int bx   = blockIdx.x;     // n-block 0..7
    const int by   = blockIdx.y;     // m-block 0..63
    const int wr   = wid >> 1;       // wave row 0..1
    const int wc   = wid & 1;        // wave col 0..1
    const int fr   = lane & 15;
    const int fg   = lane >> 4;
    const int chunk = fg ^ (fr & 3) ^ ((fr >> 2) & 3);

    f32x4 acc[4][4] = {};

    const size_t aT = (size_t)by * 32;
    const size_t bT = (size_t)bx * 32;
    const int soff  = wid * 2048 + lane * 16;   // staging byte offset

    for (int kt = 0; kt < 32; ++kt) {
        const char* at_h = (const char*)Ahi + ((aT + kt) << 13);
        const char* at_l = (const char*)Alo + ((aT + kt) << 13);
        const char* bt_h = (const char*)Bhi + ((bT + kt) << 13);
        const char* bt_l = (const char*)Blo + ((bT + kt) << 13);
        gll16(at_h + soff,        (char*)As_hi + soff);
        gll16(at_h + soff + 1024, (char*)As_hi + soff + 1024);
        gll16(at_l + soff,        (char*)As_lo + soff);
        gll16(at_l + soff + 1024, (char*)As_lo + soff + 1024);
        gll16(bt_h + soff,        (char*)Bs_hi + soff);
        gll16(bt_h + soff + 1024, (char*)Bs_hi + soff + 1024);
        gll16(bt_l + soff,        (char*)Bs_lo + soff);
        gll16(bt_l + soff + 1024, (char*)Bs_lo + soff + 1024);
        __syncthreads();   // compiler drains vmcnt before s_barrier -> LDS ready

        bf16x8 ah[4], al[4], bh[4], bl[4];
#pragma unroll
        for (int mi = 0; mi < 4; ++mi) {
            int ro = (wr * 64 + mi * 16 + fr) * 64 + chunk * 16;
            ah[mi] = *(const bf16x8*)((const char*)As_hi + ro);
            al[mi] = *(const bf16x8*)((const char*)As_lo + ro);
        }
#pragma unroll
        for (int ni = 0; ni < 4; ++ni) {
            int ro = (wc * 64 + ni * 16 + fr) * 64 + chunk * 16;
            bh[ni] = *(const bf16x8*)((const char*)Bs_hi + ro);
            bl[ni] = *(const bf16x8*)((const char*)Bs_lo + ro);
        }
#pragma unroll
        for (int mi = 0; mi < 4; ++mi)
#pragma unroll
            for (int ni = 0; ni < 4; ++ni) {
                acc[mi][ni] = __builtin_amdgcn_mfma_f32_16x16x32_bf16(ah[mi], bh[ni], acc[mi][ni], 0, 0, 0);
                acc[mi][ni] = __builtin_amdgcn_mfma_f32_16x16x32_bf16(ah[mi], bl[ni], acc[mi][ni], 0, 0, 0);
                acc[mi][ni] = __builtin_amdgcn_mfma_f32_16x16x32_bf16(al[mi], bh[ni], acc[mi][ni], 0, 0, 0);
            }
        __syncthreads();   // all reads done before next staging overwrites
    }

    // epilogue: D row = fg*4+r2, col = fr (m89-verified layout)
#pragma unroll
    for (int ni = 0; ni < 4; ++ni) {
        int col = bx * 128 + wc * 64 + ni * 16 + fr;
        float bb = bias[col];
#pragma unroll
        for (int mi = 0; mi < 4; ++mi)
#pragma unroll
            for (int r2 = 0; r2 < 4; ++r2) {
                int row = by * 128 + wr * 64 + mi * 16 + fg * 4 + r2;
                float cv = acc[mi][ni][r2] + bb;
                if (MODE == 0) {
                    C[(size_t)row * D_MODEL + col] = cv;
                } else {
                    int bq = row >> 11, s = row & (SS - 1), h = col >> 6, d = col & 63;
                    size_t base = (((size_t)(bq * NHEAD + h) * SS + s) << 6) + d;
                    if (MODE == 1) {
                        C[base] = cv;
                    } else {
                        unsigned short hv = f2bf(cv);
                        Chi[base] = hv;
                        Clo[base] = f2bf(cv - bf2f(hv));
                    }
                }
            }
    }
}

// ---------------------------------------------------------------------------
// fp32 GEMM (R5, kept as ws_size fallback path)
// ---------------------------------------------------------------------------
template <int MODE>
__global__ __launch_bounds__(256) void gemm_xwT(const float* __restrict__ A,
                                                const float* __restrict__ W,
                                                const float* __restrict__ bias,
                                                float* __restrict__ C,
                                                unsigned short* __restrict__ Chi,
                                                unsigned short* __restrict__ Clo,
                                                int M, int N, int K) {
    __shared__ float As[8][132];
    __shared__ float Bs[8][132];

    const int tid = threadIdx.x;
    const int tx  = tid & 15;
    const int ty  = tid >> 4;
    const int m0  = blockIdx.y * 128;
    const int n0  = blockIdx.x * 128;

    const int lr = tid >> 1;
    const int lk = (tid & 1) * 4;

    float acc[8][8];
#pragma unroll
    for (int i = 0; i < 8; ++i)
#pragma unroll
        for (int j = 0; j < 8; ++j) acc[i][j] = 0.f;

    for (int kt = 0; kt < K; kt += 8) {
        float4 av = *(const float4*)&A[(size_t)(m0 + lr) * K + kt + lk];
        float4 wv = *(const float4*)&W[(size_t)(n0 + lr) * K + kt + lk];
        __syncthreads();
        As[lk + 0][lr] = av.x; As[lk + 1][lr] = av.y;
        As[lk + 2][lr] = av.z; As[lk + 3][lr] = av.w;
        Bs[lk + 0][lr] = wv.x; Bs[lk + 1][lr] = wv.y;
        Bs[lk + 2][lr] = wv.z; Bs[lk + 3][lr] = wv.w;
        __syncthreads();
#pragma unroll
        for (int k = 0; k < 8; ++k) {
            float4 a0 = *(const float4*)&As[k][ty * 8];
            float4 a1 = *(const float4*)&As[k][ty * 8 + 4];
            float4 b0 = *(const float4*)&Bs[k][tx * 8];
            float4 b1 = *(const float4*)&Bs[k][tx * 8 + 4];
            float a[8] = {a0.x, a0.y, a0.z, a0.w, a1.x, a1.y, a1.z, a1.w};
            float b[8] = {b0.x, b0.y, b0.z, b0.w, b1.x, b1.y, b1.z, b1.w};
#pragma unroll
            for (int i = 0; i < 8; ++i)
#pragma unroll
                for (int j = 0; j < 8; ++j) acc[i][j] += a[i] * b[j];
        }
    }

    float bb[8];
#pragma unroll
    for (int j = 0; j < 8; ++j) bb[j] = bias[n0 + tx * 8 + j];

#pragma unroll
    for (int i = 0; i < 8; ++i) {
        int m = m0 + ty * 8 + i;
        int n = n0 + tx * 8;
        float cv[8];
#pragma unroll
        for (int j = 0; j < 8; ++j) cv[j] = acc[i][j] + bb[j];

        if (MODE == 0) {
            float* dst = &C[(size_t)m * N + n];
            *(float4*)&dst[0] = {cv[0], cv[1], cv[2], cv[3]};
            *(float4*)&dst[4] = {cv[4], cv[5], cv[6], cv[7]};
        } else {
            int bq = m >> 11;
            int s  = m & (SS - 1);
            int h  = n >> 6;
            int d  = n & 63;
            size_t base = (((size_t)(bq * NHEAD + h) * SS + s) << 6) + d;
            if (MODE == 1) {
                float* dst = &C[base];
                *(float4*)&dst[0] = {cv[0], cv[1], cv[2], cv[3]};
                *(float4*)&dst[4] = {cv[4], cv[5], cv[6], cv[7]};
            } else {
                u16x8 h8, l8;
#pragma unroll
                for (int j = 0; j < 8; ++j) {
                    unsigned short hv = f2bf(cv[j]);
                    h8[j] = hv;
                    l8[j] = f2bf(cv[j] - bf2f(hv));
                }
                *(u16x8*)&Chi[base] = h8;
                *(u16x8*)&Clo[base] = l8;
            }
        }
    }
}

// ---------------------------------------------------------------------------
// MFMA flash attention (unchanged from R5; validated)
// ---------------------------------------------------------------------------
__global__ __launch_bounds__(256) void attn_mfma(const float* __restrict__ Qp,
                                                 const unsigned short* __restrict__ Khig,
                                                 const unsigned short* __restrict__ Klog,
                                                 const unsigned short* __restrict__ Vhig,
                                                 const unsigned short* __restrict__ Vlog,
                                                 const int* __restrict__ mask,
                                                 float* __restrict__ ctx) {
    __shared__ short Khi[32 * 72], Klo[32 * 72];
    __shared__ short Vhi[64 * 40], Vlo[64 * 40];
    __shared__ float Pbuf[4][16 * 36];
    __shared__ int   msk[32];

    const int tid  = threadIdx.x;
    const int lane = tid & 63;
    const int wid  = tid >> 6;

    const int bid = blockIdx.x;
    const int swz = (bid & 7) * 256 + (bid >> 3);
    const int qt  = swz & 31;
    const int bh  = swz >> 5;
    const int b   = bh >> 4;
    const int h   = bh & 15;

    const int q0  = qt * 64;
    const int wq0 = wid * 16;

    const int fr = lane & 15;
    const int fg = lane >> 4;

    const float* qbase = Qp + ((size_t)bh * SS + q0 + wq0) * DK;
    const unsigned short* khbase = Khig + (size_t)bh * SS * DK;
    const unsigned short* klbase = Klog + (size_t)bh * SS * DK;
    const unsigned short* vhbase = Vhig + (size_t)bh * SS * DK;
    const unsigned short* vlbase = Vlog + (size_t)bh * SS * DK;
    const int* mrow = mask + b * SS;

    bf16x8 qh[2], ql[2];
#pragma unroll
    for (int kb = 0; kb < 2; ++kb) {
        const float* p = qbase + (size_t)fr * DK + kb * 32 + fg * 8;
        float4 a  = *(const float4*)p;
        float4 b4 = *(const float4*)(p + 4);
        float vals[8] = {a.x, a.y, a.z, a.w, b4.x, b4.y, b4.z, b4.w};
#pragma unroll
        for (int i = 0; i < 8; ++i) {
            float s = vals[i] * 0.125f;
            unsigned short hi = f2bf(s);
            qh[kb][i] = (short)hi;
            ql[kb][i] = (short)f2bf(s - bf2f(hi));
        }
    }

    f32x4 O[4] = {};
    float m_run[4], l_run[4];
#pragma unroll
    for (int r = 0; r < 4; ++r) { m_run[r] = -3.0e38f; l_run[r] = 0.f; }

    const int sk_k = tid >> 3;
    const int sk_d = (tid & 7) * 8;
    const int sv_d = tid & 63;
    const int sv_k = (tid >> 6) * 8;

    for (int t = 0; t < SS / 32; ++t) {
        const int kv0 = t * 32;

        size_t koff = (size_t)(kv0 + sk_k) * DK + sk_d;
        u16x8 kh8 = *(const u16x8*)&khbase[koff];
        u16x8 kl8 = *(const u16x8*)&klbase[koff];
        unsigned short vh[8], vl[8];
#pragma unroll
        for (int j = 0; j < 8; ++j) {
            size_t voff = (size_t)(kv0 + sv_k + j) * DK + sv_d;
            vh[j] = vhbase[voff];
            vl[j] = vlbase[voff];
        }
        int mval = (tid < 32) ? mrow[kv0 + tid] : 0;

        __syncthreads();
        *(u16x8*)&Khi[sk_k * 72 + sk_d] = kh8;
        *(u16x8*)&Klo[sk_k * 72 + sk_d] = kl8;
        {
            u16x8 h8, l8;
#pragma unroll
            for (int j = 0; j < 8; ++j) { h8[j] = vh[j]; l8[j] = vl[j]; }
            *(u16x8*)&Vhi[sv_d * 40 + sv_k] = h8;
            *(u16x8*)&Vlo[sv_d * 40 + sv_k] = l8;
        }
        if (tid < 32) msk[tid] = mval;
        __syncthreads();

        f32x4 acc[2] = {};
#pragma unroll
        for (int kyb = 0; kyb < 2; ++kyb) {
#pragma unroll
            for (int kb = 0; kb < 2; ++kb) {
                int idx = (kyb * 16 + fr) * 72 + kb * 32 + fg * 8;
                bf16x8 kh = *(const bf16x8*)&Khi[idx];
                bf16x8 kl = *(const bf16x8*)&Klo[idx];
                acc[kyb] = __builtin_amdgcn_mfma_f32_16x16x32_bf16(qh[kb], kh, acc[kyb], 0, 0, 0);
                acc[kyb] = __builtin_amdgcn_mfma_f32_16x16x32_bf16(qh[kb], kl, acc[kyb], 0, 0, 0);
                acc[kyb] = __builtin_amdgcn_mfma_f32_16x16x32_bf16(ql[kb], kh, acc[kyb], 0, 0, 0);
            }
        }

        float sc[2][4];
#pragma unroll
        for (int kyb = 0; kyb < 2; ++kyb) {
            int mv = msk[kyb * 16 + fr];
#pragma unroll
            for (int r = 0; r < 4; ++r)
                sc[kyb][r] = mv ? acc[kyb][r] : -1.0e9f;
        }
        float scale[4], p[2][4];
#pragma unroll
        for (int r = 0; r < 4; ++r) {
            float v = fmaxf(sc[0][r], sc[1][r]);
            v = fmaxf(v, __shfl_xor(v, 1));
            v = fmaxf(v, __shfl_xor(v, 2));
            v = fmaxf(v, __shfl_xor(v, 4));
            v = fmaxf(v, __shfl_xor(v, 8));
            float m_new = fmaxf(m_run[r], v);
            scale[r] = __expf(m_run[r] - m_new);
            m_run[r] = m_new;
            p[0][r] = __expf(sc[0][r] - m_new);
            p[1][r] = __expf(sc[1][r] - m_new);
            float s = p[0][r] + p[1][r];
            s += __shfl_xor(s, 1);
            s += __shfl_xor(s, 2);
            s += __shfl_xor(s, 4);
            s += __shfl_xor(s, 8);
            l_run[r] = l_run[r] * scale[r] + s;
        }

        float* pw = Pbuf[wid];
#pragma unroll
        for (int r = 0; r < 4; ++r) {
            pw[(fg * 4 + r) * 36 + fr]      = p[0][r];
            pw[(fg * 4 + r) * 36 + 16 + fr] = p[1][r];
        }
#pragma unroll
        for (int db = 0; db < 4; ++db)
#pragma unroll
            for (int r = 0; r < 4; ++r)
                O[db][r] *= scale[r];

        __syncthreads();

        float pr[8];
        {
            const float* prd = &pw[fr * 36 + fg * 8];
            *(float4*)&pr[0] = *(const float4*)&prd[0];
            *(float4*)&pr[4] = *(const float4*)&prd[4];
        }
        bf16x8 ph8, pl8;
#pragma unroll
        for (int i = 0; i < 8; ++i) {
            unsigned short hi = f2bf(pr[i]);
            ph8[i] = (short)hi;
            pl8[i] = (short)f2bf(pr[i] - bf2f(hi));
        }

#pragma unroll
        for (int db = 0; db < 4; ++db) {
            int idx = (db * 16 + fr) * 40 + fg * 8;
            bf16x8 vh8 = *(const bf16x8*)&Vhi[idx];
            bf16x8 vl8 = *(const bf16x8*)&Vlo[idx];
            O[db] = __builtin_amdgcn_mfma_f32_16x16x32_bf16(ph8, vh8, O[db], 0, 0, 0);
            O[db] = __builtin_amdgcn_mfma_f32_16x16x32_bf16(ph8, vl8, O[db], 0, 0, 0);
            O[db] = __builtin_amdgcn_mfma_f32_16x16x32_bf16(pl8, vh8, O[db], 0, 0, 0);
        }
    }

    float* cbase = ctx + ((size_t)b * SS + q0 + wq0) * D_MODEL + h * DK;
#pragma unroll
    for (int r = 0; r < 4; ++r) {
        float inv = 1.0f / l_run[r];
        int q = fg * 4 + r;
#pragma unroll
        for (int db = 0; db < 4; ++db)
            cbase[(size_t)q * D_MODEL + db * 16 + fr] = O[db][r] * inv;
    }
}

// ---------------------------------------------------------------------------
extern "C" void kernel_launch(void* const* d_in, const int* in_sizes, int n_in,
                              void* d_out, int out_size, void* d_ws, size_t ws_size,
                              hipStream_t stream) {
    const float* q    = (const float*)d_in[0];
    const float* k    = (const float*)d_in[1];
    const float* v    = (const float*)d_in[2];
    const int*   mask = (const int*)d_in[3];
    const float* w_q  = (const float*)d_in[4];
    const float* b_q  = (const float*)d_in[5];
    const float* w_k  = (const float*)d_in[6];
    const float* b_k  = (const float*)d_in[7];
    const float* w_v  = (const float*)d_in[8];
    const float* b_v  = (const float*)d_in[9];
    const float* w_o  = (const float*)d_in[10];
    const float* b_o  = (const float*)d_in[11];
    float* out = (float*)d_out;

    const int M = BB * SS;                       // 8192
    const size_t PSZ = (size_t)M * D_MODEL;      // 8,388,608 elems
    const size_t NEED = (size_t)208 << 20;
    char* w = (char*)d_ws;
    dim3 block(256);

    if (ws_size >= NEED) {
        // ---- fast path: split-bf16 MFMA GEMMs ----
        float* qp            = (float*)(w);                          // [0,32)
        unsigned short* khi  = (unsigned short*)(w + ((size_t)32 << 20));
        unsigned short* klo  = (unsigned short*)(w + ((size_t)48 << 20));
        unsigned short* vhi  = (unsigned short*)(w + ((size_t)64 << 20));
        unsigned short* vlo  = (unsigned short*)(w + ((size_t)80 << 20));
        unsigned short* Aq_h = (unsigned short*)(w + ((size_t)96 << 20));
        unsigned short* Aq_l = (unsigned short*)(w + ((size_t)112 << 20));
        float* ctx           = (float*)(w + ((size_t)96 << 20));     // alias Aq (dead)
        unsigned short* Ak_h = (unsigned short*)(w + ((size_t)128 << 20));
        unsigned short* Ak_l = (unsigned short*)(w + ((size_t)144 << 20));
        unsigned short* Av_h = (unsigned short*)(w + ((size_t)160 << 20));
        unsigned short* Av_l = (unsigned short*)(w + ((size_t)176 << 20));
        unsigned short* Wq_h = (unsigned short*)(w + ((size_t)192 << 20));
        unsigned short* Wq_l = (unsigned short*)(w + ((size_t)194 << 20));
        unsigned short* Wk_h = (unsigned short*)(w + ((size_t)196 << 20));
        unsigned short* Wk_l = (unsigned short*)(w + ((size_t)198 << 20));
        unsigned short* Wv_h = (unsigned short*)(w + ((size_t)200 << 20));
        unsigned short* Wv_l = (unsigned short*)(w + ((size_t)202 << 20));
        unsigned short* Wo_h = (unsigned short*)(w + ((size_t)204 << 20));
        unsigned short* Wo_l = (unsigned short*)(w + ((size_t)206 << 20));
        unsigned short* Ac_h = Ak_h;   // Actx aliases Ak (dead after gemm_k)
        unsigned short* Ac_l = Ak_l;

        const int ACT_CHUNKS = M * 128;        // 1,048,576
        const int W_CHUNKS   = 1024 * 128;     // 131,072

        SplitJobs8 J{};
        J.j[0] = {q,   Aq_h, Aq_l, ACT_CHUNKS};
        J.j[1] = {k,   Ak_h, Ak_l, ACT_CHUNKS};
        J.j[2] = {v,   Av_h, Av_l, ACT_CHUNKS};
        J.j[3] = {w_q, Wq_h, Wq_l, W_CHUNKS};
        J.j[4] = {w_k, Wk_h, Wk_l, W_CHUNKS};
        J.j[5] = {w_v, Wv_h, Wv_l, W_CHUNKS};
        J.j[6] = {w_o, Wo_h, Wo_l, W_CHUNKS};
        presplit<<<dim3(4096, 7), block, 0, stream>>>(J);

        dim3 ggrid(D_MODEL / 128, M / 128);    // 8 x 64
        gemm_mfma<1><<<ggrid, block, 0, stream>>>(Aq_h, Aq_l, Wq_h, Wq_l, b_q, qp, nullptr, nullptr);
        gemm_mfma<2><<<ggrid, block, 0, stream>>>(Ak_h, Ak_l, Wk_h, Wk_l, b_k, nullptr, khi, klo);
        gemm_mfma<2><<<ggrid, block, 0, stream>>>(Av_h, Av_l, Wv_h, Wv_l, b_v, nullptr, vhi, vlo);

        attn_mfma<<<dim3(BB * NHEAD * (SS / 64)), block, 0, stream>>>(qp, khi, klo, vhi, vlo, mask, ctx);

        SplitJobs8 J2{};
        J2.j[0] = {ctx, Ac_h, Ac_l, ACT_CHUNKS};
        presplit<<<dim3(4096, 1), block, 0, stream>>>(J2);

        gemm_mfma<0><<<ggrid, block, 0, stream>>>(Ac_h, Ac_l, Wo_h, Wo_l, b_o, out, nullptr, nullptr);
    } else {
        // ---- fallback: proven R5 pipeline (128 MB ws) ----
        float* qp           = (float*)d_ws;
        unsigned short* khi = (unsigned short*)(qp + PSZ);
        unsigned short* klo = khi + PSZ;
        unsigned short* vhi = klo + PSZ;
        unsigned short* vlo = vhi + PSZ;
        float* ctx          = (float*)(vlo + PSZ);

        dim3 grid(D_MODEL / 128, M / 128);
        gemm_xwT<1><<<grid, block, 0, stream>>>(q, w_q, b_q, qp, nullptr, nullptr, M, D_MODEL, D_MODEL);
        gemm_xwT<2><<<grid, block, 0, stream>>>(k, w_k, b_k, nullptr, khi, klo, M, D_MODEL, D_MODEL);
        gemm_xwT<2><<<grid, block, 0, stream>>>(v, w_v, b_v, nullptr, vhi, vlo, M, D_MODEL, D_MODEL);
        attn_mfma<<<dim3(BB * NHEAD * (SS / 64)), block, 0, stream>>>(qp, khi, klo, vhi, vlo, mask, ctx);
        gemm_xwT<0><<<grid, block, 0, stream>>>(ctx, w_o, b_o, out, nullptr, nullptr, M, D_MODEL, D_MODEL);
    }
}

// Round 7
// 557.659 us; speedup vs baseline: 5.1890x; 1.2248x over previous
//
#include <hip/hip_runtime.h>
#include <stdint.h>

#define D_MODEL 1024
#define NHEAD   16
#define DK      64
#define SS      2048
#define BB      4

typedef short bf16x8 __attribute__((ext_vector_type(8)));
typedef unsigned short u16x8 __attribute__((ext_vector_type(8)));
typedef float f32x4  __attribute__((ext_vector_type(4)));

__device__ inline unsigned short f2bf(float x) {
    unsigned u = __float_as_uint(x);
    return (unsigned short)((u + 0x7fff + ((u >> 16) & 1)) >> 16);
}
__device__ inline float bf2f(unsigned short h) {
    return __uint_as_float(((unsigned)h) << 16);
}

__device__ inline void gll16(const void* g, void* l) {
    __builtin_amdgcn_global_load_lds(
        (const __attribute__((address_space(1))) unsigned int*)(g),
        (__attribute__((address_space(3))) unsigned int*)(l),
        16, 0, 0);
}

// ---------------------------------------------------------------------------
// Pre-split: fp32 row-major [R][1024] -> bf16 hi/lo tiled-swizzled (unchanged)
// ---------------------------------------------------------------------------
struct SplitJob { const float* src; unsigned short* hi; unsigned short* lo; int nchunks; };
struct SplitJobs8 { SplitJob j[8]; };

__global__ __launch_bounds__(256) void presplit(SplitJobs8 jobs) {
    const SplitJob J = jobs.j[blockIdx.y];
    int g = blockIdx.x * 256 + threadIdx.x;
    if (g >= J.nchunks) return;
    int tile = g >> 9;
    int w    = g & 511;
    int r    = w >> 2;
    int cc   = w & 3;
    int mt   = tile >> 5;
    int kt   = tile & 31;
    int m    = mt * 128 + r;
    int k0   = kt * 32 + cc * 8;

    const float* s = J.src + (size_t)m * 1024 + k0;
    float4 f0 = *(const float4*)s;
    float4 f1 = *(const float4*)(s + 4);
    float vals[8] = {f0.x, f0.y, f0.z, f0.w, f1.x, f1.y, f1.z, f1.w};
    u16x8 h8, l8;
#pragma unroll
    for (int i = 0; i < 8; ++i) {
        unsigned short hv = f2bf(vals[i]);
        h8[i] = hv;
        l8[i] = f2bf(vals[i] - bf2f(hv));
    }
    int slot = cc ^ (r & 3) ^ ((r >> 2) & 3);
    size_t doff = (size_t)tile * 4096 + r * 32 + slot * 8;
    *(u16x8*)(J.hi + doff) = h8;
    *(u16x8*)(J.lo + doff) = l8;
}

// ---------------------------------------------------------------------------
// Split-bf16 MFMA GEMM (unchanged from R6, validated)
// ---------------------------------------------------------------------------
template <int MODE>
__global__ __launch_bounds__(256) void gemm_mfma(const unsigned short* __restrict__ Ahi,
                                                 const unsigned short* __restrict__ Alo,
                                                 const unsigned short* __restrict__ Bhi,
                                                 const unsigned short* __restrict__ Blo,
                                                 const float* __restrict__ bias,
                                                 float* __restrict__ C,
                                                 unsigned short* __restrict__ Chi,
                                                 unsigned short* __restrict__ Clo) {
    __shared__ unsigned short As_hi[4096], As_lo[4096], Bs_hi[4096], Bs_lo[4096];

    const int tid  = threadIdx.x;
    const int lane = tid & 63;
    const int wid  = tid >> 6;
    const int bx   = blockIdx.x;
    const int by   = blockIdx.y;
    const int wr   = wid >> 1;
    const int wc   = wid & 1;
    const int fr   = lane & 15;
    const int fg   = lane >> 4;
    const int chunk = fg ^ (fr & 3) ^ ((fr >> 2) & 3);

    f32x4 acc[4][4] = {};

    const size_t aT = (size_t)by * 32;
    const size_t bT = (size_t)bx * 32;
    const int soff  = wid * 2048 + lane * 16;

    for (int kt = 0; kt < 32; ++kt) {
        const char* at_h = (const char*)Ahi + ((aT + kt) << 13);
        const char* at_l = (const char*)Alo + ((aT + kt) << 13);
        const char* bt_h = (const char*)Bhi + ((bT + kt) << 13);
        const char* bt_l = (const char*)Blo + ((bT + kt) << 13);
        gll16(at_h + soff,        (char*)As_hi + soff);
        gll16(at_h + soff + 1024, (char*)As_hi + soff + 1024);
        gll16(at_l + soff,        (char*)As_lo + soff);
        gll16(at_l + soff + 1024, (char*)As_lo + soff + 1024);
        gll16(bt_h + soff,        (char*)Bs_hi + soff);
        gll16(bt_h + soff + 1024, (char*)Bs_hi + soff + 1024);
        gll16(bt_l + soff,        (char*)Bs_lo + soff);
        gll16(bt_l + soff + 1024, (char*)Bs_lo + soff + 1024);
        __syncthreads();

        bf16x8 ah[4], al[4], bh[4], bl[4];
#pragma unroll
        for (int mi = 0; mi < 4; ++mi) {
            int ro = (wr * 64 + mi * 16 + fr) * 64 + chunk * 16;
            ah[mi] = *(const bf16x8*)((const char*)As_hi + ro);
            al[mi] = *(const bf16x8*)((const char*)As_lo + ro);
        }
#pragma unroll
        for (int ni = 0; ni < 4; ++ni) {
            int ro = (wc * 64 + ni * 16 + fr) * 64 + chunk * 16;
            bh[ni] = *(const bf16x8*)((const char*)Bs_hi + ro);
            bl[ni] = *(const bf16x8*)((const char*)Bs_lo + ro);
        }
#pragma unroll
        for (int mi = 0; mi < 4; ++mi)
#pragma unroll
            for (int ni = 0; ni < 4; ++ni) {
                acc[mi][ni] = __builtin_amdgcn_mfma_f32_16x16x32_bf16(ah[mi], bh[ni], acc[mi][ni], 0, 0, 0);
                acc[mi][ni] = __builtin_amdgcn_mfma_f32_16x16x32_bf16(ah[mi], bl[ni], acc[mi][ni], 0, 0, 0);
                acc[mi][ni] = __builtin_amdgcn_mfma_f32_16x16x32_bf16(al[mi], bh[ni], acc[mi][ni], 0, 0, 0);
            }
        __syncthreads();
    }

#pragma unroll
    for (int ni = 0; ni < 4; ++ni) {
        int col = bx * 128 + wc * 64 + ni * 16 + fr;
        float bb = bias[col];
#pragma unroll
        for (int mi = 0; mi < 4; ++mi)
#pragma unroll
            for (int r2 = 0; r2 < 4; ++r2) {
                int row = by * 128 + wr * 64 + mi * 16 + fg * 4 + r2;
                float cv = acc[mi][ni][r2] + bb;
                if (MODE == 0) {
                    C[(size_t)row * D_MODEL + col] = cv;
                } else {
                    int bq = row >> 11, s = row & (SS - 1), h = col >> 6, d = col & 63;
                    size_t base = (((size_t)(bq * NHEAD + h) * SS + s) << 6) + d;
                    if (MODE == 1) {
                        C[base] = cv;
                    } else {
                        unsigned short hv = f2bf(cv);
                        Chi[base] = hv;
                        Clo[base] = f2bf(cv - bf2f(hv));
                    }
                }
            }
    }
}

// ---------------------------------------------------------------------------
// V transpose: vhi/vlo [bh][S][64] -> vthi/vtlo [bh][64][S]
// ---------------------------------------------------------------------------
__global__ __launch_bounds__(256) void vtrans(const unsigned short* __restrict__ vhi,
                                              const unsigned short* __restrict__ vlo,
                                              unsigned short* __restrict__ vthi,
                                              unsigned short* __restrict__ vtlo) {
    __shared__ unsigned short T0[64][72], T1[64][72];
    const int tid = threadIdx.x;
    const int st  = blockIdx.x;      // s-tile (64 rows)
    const int bh  = blockIdx.y;

    {
        int row = tid >> 2;           // s-local
        int c2  = (tid & 3) * 2;      // 2 chunks of 8 u16
        size_t src = ((size_t)bh * SS + st * 64 + row) * 64 + c2 * 8;
        u16x8 a0 = *(const u16x8*)&vhi[src];
        u16x8 a1 = *(const u16x8*)&vhi[src + 8];
        u16x8 b0 = *(const u16x8*)&vlo[src];
        u16x8 b1 = *(const u16x8*)&vlo[src + 8];
        *(u16x8*)&T0[row][c2 * 8]     = a0;
        *(u16x8*)&T0[row][c2 * 8 + 8] = a1;
        *(u16x8*)&T1[row][c2 * 8]     = b0;
        *(u16x8*)&T1[row][c2 * 8 + 8] = b1;
    }
    __syncthreads();
    {
        int d   = tid >> 2;
        int sch = tid & 3;            // 16-s chunk
        u16x8 h0, h1, l0, l1;
#pragma unroll
        for (int j = 0; j < 8; ++j) {
            h0[j] = T0[sch * 16 + j][d];
            h1[j] = T0[sch * 16 + 8 + j][d];
            l0[j] = T1[sch * 16 + j][d];
            l1[j] = T1[sch * 16 + 8 + j][d];
        }
        size_t ob = ((size_t)bh * 64 + d) * SS + st * 64 + sch * 16;
        *(u16x8*)&vthi[ob]     = h0;
        *(u16x8*)&vthi[ob + 8] = h1;
        *(u16x8*)&vtlo[ob]     = l0;
        *(u16x8*)&vtlo[ob + 8] = l1;
    }
}

// ---------------------------------------------------------------------------
// MFMA flash attention v2: 512 threads (8 waves x 16 q-rows = 128 q),
// KVBLK=64, global_load_lds staging with XOR-swizzled source, Vt from the
// pre-transposed global. Pbuf write->read fenced by lgkmcnt(0)+sched_barrier
// (wave-private buffer, rule-18 pattern).
// ---------------------------------------------------------------------------
__global__ __launch_bounds__(512) void attn_mfma2(const float* __restrict__ Qp,
                                                  const unsigned short* __restrict__ Khig,
                                                  const unsigned short* __restrict__ Klog,
                                                  const unsigned short* __restrict__ VThig,
                                                  const unsigned short* __restrict__ VTlog,
                                                  const int* __restrict__ mask,
                                                  float* __restrict__ ctx) {
    __shared__ unsigned short KsH[4096], KsL[4096];   // [64 key][64 d], slot-swz
    __shared__ unsigned short VsH[4096], VsL[4096];   // [64 d][64 key], slot-swz
    __shared__ float Pbuf[8][16 * 68];
    __shared__ int   msk[64];

    const int tid  = threadIdx.x;
    const int lane = tid & 63;
    const int wid  = tid >> 6;

    const int bid = blockIdx.x;                   // 1024 blocks
    const int swz = (bid & 7) * 128 + (bid >> 3); // XCD swizzle
    const int qt  = swz & 15;                     // 16 q-tiles of 128
    const int bh  = swz >> 4;
    const int b   = bh >> 4;
    const int h   = bh & 15;

    const int q0  = qt * 128;
    const int wq0 = wid * 16;

    const int fr = lane & 15;
    const int fg = lane >> 4;

    const float* qbase = Qp + ((size_t)bh * SS + q0 + wq0) * DK;
    const unsigned short* khb = Khig + (size_t)bh * SS * DK;
    const unsigned short* klb = Klog + (size_t)bh * SS * DK;
    const unsigned short* vhb = VThig + (size_t)bh * DK * SS;
    const unsigned short* vlb = VTlog + (size_t)bh * DK * SS;
    const int* mrow = mask + b * SS;

    // Q fragments, pre-scaled 1/8
    bf16x8 qh[2], ql[2];
#pragma unroll
    for (int kb = 0; kb < 2; ++kb) {
        const float* p = qbase + (size_t)fr * DK + kb * 32 + fg * 8;
        float4 a  = *(const float4*)p;
        float4 b4 = *(const float4*)(p + 4);
        float vals[8] = {a.x, a.y, a.z, a.w, b4.x, b4.y, b4.z, b4.w};
#pragma unroll
        for (int i = 0; i < 8; ++i) {
            float s = vals[i] * 0.125f;
            unsigned short hi = f2bf(s);
            qh[kb][i] = (short)hi;
            ql[kb][i] = (short)f2bf(s - bf2f(hi));
        }
    }

    f32x4 O[4] = {};
    float m_run[4], l_run[4];
#pragma unroll
    for (int r = 0; r < 4; ++r) { m_run[r] = -3.0e38f; l_run[r] = 0.f; }

    // staging geometry: 512 slots of 16B per 8KB array, 1 per thread
    const int srow = tid >> 3;              // LDS row (key for K, d for Vt)
    const int ssl  = tid & 7;               // LDS slot
    const int sch  = ssl ^ (srow & 7);      // global chunk (involution)
    const int ldsb = tid * 8;               // u16 offset = slot*8

    // fragment-read slot offsets (u16): row&7 == fr&7 for all kyb/db
    const int sl0 = ((0 + fg) ^ (fr & 7)) * 8;
    const int sl1 = ((4 + fg) ^ (fr & 7)) * 8;

    for (int t = 0; t < SS / 64; ++t) {
        const int kv0 = t * 64;

        __syncthreads();   // previous tile's LDS reads complete
        gll16(&khb[(size_t)(kv0 + srow) * 64 + sch * 8], &KsH[ldsb]);
        gll16(&klb[(size_t)(kv0 + srow) * 64 + sch * 8], &KsL[ldsb]);
        gll16(&vhb[(size_t)srow * SS + kv0 + sch * 8],   &VsH[ldsb]);
        gll16(&vlb[(size_t)srow * SS + kv0 + sch * 8],   &VsL[ldsb]);
        if (tid < 64) msk[tid] = mrow[kv0 + tid];
        __syncthreads();   // vmcnt+lgkm drained before barrier

        // --- QK^T: acc[kyb], D row=q=fg*4+r, col=key=kyb*16+fr
        f32x4 acc[4] = {};
#pragma unroll
        for (int kyb = 0; kyb < 4; ++kyb) {
            const int rb = (kyb * 16 + fr) * 64;
            {
                bf16x8 kh = *(const bf16x8*)&KsH[rb + sl0];
                bf16x8 kl = *(const bf16x8*)&KsL[rb + sl0];
                acc[kyb] = __builtin_amdgcn_mfma_f32_16x16x32_bf16(qh[0], kh, acc[kyb], 0, 0, 0);
                acc[kyb] = __builtin_amdgcn_mfma_f32_16x16x32_bf16(qh[0], kl, acc[kyb], 0, 0, 0);
                acc[kyb] = __builtin_amdgcn_mfma_f32_16x16x32_bf16(ql[0], kh, acc[kyb], 0, 0, 0);
            }
            {
                bf16x8 kh = *(const bf16x8*)&KsH[rb + sl1];
                bf16x8 kl = *(const bf16x8*)&KsL[rb + sl1];
                acc[kyb] = __builtin_amdgcn_mfma_f32_16x16x32_bf16(qh[1], kh, acc[kyb], 0, 0, 0);
                acc[kyb] = __builtin_amdgcn_mfma_f32_16x16x32_bf16(qh[1], kl, acc[kyb], 0, 0, 0);
                acc[kyb] = __builtin_amdgcn_mfma_f32_16x16x32_bf16(ql[1], kh, acc[kyb], 0, 0, 0);
            }
        }

        // --- mask + online softmax (row-reduce over 16 lanes)
        float sc[4][4];
#pragma unroll
        for (int kyb = 0; kyb < 4; ++kyb) {
            int mv = msk[kyb * 16 + fr];
#pragma unroll
            for (int r = 0; r < 4; ++r)
                sc[kyb][r] = mv ? acc[kyb][r] : -1.0e9f;
        }
        float scale[4], p[4][4];
#pragma unroll
        for (int r = 0; r < 4; ++r) {
            float v = fmaxf(fmaxf(sc[0][r], sc[1][r]), fmaxf(sc[2][r], sc[3][r]));
            v = fmaxf(v, __shfl_xor(v, 1));
            v = fmaxf(v, __shfl_xor(v, 2));
            v = fmaxf(v, __shfl_xor(v, 4));
            v = fmaxf(v, __shfl_xor(v, 8));
            float m_new = fmaxf(m_run[r], v);
            scale[r] = __expf(m_run[r] - m_new);
            m_run[r] = m_new;
            float s = 0.f;
#pragma unroll
            for (int kyb = 0; kyb < 4; ++kyb) {
                p[kyb][r] = __expf(sc[kyb][r] - m_new);
                s += p[kyb][r];
            }
            s += __shfl_xor(s, 1);
            s += __shfl_xor(s, 2);
            s += __shfl_xor(s, 4);
            s += __shfl_xor(s, 8);
            l_run[r] = l_run[r] * scale[r] + s;
        }

        // --- transpose P via wave-private LDS
        float* pw = Pbuf[wid];
#pragma unroll
        for (int kyb = 0; kyb < 4; ++kyb)
#pragma unroll
            for (int r = 0; r < 4; ++r)
                pw[(fg * 4 + r) * 68 + kyb * 16 + fr] = p[kyb][r];
#pragma unroll
        for (int db = 0; db < 4; ++db)
#pragma unroll
            for (int r = 0; r < 4; ++r)
                O[db][r] *= scale[r];

        asm volatile("s_waitcnt lgkmcnt(0)" ::: "memory");
        __builtin_amdgcn_sched_barrier(0);

        bf16x8 ph[2], pl[2];
#pragma unroll
        for (int kb = 0; kb < 2; ++kb) {
            const float* prd = &pw[fr * 68 + kb * 32 + fg * 8];
            float4 p0 = *(const float4*)&prd[0];
            float4 p1 = *(const float4*)&prd[4];
            float vals[8] = {p0.x, p0.y, p0.z, p0.w, p1.x, p1.y, p1.z, p1.w};
#pragma unroll
            for (int i = 0; i < 8; ++i) {
                unsigned short hi = f2bf(vals[i]);
                ph[kb][i] = (short)hi;
                pl[kb][i] = (short)f2bf(vals[i] - bf2f(hi));
            }
        }

        // --- PV: O[q][d], B-frag from Vt rows d=db*16+fr
#pragma unroll
        for (int db = 0; db < 4; ++db) {
            const int rb = (db * 16 + fr) * 64;
            {
                bf16x8 vh = *(const bf16x8*)&VsH[rb + sl0];
                bf16x8 vl = *(const bf16x8*)&VsL[rb + sl0];
                O[db] = __builtin_amdgcn_mfma_f32_16x16x32_bf16(ph[0], vh, O[db], 0, 0, 0);
                O[db] = __builtin_amdgcn_mfma_f32_16x16x32_bf16(ph[0], vl, O[db], 0, 0, 0);
                O[db] = __builtin_amdgcn_mfma_f32_16x16x32_bf16(pl[0], vh, O[db], 0, 0, 0);
            }
            {
                bf16x8 vh = *(const bf16x8*)&VsH[rb + sl1];
                bf16x8 vl = *(const bf16x8*)&VsL[rb + sl1];
                O[db] = __builtin_amdgcn_mfma_f32_16x16x32_bf16(ph[1], vh, O[db], 0, 0, 0);
                O[db] = __builtin_amdgcn_mfma_f32_16x16x32_bf16(ph[1], vl, O[db], 0, 0, 0);
                O[db] = __builtin_amdgcn_mfma_f32_16x16x32_bf16(pl[1], vh, O[db], 0, 0, 0);
            }
        }
    }

    float* cbase = ctx + ((size_t)b * SS + q0 + wq0) * D_MODEL + h * DK;
#pragma unroll
    for (int r = 0; r < 4; ++r) {
        float inv = 1.0f / l_run[r];
        int q = fg * 4 + r;
#pragma unroll
        for (int db = 0; db < 4; ++db)
            cbase[(size_t)q * D_MODEL + db * 16 + fr] = O[db][r] * inv;
    }
}

// ---------------------------------------------------------------------------
// fp32 GEMM + old attention (fallback path, unchanged/validated)
// ---------------------------------------------------------------------------
template <int MODE>
__global__ __launch_bounds__(256) void gemm_xwT(const float* __restrict__ A,
                                                const float* __restrict__ W,
                                                const float* __restrict__ bias,
                                                float* __restrict__ C,
                                                unsigned short* __restrict__ Chi,
                                                unsigned short* __restrict__ Clo,
                                                int M, int N, int K) {
    __shared__ float As[8][132];
    __shared__ float Bs[8][132];

    const int tid = threadIdx.x;
    const int tx  = tid & 15;
    const int ty  = tid >> 4;
    const int m0  = blockIdx.y * 128;
    const int n0  = blockIdx.x * 128;

    const int lr = tid >> 1;
    const int lk = (tid & 1) * 4;

    float acc[8][8];
#pragma unroll
    for (int i = 0; i < 8; ++i)
#pragma unroll
        for (int j = 0; j < 8; ++j) acc[i][j] = 0.f;

    for (int kt = 0; kt < K; kt += 8) {
        float4 av = *(const float4*)&A[(size_t)(m0 + lr) * K + kt + lk];
        float4 wv = *(const float4*)&W[(size_t)(n0 + lr) * K + kt + lk];
        __syncthreads();
        As[lk + 0][lr] = av.x; As[lk + 1][lr] = av.y;
        As[lk + 2][lr] = av.z; As[lk + 3][lr] = av.w;
        Bs[lk + 0][lr] = wv.x; Bs[lk + 1][lr] = wv.y;
        Bs[lk + 2][lr] = wv.z; Bs[lk + 3][lr] = wv.w;
        __syncthreads();
#pragma unroll
        for (int k = 0; k < 8; ++k) {
            float4 a0 = *(const float4*)&As[k][ty * 8];
            float4 a1 = *(const float4*)&As[k][ty * 8 + 4];
            float4 b0 = *(const float4*)&Bs[k][tx * 8];
            float4 b1 = *(const float4*)&Bs[k][tx * 8 + 4];
            float a[8] = {a0.x, a0.y, a0.z, a0.w, a1.x, a1.y, a1.z, a1.w};
            float b[8] = {b0.x, b0.y, b0.z, b0.w, b1.x, b1.y, b1.z, b1.w};
#pragma unroll
            for (int i = 0; i < 8; ++i)
#pragma unroll
                for (int j = 0; j < 8; ++j) acc[i][j] += a[i] * b[j];
        }
    }

    float bb[8];
#pragma unroll
    for (int j = 0; j < 8; ++j) bb[j] = bias[n0 + tx * 8 + j];

#pragma unroll
    for (int i = 0; i < 8; ++i) {
        int m = m0 + ty * 8 + i;
        int n = n0 + tx * 8;
        float cv[8];
#pragma unroll
        for (int j = 0; j < 8; ++j) cv[j] = acc[i][j] + bb[j];

        if (MODE == 0) {
            float* dst = &C[(size_t)m * N + n];
            *(float4*)&dst[0] = {cv[0], cv[1], cv[2], cv[3]};
            *(float4*)&dst[4] = {cv[4], cv[5], cv[6], cv[7]};
        } else {
            int bq = m >> 11;
            int s  = m & (SS - 1);
            int h  = n >> 6;
            int d  = n & 63;
            size_t base = (((size_t)(bq * NHEAD + h) * SS + s) << 6) + d;
            if (MODE == 1) {
                float* dst = &C[base];
                *(float4*)&dst[0] = {cv[0], cv[1], cv[2], cv[3]};
                *(float4*)&dst[4] = {cv[4], cv[5], cv[6], cv[7]};
            } else {
                u16x8 h8, l8;
#pragma unroll
                for (int j = 0; j < 8; ++j) {
                    unsigned short hv = f2bf(cv[j]);
                    h8[j] = hv;
                    l8[j] = f2bf(cv[j] - bf2f(hv));
                }
                *(u16x8*)&Chi[base] = h8;
                *(u16x8*)&Clo[base] = l8;
            }
        }
    }
}

__global__ __launch_bounds__(256) void attn_mfma(const float* __restrict__ Qp,
                                                 const unsigned short* __restrict__ Khig,
                                                 const unsigned short* __restrict__ Klog,
                                                 const unsigned short* __restrict__ Vhig,
                                                 const unsigned short* __restrict__ Vlog,
                                                 const int* __restrict__ mask,
                                                 float* __restrict__ ctx) {
    __shared__ short Khi[32 * 72], Klo[32 * 72];
    __shared__ short Vhi[64 * 40], Vlo[64 * 40];
    __shared__ float Pbuf[4][16 * 36];
    __shared__ int   msk[32];

    const int tid  = threadIdx.x;
    const int lane = tid & 63;
    const int wid  = tid >> 6;

    const int bid = blockIdx.x;
    const int swz = (bid & 7) * 256 + (bid >> 3);
    const int qt  = swz & 31;
    const int bh  = swz >> 5;
    const int b   = bh >> 4;
    const int h   = bh & 15;

    const int q0  = qt * 64;
    const int wq0 = wid * 16;

    const int fr = lane & 15;
    const int fg = lane >> 4;

    const float* qbase = Qp + ((size_t)bh * SS + q0 + wq0) * DK;
    const unsigned short* khbase = Khig + (size_t)bh * SS * DK;
    const unsigned short* klbase = Klog + (size_t)bh * SS * DK;
    const unsigned short* vhbase = Vhig + (size_t)bh * SS * DK;
    const unsigned short* vlbase = Vlog + (size_t)bh * SS * DK;
    const int* mrow = mask + b * SS;

    bf16x8 qh[2], ql[2];
#pragma unroll
    for (int kb = 0; kb < 2; ++kb) {
        const float* p = qbase + (size_t)fr * DK + kb * 32 + fg * 8;
        float4 a  = *(const float4*)p;
        float4 b4 = *(const float4*)(p + 4);
        float vals[8] = {a.x, a.y, a.z, a.w, b4.x, b4.y, b4.z, b4.w};
#pragma unroll
        for (int i = 0; i < 8; ++i) {
            float s = vals[i] * 0.125f;
            unsigned short hi = f2bf(s);
            qh[kb][i] = (short)hi;
            ql[kb][i] = (short)f2bf(s - bf2f(hi));
        }
    }

    f32x4 O[4] = {};
    float m_run[4], l_run[4];
#pragma unroll
    for (int r = 0; r < 4; ++r) { m_run[r] = -3.0e38f; l_run[r] = 0.f; }

    const int sk_k = tid >> 3;
    const int sk_d = (tid & 7) * 8;
    const int sv_d = tid & 63;
    const int sv_k = (tid >> 6) * 8;

    for (int t = 0; t < SS / 32; ++t) {
        const int kv0 = t * 32;

        size_t koff = (size_t)(kv0 + sk_k) * DK + sk_d;
        u16x8 kh8 = *(const u16x8*)&khbase[koff];
        u16x8 kl8 = *(const u16x8*)&klbase[koff];
        unsigned short vh[8], vl[8];
#pragma unroll
        for (int j = 0; j < 8; ++j) {
            size_t voff = (size_t)(kv0 + sv_k + j) * DK + sv_d;
            vh[j] = vhbase[voff];
            vl[j] = vlbase[voff];
        }
        int mval = (tid < 32) ? mrow[kv0 + tid] : 0;

        __syncthreads();
        *(u16x8*)&Khi[sk_k * 72 + sk_d] = kh8;
        *(u16x8*)&Klo[sk_k * 72 + sk_d] = kl8;
        {
            u16x8 h8, l8;
#pragma unroll
            for (int j = 0; j < 8; ++j) { h8[j] = vh[j]; l8[j] = vl[j]; }
            *(u16x8*)&Vhi[sv_d * 40 + sv_k] = h8;
            *(u16x8*)&Vlo[sv_d * 40 + sv_k] = l8;
        }
        if (tid < 32) msk[tid] = mval;
        __syncthreads();

        f32x4 acc[2] = {};
#pragma unroll
        for (int kyb = 0; kyb < 2; ++kyb) {
#pragma unroll
            for (int kb = 0; kb < 2; ++kb) {
                int idx = (kyb * 16 + fr) * 72 + kb * 32 + fg * 8;
                bf16x8 kh = *(const bf16x8*)&Khi[idx];
                bf16x8 kl = *(const bf16x8*)&Klo[idx];
                acc[kyb] = __builtin_amdgcn_mfma_f32_16x16x32_bf16(qh[kb], kh, acc[kyb], 0, 0, 0);
                acc[kyb] = __builtin_amdgcn_mfma_f32_16x16x32_bf16(qh[kb], kl, acc[kyb], 0, 0, 0);
                acc[kyb] = __builtin_amdgcn_mfma_f32_16x16x32_bf16(ql[kb], kh, acc[kyb], 0, 0, 0);
            }
        }

        float sc[2][4];
#pragma unroll
        for (int kyb = 0; kyb < 2; ++kyb) {
            int mv = msk[kyb * 16 + fr];
#pragma unroll
            for (int r = 0; r < 4; ++r)
                sc[kyb][r] = mv ? acc[kyb][r] : -1.0e9f;
        }
        float scale[4], p[2][4];
#pragma unroll
        for (int r = 0; r < 4; ++r) {
            float v = fmaxf(sc[0][r], sc[1][r]);
            v = fmaxf(v, __shfl_xor(v, 1));
            v = fmaxf(v, __shfl_xor(v, 2));
            v = fmaxf(v, __shfl_xor(v, 4));
            v = fmaxf(v, __shfl_xor(v, 8));
            float m_new = fmaxf(m_run[r], v);
            scale[r] = __expf(m_run[r] - m_new);
            m_run[r] = m_new;
            p[0][r] = __expf(sc[0][r] - m_new);
            p[1][r] = __expf(sc[1][r] - m_new);
            float s = p[0][r] + p[1][r];
            s += __shfl_xor(s, 1);
            s += __shfl_xor(s, 2);
            s += __shfl_xor(s, 4);
            s += __shfl_xor(s, 8);
            l_run[r] = l_run[r] * scale[r] + s;
        }

        float* pw = Pbuf[wid];
#pragma unroll
        for (int r = 0; r < 4; ++r) {
            pw[(fg * 4 + r) * 36 + fr]      = p[0][r];
            pw[(fg * 4 + r) * 36 + 16 + fr] = p[1][r];
        }
#pragma unroll
        for (int db = 0; db < 4; ++db)
#pragma unroll
            for (int r = 0; r < 4; ++r)
                O[db][r] *= scale[r];

        __syncthreads();

        float pr[8];
        {
            const float* prd = &pw[fr * 36 + fg * 8];
            *(float4*)&pr[0] = *(const float4*)&prd[0];
            *(float4*)&pr[4] = *(const float4*)&prd[4];
        }
        bf16x8 ph8, pl8;
#pragma unroll
        for (int i = 0; i < 8; ++i) {
            unsigned short hi = f2bf(pr[i]);
            ph8[i] = (short)hi;
            pl8[i] = (short)f2bf(pr[i] - bf2f(hi));
        }

#pragma unroll
        for (int db = 0; db < 4; ++db) {
            int idx = (db * 16 + fr) * 40 + fg * 8;
            bf16x8 vh8 = *(const bf16x8*)&Vhi[idx];
            bf16x8 vl8 = *(const bf16x8*)&Vlo[idx];
            O[db] = __builtin_amdgcn_mfma_f32_16x16x32_bf16(ph8, vh8, O[db], 0, 0, 0);
            O[db] = __builtin_amdgcn_mfma_f32_16x16x32_bf16(ph8, vl8, O[db], 0, 0, 0);
            O[db] = __builtin_amdgcn_mfma_f32_16x16x32_bf16(pl8, vh8, O[db], 0, 0, 0);
        }
    }

    float* cbase = ctx + ((size_t)b * SS + q0 + wq0) * D_MODEL + h * DK;
#pragma unroll
    for (int r = 0; r < 4; ++r) {
        float inv = 1.0f / l_run[r];
        int q = fg * 4 + r;
#pragma unroll
        for (int db = 0; db < 4; ++db)
            cbase[(size_t)q * D_MODEL + db * 16 + fr] = O[db][r] * inv;
    }
}

// ---------------------------------------------------------------------------
extern "C" void kernel_launch(void* const* d_in, const int* in_sizes, int n_in,
                              void* d_out, int out_size, void* d_ws, size_t ws_size,
                              hipStream_t stream) {
    const float* q    = (const float*)d_in[0];
    const float* k    = (const float*)d_in[1];
    const float* v    = (const float*)d_in[2];
    const int*   mask = (const int*)d_in[3];
    const float* w_q  = (const float*)d_in[4];
    const float* b_q  = (const float*)d_in[5];
    const float* w_k  = (const float*)d_in[6];
    const float* b_k  = (const float*)d_in[7];
    const float* w_v  = (const float*)d_in[8];
    const float* b_v  = (const float*)d_in[9];
    const float* w_o  = (const float*)d_in[10];
    const float* b_o  = (const float*)d_in[11];
    float* out = (float*)d_out;

    const int M = BB * SS;
    const size_t PSZ = (size_t)M * D_MODEL;
    const size_t NEED = (size_t)208 << 20;
    char* w = (char*)d_ws;
    dim3 block(256);

    if (ws_size >= NEED) {
        float* qp            = (float*)(w);
        unsigned short* khi  = (unsigned short*)(w + ((size_t)32 << 20));
        unsigned short* klo  = (unsigned short*)(w + ((size_t)48 << 20));
        unsigned short* vhi  = (unsigned short*)(w + ((size_t)64 << 20));
        unsigned short* vlo  = (unsigned short*)(w + ((size_t)80 << 20));
        unsigned short* Aq_h = (unsigned short*)(w + ((size_t)96 << 20));
        unsigned short* Aq_l = (unsigned short*)(w + ((size_t)112 << 20));
        float* ctx           = (float*)(w + ((size_t)96 << 20));     // alias Aq (dead)
        unsigned short* Ak_h = (unsigned short*)(w + ((size_t)128 << 20));
        unsigned short* Ak_l = (unsigned short*)(w + ((size_t)144 << 20));
        unsigned short* Av_h = (unsigned short*)(w + ((size_t)160 << 20));
        unsigned short* Av_l = (unsigned short*)(w + ((size_t)176 << 20));
        unsigned short* vthi = (unsigned short*)(w + ((size_t)160 << 20)); // alias Av_h (dead post V-GEMM)
        unsigned short* vtlo = (unsigned short*)(w + ((size_t)176 << 20)); // alias Av_l
        unsigned short* Wq_h = (unsigned short*)(w + ((size_t)192 << 20));
        unsigned short* Wq_l = (unsigned short*)(w + ((size_t)194 << 20));
        unsigned short* Wk_h = (unsigned short*)(w + ((size_t)196 << 20));
        unsigned short* Wk_l = (unsigned short*)(w + ((size_t)198 << 20));
        unsigned short* Wv_h = (unsigned short*)(w + ((size_t)200 << 20));
        unsigned short* Wv_l = (unsigned short*)(w + ((size_t)202 << 20));
        unsigned short* Wo_h = (unsigned short*)(w + ((size_t)204 << 20));
        unsigned short* Wo_l = (unsigned short*)(w + ((size_t)206 << 20));
        unsigned short* Ac_h = Ak_h;   // ctx presplit aliases Ak (dead post attn inputs)
        unsigned short* Ac_l = Ak_l;

        const int ACT_CHUNKS = M * 128;
        const int W_CHUNKS   = 1024 * 128;

        SplitJobs8 J{};
        J.j[0] = {q,   Aq_h, Aq_l, ACT_CHUNKS};
        J.j[1] = {k,   Ak_h, Ak_l, ACT_CHUNKS};
        J.j[2] = {v,   Av_h, Av_l, ACT_CHUNKS};
        J.j[3] = {w_q, Wq_h, Wq_l, W_CHUNKS};
        J.j[4] = {w_k, Wk_h, Wk_l, W_CHUNKS};
        J.j[5] = {w_v, Wv_h, Wv_l, W_CHUNKS};
        J.j[6] = {w_o, Wo_h, Wo_l, W_CHUNKS};
        presplit<<<dim3(4096, 7), block, 0, stream>>>(J);

        dim3 ggrid(D_MODEL / 128, M / 128);
        gemm_mfma<1><<<ggrid, block, 0, stream>>>(Aq_h, Aq_l, Wq_h, Wq_l, b_q, qp, nullptr, nullptr);
        gemm_mfma<2><<<ggrid, block, 0, stream>>>(Ak_h, Ak_l, Wk_h, Wk_l, b_k, nullptr, khi, klo);
        gemm_mfma<2><<<ggrid, block, 0, stream>>>(Av_h, Av_l, Wv_h, Wv_l, b_v, nullptr, vhi, vlo);

        vtrans<<<dim3(SS / 64, BB * NHEAD), block, 0, stream>>>(vhi, vlo, vthi, vtlo);

        attn_mfma2<<<dim3(BB * NHEAD * (SS / 128)), dim3(512), 0, stream>>>(
            qp, khi, klo, vthi, vtlo, mask, ctx);

        SplitJobs8 J2{};
        J2.j[0] = {ctx, Ac_h, Ac_l, ACT_CHUNKS};
        presplit<<<dim3(4096, 1), block, 0, stream>>>(J2);

        gemm_mfma<0><<<ggrid, block, 0, stream>>>(Ac_h, Ac_l, Wo_h, Wo_l, b_o, out, nullptr, nullptr);
    } else {
        float* qp           = (float*)d_ws;
        unsigned short* khi = (unsigned short*)(qp + PSZ);
        unsigned short* klo = khi + PSZ;
        unsigned short* vhi = klo + PSZ;
        unsigned short* vlo = vhi + PSZ;
        float* ctx          = (float*)(vlo + PSZ);

        dim3 grid(D_MODEL / 128, M / 128);
        gemm_xwT<1><<<grid, block, 0, stream>>>(q, w_q, b_q, qp, nullptr, nullptr, M, D_MODEL, D_MODEL);
        gemm_xwT<2><<<grid, block, 0, stream>>>(k, w_k, b_k, nullptr, khi, klo, M, D_MODEL, D_MODEL);
        gemm_xwT<2><<<grid, block, 0, stream>>>(v, w_v, b_v, nullptr, vhi, vlo, M, D_MODEL, D_MODEL);
        attn_mfma<<<dim3(BB * NHEAD * (SS / 64)), block, 0, stream>>>(qp, khi, klo, vhi, vlo, mask, ctx);
        gemm_xwT<0><<<grid, block, 0, stream>>>(ctx, w_o, b_o, out, nullptr, nullptr, M, D_MODEL, D_MODEL);
    }
}

// Round 8
// 546.272 us; speedup vs baseline: 5.2972x; 1.0208x over previous
//
#include <hip/hip_runtime.h>
#include <stdint.h>

#define D_MODEL 1024
#define NHEAD   16
#define DK      64
#define SS      2048
#define BB      4

typedef short bf16x8 __attribute__((ext_vector_type(8)));
typedef unsigned short u16x8 __attribute__((ext_vector_type(8)));
typedef float f32x4  __attribute__((ext_vector_type(4)));

__device__ inline unsigned short f2bf(float x) {
    unsigned u = __float_as_uint(x);
    return (unsigned short)((u + 0x7fff + ((u >> 16) & 1)) >> 16);
}
__device__ inline float bf2f(unsigned short h) {
    return __uint_as_float(((unsigned)h) << 16);
}

__device__ inline void gll16(const void* g, void* l) {
    __builtin_amdgcn_global_load_lds(
        (const __attribute__((address_space(1))) unsigned int*)(g),
        (__attribute__((address_space(3))) unsigned int*)(l),
        16, 0, 0);
}

// ---------------------------------------------------------------------------
// Pre-split: fp32 row-major [R][1024] -> bf16 hi/lo tiled-swizzled (unchanged)
// ---------------------------------------------------------------------------
struct SplitJob { const float* src; unsigned short* hi; unsigned short* lo; int nchunks; };
struct SplitJobs8 { SplitJob j[8]; };

__global__ __launch_bounds__(256) void presplit(SplitJobs8 jobs) {
    const SplitJob J = jobs.j[blockIdx.y];
    int g = blockIdx.x * 256 + threadIdx.x;
    if (g >= J.nchunks) return;
    int tile = g >> 9;
    int w    = g & 511;
    int r    = w >> 2;
    int cc   = w & 3;
    int mt   = tile >> 5;
    int kt   = tile & 31;
    int m    = mt * 128 + r;
    int k0   = kt * 32 + cc * 8;

    const float* s = J.src + (size_t)m * 1024 + k0;
    float4 f0 = *(const float4*)s;
    float4 f1 = *(const float4*)(s + 4);
    float vals[8] = {f0.x, f0.y, f0.z, f0.w, f1.x, f1.y, f1.z, f1.w};
    u16x8 h8, l8;
#pragma unroll
    for (int i = 0; i < 8; ++i) {
        unsigned short hv = f2bf(vals[i]);
        h8[i] = hv;
        l8[i] = f2bf(vals[i] - bf2f(hv));
    }
    int slot = cc ^ (r & 3) ^ ((r >> 2) & 3);
    size_t doff = (size_t)tile * 4096 + r * 32 + slot * 8;
    *(u16x8*)(J.hi + doff) = h8;
    *(u16x8*)(J.lo + doff) = l8;
}

// ---------------------------------------------------------------------------
// Split-bf16 MFMA GEMM (unchanged from R6, validated)
// ---------------------------------------------------------------------------
template <int MODE>
__global__ __launch_bounds__(256) void gemm_mfma(const unsigned short* __restrict__ Ahi,
                                                 const unsigned short* __restrict__ Alo,
                                                 const unsigned short* __restrict__ Bhi,
                                                 const unsigned short* __restrict__ Blo,
                                                 const float* __restrict__ bias,
                                                 float* __restrict__ C,
                                                 unsigned short* __restrict__ Chi,
                                                 unsigned short* __restrict__ Clo) {
    __shared__ unsigned short As_hi[4096], As_lo[4096], Bs_hi[4096], Bs_lo[4096];

    const int tid  = threadIdx.x;
    const int lane = tid & 63;
    const int wid  = tid >> 6;
    const int bx   = blockIdx.x;
    const int by   = blockIdx.y;
    const int wr   = wid >> 1;
    const int wc   = wid & 1;
    const int fr   = lane & 15;
    const int fg   = lane >> 4;
    const int chunk = fg ^ (fr & 3) ^ ((fr >> 2) & 3);

    f32x4 acc[4][4] = {};

    const size_t aT = (size_t)by * 32;
    const size_t bT = (size_t)bx * 32;
    const int soff  = wid * 2048 + lane * 16;

    for (int kt = 0; kt < 32; ++kt) {
        const char* at_h = (const char*)Ahi + ((aT + kt) << 13);
        const char* at_l = (const char*)Alo + ((aT + kt) << 13);
        const char* bt_h = (const char*)Bhi + ((bT + kt) << 13);
        const char* bt_l = (const char*)Blo + ((bT + kt) << 13);
        gll16(at_h + soff,        (char*)As_hi + soff);
        gll16(at_h + soff + 1024, (char*)As_hi + soff + 1024);
        gll16(at_l + soff,        (char*)As_lo + soff);
        gll16(at_l + soff + 1024, (char*)As_lo + soff + 1024);
        gll16(bt_h + soff,        (char*)Bs_hi + soff);
        gll16(bt_h + soff + 1024, (char*)Bs_hi + soff + 1024);
        gll16(bt_l + soff,        (char*)Bs_lo + soff);
        gll16(bt_l + soff + 1024, (char*)Bs_lo + soff + 1024);
        __syncthreads();

        bf16x8 ah[4], al[4], bh[4], bl[4];
#pragma unroll
        for (int mi = 0; mi < 4; ++mi) {
            int ro = (wr * 64 + mi * 16 + fr) * 64 + chunk * 16;
            ah[mi] = *(const bf16x8*)((const char*)As_hi + ro);
            al[mi] = *(const bf16x8*)((const char*)As_lo + ro);
        }
#pragma unroll
        for (int ni = 0; ni < 4; ++ni) {
            int ro = (wc * 64 + ni * 16 + fr) * 64 + chunk * 16;
            bh[ni] = *(const bf16x8*)((const char*)Bs_hi + ro);
            bl[ni] = *(const bf16x8*)((const char*)Bs_lo + ro);
        }
#pragma unroll
        for (int mi = 0; mi < 4; ++mi)
#pragma unroll
            for (int ni = 0; ni < 4; ++ni) {
                acc[mi][ni] = __builtin_amdgcn_mfma_f32_16x16x32_bf16(ah[mi], bh[ni], acc[mi][ni], 0, 0, 0);
                acc[mi][ni] = __builtin_amdgcn_mfma_f32_16x16x32_bf16(ah[mi], bl[ni], acc[mi][ni], 0, 0, 0);
                acc[mi][ni] = __builtin_amdgcn_mfma_f32_16x16x32_bf16(al[mi], bh[ni], acc[mi][ni], 0, 0, 0);
            }
        __syncthreads();
    }

#pragma unroll
    for (int ni = 0; ni < 4; ++ni) {
        int col = bx * 128 + wc * 64 + ni * 16 + fr;
        float bb = bias[col];
#pragma unroll
        for (int mi = 0; mi < 4; ++mi)
#pragma unroll
            for (int r2 = 0; r2 < 4; ++r2) {
                int row = by * 128 + wr * 64 + mi * 16 + fg * 4 + r2;
                float cv = acc[mi][ni][r2] + bb;
                if (MODE == 0) {
                    C[(size_t)row * D_MODEL + col] = cv;
                } else {
                    int bq = row >> 11, s = row & (SS - 1), h = col >> 6, d = col & 63;
                    size_t base = (((size_t)(bq * NHEAD + h) * SS + s) << 6) + d;
                    if (MODE == 1) {
                        C[base] = cv;
                    } else {
                        unsigned short hv = f2bf(cv);
                        Chi[base] = hv;
                        Clo[base] = f2bf(cv - bf2f(hv));
                    }
                }
            }
    }
}

// ---------------------------------------------------------------------------
// V transpose: vhi/vlo [bh][S][64] -> vthi/vtlo [bh][64][S]  (unchanged)
// ---------------------------------------------------------------------------
__global__ __launch_bounds__(256) void vtrans(const unsigned short* __restrict__ vhi,
                                              const unsigned short* __restrict__ vlo,
                                              unsigned short* __restrict__ vthi,
                                              unsigned short* __restrict__ vtlo) {
    __shared__ unsigned short T0[64][72], T1[64][72];
    const int tid = threadIdx.x;
    const int st  = blockIdx.x;
    const int bh  = blockIdx.y;

    {
        int row = tid >> 2;
        int c2  = (tid & 3) * 2;
        size_t src = ((size_t)bh * SS + st * 64 + row) * 64 + c2 * 8;
        u16x8 a0 = *(const u16x8*)&vhi[src];
        u16x8 a1 = *(const u16x8*)&vhi[src + 8];
        u16x8 b0 = *(const u16x8*)&vlo[src];
        u16x8 b1 = *(const u16x8*)&vlo[src + 8];
        *(u16x8*)&T0[row][c2 * 8]     = a0;
        *(u16x8*)&T0[row][c2 * 8 + 8] = a1;
        *(u16x8*)&T1[row][c2 * 8]     = b0;
        *(u16x8*)&T1[row][c2 * 8 + 8] = b1;
    }
    __syncthreads();
    {
        int d   = tid >> 2;
        int sch = tid & 3;
        u16x8 h0, h1, l0, l1;
#pragma unroll
        for (int j = 0; j < 8; ++j) {
            h0[j] = T0[sch * 16 + j][d];
            h1[j] = T0[sch * 16 + 8 + j][d];
            l0[j] = T1[sch * 16 + j][d];
            l1[j] = T1[sch * 16 + 8 + j][d];
        }
        size_t ob = ((size_t)bh * 64 + d) * SS + st * 64 + sch * 16;
        *(u16x8*)&vthi[ob]     = h0;
        *(u16x8*)&vthi[ob + 8] = h1;
        *(u16x8*)&vtlo[ob]     = l0;
        *(u16x8*)&vtlo[ob + 8] = l1;
    }
}

// ---------------------------------------------------------------------------
// MFMA flash attention v3: as v2 (512 thr, KVBLK=64, gll16 + swz source) but
// - Pbuf shrunk to [16][36]/wave, PV in two key-half phases  -> LDS 50KB,
//   3 blocks/CU
// - s_setprio(1) around MFMA clusters (T5)
// - mask read directly from global (no LDS staging)
// - epilogue writes ctx directly as split bf16 in the tiled-swizzled GEMM
//   layout (kills the ctx presplit pass). Math identical to v2.
// ---------------------------------------------------------------------------
__global__ __launch_bounds__(512) void attn_mfma3(const float* __restrict__ Qp,
                                                  const unsigned short* __restrict__ Khig,
                                                  const unsigned short* __restrict__ Klog,
                                                  const unsigned short* __restrict__ VThig,
                                                  const unsigned short* __restrict__ VTlog,
                                                  const int* __restrict__ mask,
                                                  unsigned short* __restrict__ Ach,
                                                  unsigned short* __restrict__ Acl) {
    __shared__ unsigned short KsH[4096], KsL[4096];   // [64 key][64 d], slot-swz
    __shared__ unsigned short VsH[4096], VsL[4096];   // [64 d][64 key], slot-swz
    __shared__ float Pbuf[8][16 * 36];                // per-wave, 16 q x 32 keys (half)

    const int tid  = threadIdx.x;
    const int lane = tid & 63;
    const int wid  = tid >> 6;

    const int bid = blockIdx.x;
    const int swz = (bid & 7) * 128 + (bid >> 3);
    const int qt  = swz & 15;
    const int bh  = swz >> 4;
    const int b   = bh >> 4;
    const int h   = bh & 15;

    const int q0  = qt * 128;
    const int wq0 = wid * 16;

    const int fr = lane & 15;
    const int fg = lane >> 4;

    const float* qbase = Qp + ((size_t)bh * SS + q0 + wq0) * DK;
    const unsigned short* khb = Khig + (size_t)bh * SS * DK;
    const unsigned short* klb = Klog + (size_t)bh * SS * DK;
    const unsigned short* vhb = VThig + (size_t)bh * DK * SS;
    const unsigned short* vlb = VTlog + (size_t)bh * DK * SS;
    const int* mrow = mask + b * SS;

    // Q fragments, pre-scaled 1/8
    bf16x8 qh[2], ql[2];
#pragma unroll
    for (int kb = 0; kb < 2; ++kb) {
        const float* p = qbase + (size_t)fr * DK + kb * 32 + fg * 8;
        float4 a  = *(const float4*)p;
        float4 b4 = *(const float4*)(p + 4);
        float vals[8] = {a.x, a.y, a.z, a.w, b4.x, b4.y, b4.z, b4.w};
#pragma unroll
        for (int i = 0; i < 8; ++i) {
            float s = vals[i] * 0.125f;
            unsigned short hi = f2bf(s);
            qh[kb][i] = (short)hi;
            ql[kb][i] = (short)f2bf(s - bf2f(hi));
        }
    }

    f32x4 O[4] = {};
    float m_run[4], l_run[4];
#pragma unroll
    for (int r = 0; r < 4; ++r) { m_run[r] = -3.0e38f; l_run[r] = 0.f; }

    const int srow = tid >> 3;
    const int ssl  = tid & 7;
    const int sch  = ssl ^ (srow & 7);
    const int ldsb = tid * 8;

    const int sl0 = ((0 + fg) ^ (fr & 7)) * 8;
    const int sl1 = ((4 + fg) ^ (fr & 7)) * 8;

    float* pw = Pbuf[wid];

    for (int t = 0; t < SS / 64; ++t) {
        const int kv0 = t * 64;

        __syncthreads();   // previous tile's LDS reads complete
        gll16(&khb[(size_t)(kv0 + srow) * 64 + sch * 8], &KsH[ldsb]);
        gll16(&klb[(size_t)(kv0 + srow) * 64 + sch * 8], &KsL[ldsb]);
        gll16(&vhb[(size_t)srow * SS + kv0 + sch * 8],   &VsH[ldsb]);
        gll16(&vlb[(size_t)srow * SS + kv0 + sch * 8],   &VsL[ldsb]);
        // mask values straight from global (L2-resident)
        int mv[4];
#pragma unroll
        for (int kyb = 0; kyb < 4; ++kyb) mv[kyb] = mrow[kv0 + kyb * 16 + fr];
        __syncthreads();   // staging drained

        // --- QK^T
        f32x4 acc[4] = {};
        __builtin_amdgcn_s_setprio(1);
#pragma unroll
        for (int kyb = 0; kyb < 4; ++kyb) {
            const int rb = (kyb * 16 + fr) * 64;
            {
                bf16x8 kh = *(const bf16x8*)&KsH[rb + sl0];
                bf16x8 kl = *(const bf16x8*)&KsL[rb + sl0];
                acc[kyb] = __builtin_amdgcn_mfma_f32_16x16x32_bf16(qh[0], kh, acc[kyb], 0, 0, 0);
                acc[kyb] = __builtin_amdgcn_mfma_f32_16x16x32_bf16(qh[0], kl, acc[kyb], 0, 0, 0);
                acc[kyb] = __builtin_amdgcn_mfma_f32_16x16x32_bf16(ql[0], kh, acc[kyb], 0, 0, 0);
            }
            {
                bf16x8 kh = *(const bf16x8*)&KsH[rb + sl1];
                bf16x8 kl = *(const bf16x8*)&KsL[rb + sl1];
                acc[kyb] = __builtin_amdgcn_mfma_f32_16x16x32_bf16(qh[1], kh, acc[kyb], 0, 0, 0);
                acc[kyb] = __builtin_amdgcn_mfma_f32_16x16x32_bf16(qh[1], kl, acc[kyb], 0, 0, 0);
                acc[kyb] = __builtin_amdgcn_mfma_f32_16x16x32_bf16(ql[1], kh, acc[kyb], 0, 0, 0);
            }
        }
        __builtin_amdgcn_s_setprio(0);

        // --- mask + online softmax
        float sc[4][4];
#pragma unroll
        for (int kyb = 0; kyb < 4; ++kyb)
#pragma unroll
            for (int r = 0; r < 4; ++r)
                sc[kyb][r] = mv[kyb] ? acc[kyb][r] : -1.0e9f;

        float scale[4], p[4][4];
#pragma unroll
        for (int r = 0; r < 4; ++r) {
            float v = fmaxf(fmaxf(sc[0][r], sc[1][r]), fmaxf(sc[2][r], sc[3][r]));
            v = fmaxf(v, __shfl_xor(v, 1));
            v = fmaxf(v, __shfl_xor(v, 2));
            v = fmaxf(v, __shfl_xor(v, 4));
            v = fmaxf(v, __shfl_xor(v, 8));
            float m_new = fmaxf(m_run[r], v);
            scale[r] = __expf(m_run[r] - m_new);
            m_run[r] = m_new;
            float s = 0.f;
#pragma unroll
            for (int kyb = 0; kyb < 4; ++kyb) {
                p[kyb][r] = __expf(sc[kyb][r] - m_new);
                s += p[kyb][r];
            }
            s += __shfl_xor(s, 1);
            s += __shfl_xor(s, 2);
            s += __shfl_xor(s, 4);
            s += __shfl_xor(s, 8);
            l_run[r] = l_run[r] * scale[r] + s;
        }

        // O rescale once per tile (before both PV halves)
#pragma unroll
        for (int db = 0; db < 4; ++db)
#pragma unroll
            for (int r = 0; r < 4; ++r)
                O[db][r] *= scale[r];

        // --- two PV half-phases over key halves (reuse small Pbuf)
#pragma unroll
        for (int ph2 = 0; ph2 < 2; ++ph2) {
            // transpose this half's P (wave-private)
#pragma unroll
            for (int kyb2 = 0; kyb2 < 2; ++kyb2)
#pragma unroll
                for (int r = 0; r < 4; ++r)
                    pw[(fg * 4 + r) * 36 + kyb2 * 16 + fr] = p[ph2 * 2 + kyb2][r];

            asm volatile("s_waitcnt lgkmcnt(0)" ::: "memory");
            __builtin_amdgcn_sched_barrier(0);

            bf16x8 ph8, pl8;
            {
                const float* prd = &pw[fr * 36 + fg * 8];
                float4 p0 = *(const float4*)&prd[0];
                float4 p1 = *(const float4*)&prd[4];
                float vals[8] = {p0.x, p0.y, p0.z, p0.w, p1.x, p1.y, p1.z, p1.w};
#pragma unroll
                for (int i = 0; i < 8; ++i) {
                    unsigned short hi = f2bf(vals[i]);
                    ph8[i] = (short)hi;
                    pl8[i] = (short)f2bf(vals[i] - bf2f(hi));
                }
            }

            const int sl = ((ph2 * 4 + fg) ^ (fr & 7)) * 8;
            __builtin_amdgcn_s_setprio(1);
#pragma unroll
            for (int db = 0; db < 4; ++db) {
                const int rb = (db * 16 + fr) * 64;
                bf16x8 vh = *(const bf16x8*)&VsH[rb + sl];
                bf16x8 vl = *(const bf16x8*)&VsL[rb + sl];
                O[db] = __builtin_amdgcn_mfma_f32_16x16x32_bf16(ph8, vh, O[db], 0, 0, 0);
                O[db] = __builtin_amdgcn_mfma_f32_16x16x32_bf16(ph8, vl, O[db], 0, 0, 0);
                O[db] = __builtin_amdgcn_mfma_f32_16x16x32_bf16(pl8, vh, O[db], 0, 0, 0);
            }
            __builtin_amdgcn_s_setprio(0);

            // WAR fence: this half's Pbuf reads retired before next half's writes
            asm volatile("s_waitcnt lgkmcnt(0)" ::: "memory");
            __builtin_amdgcn_sched_barrier(0);
        }
    }

    // --- epilogue: write O directly as split bf16 in tiled-swizzled layout
#pragma unroll
    for (int r = 0; r < 4; ++r) {
        float inv = 1.0f / l_run[r];
        int m  = b * SS + q0 + wq0 + fg * 4 + r;
        int rt = m & 127;
        int mt = m >> 7;
        int rx = (rt & 3) ^ ((rt >> 2) & 3);
#pragma unroll
        for (int db = 0; db < 4; ++db) {
            float val = O[db][r] * inv;
            int kcol = h * 64 + db * 16 + fr;
            int tile = mt * 32 + (kcol >> 5);
            int slot = (((kcol >> 3) & 3)) ^ rx;
            size_t doff = (size_t)tile * 4096 + rt * 32 + slot * 8 + (kcol & 7);
            unsigned short hv = f2bf(val);
            Ach[doff] = hv;
            Acl[doff] = f2bf(val - bf2f(hv));
        }
    }
}

// ---------------------------------------------------------------------------
// fp32 GEMM + old attention (fallback path, unchanged/validated)
// ---------------------------------------------------------------------------
template <int MODE>
__global__ __launch_bounds__(256) void gemm_xwT(const float* __restrict__ A,
                                                const float* __restrict__ W,
                                                const float* __restrict__ bias,
                                                float* __restrict__ C,
                                                unsigned short* __restrict__ Chi,
                                                unsigned short* __restrict__ Clo,
                                                int M, int N, int K) {
    __shared__ float As[8][132];
    __shared__ float Bs[8][132];

    const int tid = threadIdx.x;
    const int tx  = tid & 15;
    const int ty  = tid >> 4;
    const int m0  = blockIdx.y * 128;
    const int n0  = blockIdx.x * 128;

    const int lr = tid >> 1;
    const int lk = (tid & 1) * 4;

    float acc[8][8];
#pragma unroll
    for (int i = 0; i < 8; ++i)
#pragma unroll
        for (int j = 0; j < 8; ++j) acc[i][j] = 0.f;

    for (int kt = 0; kt < K; kt += 8) {
        float4 av = *(const float4*)&A[(size_t)(m0 + lr) * K + kt + lk];
        float4 wv = *(const float4*)&W[(size_t)(n0 + lr) * K + kt + lk];
        __syncthreads();
        As[lk + 0][lr] = av.x; As[lk + 1][lr] = av.y;
        As[lk + 2][lr] = av.z; As[lk + 3][lr] = av.w;
        Bs[lk + 0][lr] = wv.x; Bs[lk + 1][lr] = wv.y;
        Bs[lk + 2][lr] = wv.z; Bs[lk + 3][lr] = wv.w;
        __syncthreads();
#pragma unroll
        for (int k = 0; k < 8; ++k) {
            float4 a0 = *(const float4*)&As[k][ty * 8];
            float4 a1 = *(const float4*)&As[k][ty * 8 + 4];
            float4 b0 = *(const float4*)&Bs[k][tx * 8];
            float4 b1 = *(const float4*)&Bs[k][tx * 8 + 4];
            float a[8] = {a0.x, a0.y, a0.z, a0.w, a1.x, a1.y, a1.z, a1.w};
            float b[8] = {b0.x, b0.y, b0.z, b0.w, b1.x, b1.y, b1.z, b1.w};
#pragma unroll
            for (int i = 0; i < 8; ++i)
#pragma unroll
                for (int j = 0; j < 8; ++j) acc[i][j] += a[i] * b[j];
        }
    }

    float bb[8];
#pragma unroll
    for (int j = 0; j < 8; ++j) bb[j] = bias[n0 + tx * 8 + j];

#pragma unroll
    for (int i = 0; i < 8; ++i) {
        int m = m0 + ty * 8 + i;
        int n = n0 + tx * 8;
        float cv[8];
#pragma unroll
        for (int j = 0; j < 8; ++j) cv[j] = acc[i][j] + bb[j];

        if (MODE == 0) {
            float* dst = &C[(size_t)m * N + n];
            *(float4*)&dst[0] = {cv[0], cv[1], cv[2], cv[3]};
            *(float4*)&dst[4] = {cv[4], cv[5], cv[6], cv[7]};
        } else {
            int bq = m >> 11;
            int s  = m & (SS - 1);
            int h  = n >> 6;
            int d  = n & 63;
            size_t base = (((size_t)(bq * NHEAD + h) * SS + s) << 6) + d;
            if (MODE == 1) {
                float* dst = &C[base];
                *(float4*)&dst[0] = {cv[0], cv[1], cv[2], cv[3]};
                *(float4*)&dst[4] = {cv[4], cv[5], cv[6], cv[7]};
            } else {
                u16x8 h8, l8;
#pragma unroll
                for (int j = 0; j < 8; ++j) {
                    unsigned short hv = f2bf(cv[j]);
                    h8[j] = hv;
                    l8[j] = f2bf(cv[j] - bf2f(hv));
                }
                *(u16x8*)&Chi[base] = h8;
                *(u16x8*)&Clo[base] = l8;
            }
        }
    }
}

__global__ __launch_bounds__(256) void attn_mfma(const float* __restrict__ Qp,
                                                 const unsigned short* __restrict__ Khig,
                                                 const unsigned short* __restrict__ Klog,
                                                 const unsigned short* __restrict__ Vhig,
                                                 const unsigned short* __restrict__ Vlog,
                                                 const int* __restrict__ mask,
                                                 float* __restrict__ ctx) {
    __shared__ short Khi[32 * 72], Klo[32 * 72];
    __shared__ short Vhi[64 * 40], Vlo[64 * 40];
    __shared__ float Pbuf[4][16 * 36];
    __shared__ int   msk[32];

    const int tid  = threadIdx.x;
    const int lane = tid & 63;
    const int wid  = tid >> 6;

    const int bid = blockIdx.x;
    const int swz = (bid & 7) * 256 + (bid >> 3);
    const int qt  = swz & 31;
    const int bh  = swz >> 5;
    const int b   = bh >> 4;
    const int h   = bh & 15;

    const int q0  = qt * 64;
    const int wq0 = wid * 16;

    const int fr = lane & 15;
    const int fg = lane >> 4;

    const float* qbase = Qp + ((size_t)bh * SS + q0 + wq0) * DK;
    const unsigned short* khbase = Khig + (size_t)bh * SS * DK;
    const unsigned short* klbase = Klog + (size_t)bh * SS * DK;
    const unsigned short* vhbase = Vhig + (size_t)bh * SS * DK;
    const unsigned short* vlbase = Vlog + (size_t)bh * SS * DK;
    const int* mrow = mask + b * SS;

    bf16x8 qh[2], ql[2];
#pragma unroll
    for (int kb = 0; kb < 2; ++kb) {
        const float* p = qbase + (size_t)fr * DK + kb * 32 + fg * 8;
        float4 a  = *(const float4*)p;
        float4 b4 = *(const float4*)(p + 4);
        float vals[8] = {a.x, a.y, a.z, a.w, b4.x, b4.y, b4.z, b4.w};
#pragma unroll
        for (int i = 0; i < 8; ++i) {
            float s = vals[i] * 0.125f;
            unsigned short hi = f2bf(s);
            qh[kb][i] = (short)hi;
            ql[kb][i] = (short)f2bf(s - bf2f(hi));
        }
    }

    f32x4 O[4] = {};
    float m_run[4], l_run[4];
#pragma unroll
    for (int r = 0; r < 4; ++r) { m_run[r] = -3.0e38f; l_run[r] = 0.f; }

    const int sk_k = tid >> 3;
    const int sk_d = (tid & 7) * 8;
    const int sv_d = tid & 63;
    const int sv_k = (tid >> 6) * 8;

    for (int t = 0; t < SS / 32; ++t) {
        const int kv0 = t * 32;

        size_t koff = (size_t)(kv0 + sk_k) * DK + sk_d;
        u16x8 kh8 = *(const u16x8*)&khbase[koff];
        u16x8 kl8 = *(const u16x8*)&klbase[koff];
        unsigned short vh[8], vl[8];
#pragma unroll
        for (int j = 0; j < 8; ++j) {
            size_t voff = (size_t)(kv0 + sv_k + j) * DK + sv_d;
            vh[j] = vhbase[voff];
            vl[j] = vlbase[voff];
        }
        int mval = (tid < 32) ? mrow[kv0 + tid] : 0;

        __syncthreads();
        *(u16x8*)&Khi[sk_k * 72 + sk_d] = kh8;
        *(u16x8*)&Klo[sk_k * 72 + sk_d] = kl8;
        {
            u16x8 h8, l8;
#pragma unroll
            for (int j = 0; j < 8; ++j) { h8[j] = vh[j]; l8[j] = vl[j]; }
            *(u16x8*)&Vhi[sv_d * 40 + sv_k] = h8;
            *(u16x8*)&Vlo[sv_d * 40 + sv_k] = l8;
        }
        if (tid < 32) msk[tid] = mval;
        __syncthreads();

        f32x4 acc[2] = {};
#pragma unroll
        for (int kyb = 0; kyb < 2; ++kyb) {
#pragma unroll
            for (int kb = 0; kb < 2; ++kb) {
                int idx = (kyb * 16 + fr) * 72 + kb * 32 + fg * 8;
                bf16x8 kh = *(const bf16x8*)&Khi[idx];
                bf16x8 kl = *(const bf16x8*)&Klo[idx];
                acc[kyb] = __builtin_amdgcn_mfma_f32_16x16x32_bf16(qh[kb], kh, acc[kyb], 0, 0, 0);
                acc[kyb] = __builtin_amdgcn_mfma_f32_16x16x32_bf16(qh[kb], kl, acc[kyb], 0, 0, 0);
                acc[kyb] = __builtin_amdgcn_mfma_f32_16x16x32_bf16(ql[kb], kh, acc[kyb], 0, 0, 0);
            }
        }

        float sc[2][4];
#pragma unroll
        for (int kyb = 0; kyb < 2; ++kyb) {
            int mv = msk[kyb * 16 + fr];
#pragma unroll
            for (int r = 0; r < 4; ++r)
                sc[kyb][r] = mv ? acc[kyb][r] : -1.0e9f;
        }
        float scale[4], p[2][4];
#pragma unroll
        for (int r = 0; r < 4; ++r) {
            float v = fmaxf(sc[0][r], sc[1][r]);
            v = fmaxf(v, __shfl_xor(v, 1));
            v = fmaxf(v, __shfl_xor(v, 2));
            v = fmaxf(v, __shfl_xor(v, 4));
            v = fmaxf(v, __shfl_xor(v, 8));
            float m_new = fmaxf(m_run[r], v);
            scale[r] = __expf(m_run[r] - m_new);
            m_run[r] = m_new;
            p[0][r] = __expf(sc[0][r] - m_new);
            p[1][r] = __expf(sc[1][r] - m_new);
            float s = p[0][r] + p[1][r];
            s += __shfl_xor(s, 1);
            s += __shfl_xor(s, 2);
            s += __shfl_xor(s, 4);
            s += __shfl_xor(s, 8);
            l_run[r] = l_run[r] * scale[r] + s;
        }

        float* pw = Pbuf[wid];
#pragma unroll
        for (int r = 0; r < 4; ++r) {
            pw[(fg * 4 + r) * 36 + fr]      = p[0][r];
            pw[(fg * 4 + r) * 36 + 16 + fr] = p[1][r];
        }
#pragma unroll
        for (int db = 0; db < 4; ++db)
#pragma unroll
            for (int r = 0; r < 4; ++r)
                O[db][r] *= scale[r];

        __syncthreads();

        float pr[8];
        {
            const float* prd = &pw[fr * 36 + fg * 8];
            *(float4*)&pr[0] = *(const float4*)&prd[0];
            *(float4*)&pr[4] = *(const float4*)&prd[4];
        }
        bf16x8 ph8, pl8;
#pragma unroll
        for (int i = 0; i < 8; ++i) {
            unsigned short hi = f2bf(pr[i]);
            ph8[i] = (short)hi;
            pl8[i] = (short)f2bf(pr[i] - bf2f(hi));
        }

#pragma unroll
        for (int db = 0; db < 4; ++db) {
            int idx = (db * 16 + fr) * 40 + fg * 8;
            bf16x8 vh8 = *(const bf16x8*)&Vhi[idx];
            bf16x8 vl8 = *(const bf16x8*)&Vlo[idx];
            O[db] = __builtin_amdgcn_mfma_f32_16x16x32_bf16(ph8, vh8, O[db], 0, 0, 0);
            O[db] = __builtin_amdgcn_mfma_f32_16x16x32_bf16(ph8, vl8, O[db], 0, 0, 0);
            O[db] = __builtin_amdgcn_mfma_f32_16x16x32_bf16(pl8, vh8, O[db], 0, 0, 0);
        }
    }

    float* cbase = ctx + ((size_t)b * SS + q0 + wq0) * D_MODEL + h * DK;
#pragma unroll
    for (int r = 0; r < 4; ++r) {
        float inv = 1.0f / l_run[r];
        int q = fg * 4 + r;
#pragma unroll
        for (int db = 0; db < 4; ++db)
            cbase[(size_t)q * D_MODEL + db * 16 + fr] = O[db][r] * inv;
    }
}

// ---------------------------------------------------------------------------
extern "C" void kernel_launch(void* const* d_in, const int* in_sizes, int n_in,
                              void* d_out, int out_size, void* d_ws, size_t ws_size,
                              hipStream_t stream) {
    const float* q    = (const float*)d_in[0];
    const float* k    = (const float*)d_in[1];
    const float* v    = (const float*)d_in[2];
    const int*   mask = (const int*)d_in[3];
    const float* w_q  = (const float*)d_in[4];
    const float* b_q  = (const float*)d_in[5];
    const float* w_k  = (const float*)d_in[6];
    const float* b_k  = (const float*)d_in[7];
    const float* w_v  = (const float*)d_in[8];
    const float* b_v  = (const float*)d_in[9];
    const float* w_o  = (const float*)d_in[10];
    const float* b_o  = (const float*)d_in[11];
    float* out = (float*)d_out;

    const int M = BB * SS;
    const size_t PSZ = (size_t)M * D_MODEL;
    const size_t NEED = (size_t)208 << 20;
    char* w = (char*)d_ws;
    dim3 block(256);

    if (ws_size >= NEED) {
        float* qp            = (float*)(w);
        unsigned short* khi  = (unsigned short*)(w + ((size_t)32 << 20));
        unsigned short* klo  = (unsigned short*)(w + ((size_t)48 << 20));
        unsigned short* vhi  = (unsigned short*)(w + ((size_t)64 << 20));
        unsigned short* vlo  = (unsigned short*)(w + ((size_t)80 << 20));
        unsigned short* Aq_h = (unsigned short*)(w + ((size_t)96 << 20));
        unsigned short* Aq_l = (unsigned short*)(w + ((size_t)112 << 20));
        unsigned short* Ak_h = (unsigned short*)(w + ((size_t)128 << 20));
        unsigned short* Ak_l = (unsigned short*)(w + ((size_t)144 << 20));
        unsigned short* Av_h = (unsigned short*)(w + ((size_t)160 << 20));
        unsigned short* Av_l = (unsigned short*)(w + ((size_t)176 << 20));
        unsigned short* vthi = (unsigned short*)(w + ((size_t)160 << 20)); // alias Av_h (dead post V-GEMM)
        unsigned short* vtlo = (unsigned short*)(w + ((size_t)176 << 20)); // alias Av_l
        unsigned short* Wq_h = (unsigned short*)(w + ((size_t)192 << 20));
        unsigned short* Wq_l = (unsigned short*)(w + ((size_t)194 << 20));
        unsigned short* Wk_h = (unsigned short*)(w + ((size_t)196 << 20));
        unsigned short* Wk_l = (unsigned short*)(w + ((size_t)198 << 20));
        unsigned short* Wv_h = (unsigned short*)(w + ((size_t)200 << 20));
        unsigned short* Wv_l = (unsigned short*)(w + ((size_t)202 << 20));
        unsigned short* Wo_h = (unsigned short*)(w + ((size_t)204 << 20));
        unsigned short* Wo_l = (unsigned short*)(w + ((size_t)206 << 20));
        unsigned short* Ac_h = Ak_h;   // attn writes ctx-split here (Ak dead post K-GEMM inputs)
        unsigned short* Ac_l = Ak_l;

        const int ACT_CHUNKS = M * 128;
        const int W_CHUNKS   = 1024 * 128;

        SplitJobs8 J{};
        J.j[0] = {q,   Aq_h, Aq_l, ACT_CHUNKS};
        J.j[1] = {k,   Ak_h, Ak_l, ACT_CHUNKS};
        J.j[2] = {v,   Av_h, Av_l, ACT_CHUNKS};
        J.j[3] = {w_q, Wq_h, Wq_l, W_CHUNKS};
        J.j[4] = {w_k, Wk_h, Wk_l, W_CHUNKS};
        J.j[5] = {w_v, Wv_h, Wv_l, W_CHUNKS};
        J.j[6] = {w_o, Wo_h, Wo_l, W_CHUNKS};
        presplit<<<dim3(4096, 7), block, 0, stream>>>(J);

        dim3 ggrid(D_MODEL / 128, M / 128);
        gemm_mfma<1><<<ggrid, block, 0, stream>>>(Aq_h, Aq_l, Wq_h, Wq_l, b_q, qp, nullptr, nullptr);
        gemm_mfma<2><<<ggrid, block, 0, stream>>>(Ak_h, Ak_l, Wk_h, Wk_l, b_k, nullptr, khi, klo);
        gemm_mfma<2><<<ggrid, block, 0, stream>>>(Av_h, Av_l, Wv_h, Wv_l, b_v, nullptr, vhi, vlo);

        vtrans<<<dim3(SS / 64, BB * NHEAD), block, 0, stream>>>(vhi, vlo, vthi, vtlo);

        attn_mfma3<<<dim3(BB * NHEAD * (SS / 128)), dim3(512), 0, stream>>>(
            qp, khi, klo, vthi, vtlo, mask, Ac_h, Ac_l);

        gemm_mfma<0><<<ggrid, block, 0, stream>>>(Ac_h, Ac_l, Wo_h, Wo_l, b_o, out, nullptr, nullptr);
    } else {
        float* qp           = (float*)d_ws;
        unsigned short* khi = (unsigned short*)(qp + PSZ);
        unsigned short* klo = khi + PSZ;
        unsigned short* vhi = klo + PSZ;
        unsigned short* vlo = vhi + PSZ;
        float* ctx          = (float*)(vlo + PSZ);

        dim3 grid(D_MODEL / 128, M / 128);
        gemm_xwT<1><<<grid, block, 0, stream>>>(q, w_q, b_q, qp, nullptr, nullptr, M, D_MODEL, D_MODEL);
        gemm_xwT<2><<<grid, block, 0, stream>>>(k, w_k, b_k, nullptr, khi, klo, M, D_MODEL, D_MODEL);
        gemm_xwT<2><<<grid, block, 0, stream>>>(v, w_v, b_v, nullptr, vhi, vlo, M, D_MODEL, D_MODEL);
        attn_mfma<<<dim3(BB * NHEAD * (SS / 64)), block, 0, stream>>>(qp, khi, klo, vhi, vlo, mask, ctx);
        gemm_xwT<0><<<grid, block, 0, stream>>>(ctx, w_o, b_o, out, nullptr, nullptr, M, D_MODEL, D_MODEL);
    }
}

// Round 9
// 513.683 us; speedup vs baseline: 5.6332x; 1.0634x over previous
//
#include <hip/hip_runtime.h>
#include <stdint.h>

#define D_MODEL 1024
#define NHEAD   16
#define DK      64
#define SS      2048
#define BB      4

typedef short bf16x8 __attribute__((ext_vector_type(8)));
typedef unsigned short u16x8 __attribute__((ext_vector_type(8)));
typedef float f32x4  __attribute__((ext_vector_type(4)));
typedef unsigned int u32x4 __attribute__((ext_vector_type(4)));

__device__ inline unsigned short f2bf(float x) {
    unsigned u = __float_as_uint(x);
    return (unsigned short)((u + 0x7fff + ((u >> 16) & 1)) >> 16);
}
__device__ inline float bf2f(unsigned short h) {
    return __uint_as_float(((unsigned)h) << 16);
}
// packed bf16 convert: low16 = cvt(a), high16 = cvt(b)  (RNE, same as f2bf)
__device__ inline unsigned pk2(float a, float b) {
    unsigned r;
    asm("v_cvt_pk_bf16_f32 %0, %1, %2" : "=v"(r) : "v"(a), "v"(b));
    return r;
}

__device__ inline void gll16(const void* g, void* l) {
    __builtin_amdgcn_global_load_lds(
        (const __attribute__((address_space(1))) unsigned int*)(g),
        (__attribute__((address_space(3))) unsigned int*)(l),
        16, 0, 0);
}

// ---------------------------------------------------------------------------
// Pre-split: fp32 row-major [R][1024] -> bf16 hi/lo tiled-swizzled (unchanged)
// ---------------------------------------------------------------------------
struct SplitJob { const float* src; unsigned short* hi; unsigned short* lo; int nchunks; };
struct SplitJobs8 { SplitJob j[8]; };

__global__ __launch_bounds__(256) void presplit(SplitJobs8 jobs) {
    const SplitJob J = jobs.j[blockIdx.y];
    int g = blockIdx.x * 256 + threadIdx.x;
    if (g >= J.nchunks) return;
    int tile = g >> 9;
    int w    = g & 511;
    int r    = w >> 2;
    int cc   = w & 3;
    int mt   = tile >> 5;
    int kt   = tile & 31;
    int m    = mt * 128 + r;
    int k0   = kt * 32 + cc * 8;

    const float* s = J.src + (size_t)m * 1024 + k0;
    float4 f0 = *(const float4*)s;
    float4 f1 = *(const float4*)(s + 4);
    float vals[8] = {f0.x, f0.y, f0.z, f0.w, f1.x, f1.y, f1.z, f1.w};
    u16x8 h8, l8;
#pragma unroll
    for (int i = 0; i < 8; ++i) {
        unsigned short hv = f2bf(vals[i]);
        h8[i] = hv;
        l8[i] = f2bf(vals[i] - bf2f(hv));
    }
    int slot = cc ^ (r & 3) ^ ((r >> 2) & 3);
    size_t doff = (size_t)tile * 4096 + r * 32 + slot * 8;
    *(u16x8*)(J.hi + doff) = h8;
    *(u16x8*)(J.lo + doff) = l8;
}

// ---------------------------------------------------------------------------
// Split-bf16 MFMA GEMM (unchanged from R6, validated)
// ---------------------------------------------------------------------------
template <int MODE>
__global__ __launch_bounds__(256) void gemm_mfma(const unsigned short* __restrict__ Ahi,
                                                 const unsigned short* __restrict__ Alo,
                                                 const unsigned short* __restrict__ Bhi,
                                                 const unsigned short* __restrict__ Blo,
                                                 const float* __restrict__ bias,
                                                 float* __restrict__ C,
                                                 unsigned short* __restrict__ Chi,
                                                 unsigned short* __restrict__ Clo) {
    __shared__ unsigned short As_hi[4096], As_lo[4096], Bs_hi[4096], Bs_lo[4096];

    const int tid  = threadIdx.x;
    const int lane = tid & 63;
    const int wid  = tid >> 6;
    const int bx   = blockIdx.x;
    const int by   = blockIdx.y;
    const int wr   = wid >> 1;
    const int wc   = wid & 1;
    const int fr   = lane & 15;
    const int fg   = lane >> 4;
    const int chunk = fg ^ (fr & 3) ^ ((fr >> 2) & 3);

    f32x4 acc[4][4] = {};

    const size_t aT = (size_t)by * 32;
    const size_t bT = (size_t)bx * 32;
    const int soff  = wid * 2048 + lane * 16;

    for (int kt = 0; kt < 32; ++kt) {
        const char* at_h = (const char*)Ahi + ((aT + kt) << 13);
        const char* at_l = (const char*)Alo + ((aT + kt) << 13);
        const char* bt_h = (const char*)Bhi + ((bT + kt) << 13);
        const char* bt_l = (const char*)Blo + ((bT + kt) << 13);
        gll16(at_h + soff,        (char*)As_hi + soff);
        gll16(at_h + soff + 1024, (char*)As_hi + soff + 1024);
        gll16(at_l + soff,        (char*)As_lo + soff);
        gll16(at_l + soff + 1024, (char*)As_lo + soff + 1024);
        gll16(bt_h + soff,        (char*)Bs_hi + soff);
        gll16(bt_h + soff + 1024, (char*)Bs_hi + soff + 1024);
        gll16(bt_l + soff,        (char*)Bs_lo + soff);
        gll16(bt_l + soff + 1024, (char*)Bs_lo + soff + 1024);
        __syncthreads();

        bf16x8 ah[4], al[4], bh[4], bl[4];
#pragma unroll
        for (int mi = 0; mi < 4; ++mi) {
            int ro = (wr * 64 + mi * 16 + fr) * 64 + chunk * 16;
            ah[mi] = *(const bf16x8*)((const char*)As_hi + ro);
            al[mi] = *(const bf16x8*)((const char*)As_lo + ro);
        }
#pragma unroll
        for (int ni = 0; ni < 4; ++ni) {
            int ro = (wc * 64 + ni * 16 + fr) * 64 + chunk * 16;
            bh[ni] = *(const bf16x8*)((const char*)Bs_hi + ro);
            bl[ni] = *(const bf16x8*)((const char*)Bs_lo + ro);
        }
#pragma unroll
        for (int mi = 0; mi < 4; ++mi)
#pragma unroll
            for (int ni = 0; ni < 4; ++ni) {
                acc[mi][ni] = __builtin_amdgcn_mfma_f32_16x16x32_bf16(ah[mi], bh[ni], acc[mi][ni], 0, 0, 0);
                acc[mi][ni] = __builtin_amdgcn_mfma_f32_16x16x32_bf16(ah[mi], bl[ni], acc[mi][ni], 0, 0, 0);
                acc[mi][ni] = __builtin_amdgcn_mfma_f32_16x16x32_bf16(al[mi], bh[ni], acc[mi][ni], 0, 0, 0);
            }
        __syncthreads();
    }

#pragma unroll
    for (int ni = 0; ni < 4; ++ni) {
        int col = bx * 128 + wc * 64 + ni * 16 + fr;
        float bb = bias[col];
#pragma unroll
        for (int mi = 0; mi < 4; ++mi)
#pragma unroll
            for (int r2 = 0; r2 < 4; ++r2) {
                int row = by * 128 + wr * 64 + mi * 16 + fg * 4 + r2;
                float cv = acc[mi][ni][r2] + bb;
                if (MODE == 0) {
                    C[(size_t)row * D_MODEL + col] = cv;
                } else {
                    int bq = row >> 11, s = row & (SS - 1), h = col >> 6, d = col & 63;
                    size_t base = (((size_t)(bq * NHEAD + h) * SS + s) << 6) + d;
                    if (MODE == 1) {
                        C[base] = cv;
                    } else {
                        unsigned short hv = f2bf(cv);
                        Chi[base] = hv;
                        Clo[base] = f2bf(cv - bf2f(hv));
                    }
                }
            }
    }
}

// ---------------------------------------------------------------------------
// V transpose: vhi/vlo [bh][S][64] -> vthi/vtlo [bh][64][S]  (unchanged)
// ---------------------------------------------------------------------------
__global__ __launch_bounds__(256) void vtrans(const unsigned short* __restrict__ vhi,
                                              const unsigned short* __restrict__ vlo,
                                              unsigned short* __restrict__ vthi,
                                              unsigned short* __restrict__ vtlo) {
    __shared__ unsigned short T0[64][72], T1[64][72];
    const int tid = threadIdx.x;
    const int st  = blockIdx.x;
    const int bh  = blockIdx.y;

    {
        int row = tid >> 2;
        int c2  = (tid & 3) * 2;
        size_t src = ((size_t)bh * SS + st * 64 + row) * 64 + c2 * 8;
        u16x8 a0 = *(const u16x8*)&vhi[src];
        u16x8 a1 = *(const u16x8*)&vhi[src + 8];
        u16x8 b0 = *(const u16x8*)&vlo[src];
        u16x8 b1 = *(const u16x8*)&vlo[src + 8];
        *(u16x8*)&T0[row][c2 * 8]     = a0;
        *(u16x8*)&T0[row][c2 * 8 + 8] = a1;
        *(u16x8*)&T1[row][c2 * 8]     = b0;
        *(u16x8*)&T1[row][c2 * 8 + 8] = b1;
    }
    __syncthreads();
    {
        int d   = tid >> 2;
        int sch = tid & 3;
        u16x8 h0, h1, l0, l1;
#pragma unroll
        for (int j = 0; j < 8; ++j) {
            h0[j] = T0[sch * 16 + j][d];
            h1[j] = T0[sch * 16 + 8 + j][d];
            l0[j] = T1[sch * 16 + j][d];
            l1[j] = T1[sch * 16 + 8 + j][d];
        }
        size_t ob = ((size_t)bh * 64 + d) * SS + st * 64 + sch * 16;
        *(u16x8*)&vthi[ob]     = h0;
        *(u16x8*)&vthi[ob + 8] = h1;
        *(u16x8*)&vtlo[ob]     = l0;
        *(u16x8*)&vtlo[ob + 8] = l1;
    }
}

// ---------------------------------------------------------------------------
// MFMA flash attention v4 (from validated v3):
// - T14 reg-staging: tile t+1 global->reg loads issued at top of compute
//   phase (after barrier-2, so __syncthreads' vmcnt drain doesn't expose
//   them); ds_write_b128 after barrier-1 of the next tile.
// - v_cvt_pk_bf16_f32 P-split (RNE, bit-identical to f2bf): ~1/3 the VALU.
// - ones-column l: l accumulated via MFMA (B-frag = 1.0) with the same
//   rescale as O -> all sum-reduce shuffles deleted.
// ---------------------------------------------------------------------------
__global__ __launch_bounds__(512) void attn_mfma4(const float* __restrict__ Qp,
                                                  const unsigned short* __restrict__ Khig,
                                                  const unsigned short* __restrict__ Klog,
                                                  const unsigned short* __restrict__ VThig,
                                                  const unsigned short* __restrict__ VTlog,
                                                  const int* __restrict__ mask,
                                                  unsigned short* __restrict__ Ach,
                                                  unsigned short* __restrict__ Acl) {
    __shared__ unsigned short KsH[4096], KsL[4096];   // [64 key][64 d], slot-swz
    __shared__ unsigned short VsH[4096], VsL[4096];   // [64 d][64 key], slot-swz
    __shared__ float Pbuf[8][16 * 36];

    const int tid  = threadIdx.x;
    const int lane = tid & 63;
    const int wid  = tid >> 6;

    const int bid = blockIdx.x;
    const int swz = (bid & 7) * 128 + (bid >> 3);
    const int qt  = swz & 15;
    const int bh  = swz >> 4;
    const int b   = bh >> 4;
    const int h   = bh & 15;

    const int q0  = qt * 128;
    const int wq0 = wid * 16;

    const int fr = lane & 15;
    const int fg = lane >> 4;

    const float* qbase = Qp + ((size_t)bh * SS + q0 + wq0) * DK;
    const unsigned short* khb = Khig + (size_t)bh * SS * DK;
    const unsigned short* klb = Klog + (size_t)bh * SS * DK;
    const unsigned short* vhb = VThig + (size_t)bh * DK * SS;
    const unsigned short* vlb = VTlog + (size_t)bh * DK * SS;
    const int* mrow = mask + b * SS;

    // Q fragments, pre-scaled 1/8
    bf16x8 qh[2], ql[2];
#pragma unroll
    for (int kb = 0; kb < 2; ++kb) {
        const float* p = qbase + (size_t)fr * DK + kb * 32 + fg * 8;
        float4 a  = *(const float4*)p;
        float4 b4 = *(const float4*)(p + 4);
        float vals[8] = {a.x, a.y, a.z, a.w, b4.x, b4.y, b4.z, b4.w};
#pragma unroll
        for (int i = 0; i < 8; ++i) {
            float s = vals[i] * 0.125f;
            unsigned short hi = f2bf(s);
            qh[kb][i] = (short)hi;
            ql[kb][i] = (short)f2bf(s - bf2f(hi));
        }
    }

    bf16x8 ONESB;
#pragma unroll
    for (int i = 0; i < 8; ++i) ONESB[i] = (short)0x3F80;   // bf16 1.0

    f32x4 O[4] = {};
    f32x4 Lacc = {};
    float m_run[4];
#pragma unroll
    for (int r = 0; r < 4; ++r) m_run[r] = -3.0e38f;

    const int srow = tid >> 3;
    const int ssl  = tid & 7;
    const int sch  = ssl ^ (srow & 7);
    const int ldsb = tid * 8;

    const int sl0 = ((0 + fg) ^ (fr & 7)) * 8;
    const int sl1 = ((4 + fg) ^ (fr & 7)) * 8;

    float* pw = Pbuf[wid];

    // prologue: stage tile 0 into regs
    u16x8 rKh = *(const u16x8*)&khb[(size_t)srow * 64 + sch * 8];
    u16x8 rKl = *(const u16x8*)&klb[(size_t)srow * 64 + sch * 8];
    u16x8 rVh = *(const u16x8*)&vhb[(size_t)srow * SS + sch * 8];
    u16x8 rVl = *(const u16x8*)&vlb[(size_t)srow * SS + sch * 8];

    for (int t = 0; t < SS / 64; ++t) {
        const int kv0 = t * 64;

        __syncthreads();   // previous tile's LDS reads complete
        *(u16x8*)&KsH[ldsb] = rKh;
        *(u16x8*)&KsL[ldsb] = rKl;
        *(u16x8*)&VsH[ldsb] = rVh;
        *(u16x8*)&VsL[ldsb] = rVl;
        __syncthreads();   // tile t visible to all waves

        // issue tile t+1 loads now (latency hides under this tile's compute)
        if (t + 1 < SS / 64) {
            const int kn = kv0 + 64;
            rKh = *(const u16x8*)&khb[(size_t)(kn + srow) * 64 + sch * 8];
            rKl = *(const u16x8*)&klb[(size_t)(kn + srow) * 64 + sch * 8];
            rVh = *(const u16x8*)&vhb[(size_t)srow * SS + kn + sch * 8];
            rVl = *(const u16x8*)&vlb[(size_t)srow * SS + kn + sch * 8];
        }
        int mv[4];
#pragma unroll
        for (int kyb = 0; kyb < 4; ++kyb) mv[kyb] = mrow[kv0 + kyb * 16 + fr];

        // --- QK^T
        f32x4 acc[4] = {};
        __builtin_amdgcn_s_setprio(1);
#pragma unroll
        for (int kyb = 0; kyb < 4; ++kyb) {
            const int rb = (kyb * 16 + fr) * 64;
            {
                bf16x8 kh = *(const bf16x8*)&KsH[rb + sl0];
                bf16x8 kl = *(const bf16x8*)&KsL[rb + sl0];
                acc[kyb] = __builtin_amdgcn_mfma_f32_16x16x32_bf16(qh[0], kh, acc[kyb], 0, 0, 0);
                acc[kyb] = __builtin_amdgcn_mfma_f32_16x16x32_bf16(qh[0], kl, acc[kyb], 0, 0, 0);
                acc[kyb] = __builtin_amdgcn_mfma_f32_16x16x32_bf16(ql[0], kh, acc[kyb], 0, 0, 0);
            }
            {
                bf16x8 kh = *(const bf16x8*)&KsH[rb + sl1];
                bf16x8 kl = *(const bf16x8*)&KsL[rb + sl1];
                acc[kyb] = __builtin_amdgcn_mfma_f32_16x16x32_bf16(qh[1], kh, acc[kyb], 0, 0, 0);
                acc[kyb] = __builtin_amdgcn_mfma_f32_16x16x32_bf16(qh[1], kl, acc[kyb], 0, 0, 0);
                acc[kyb] = __builtin_amdgcn_mfma_f32_16x16x32_bf16(ql[1], kh, acc[kyb], 0, 0, 0);
            }
        }
        __builtin_amdgcn_s_setprio(0);

        // --- mask + online softmax (max only; sum comes from ones-MFMA)
        float sc[4][4];
#pragma unroll
        for (int kyb = 0; kyb < 4; ++kyb)
#pragma unroll
            for (int r = 0; r < 4; ++r)
                sc[kyb][r] = mv[kyb] ? acc[kyb][r] : -1.0e9f;

        float scale[4], p[4][4];
#pragma unroll
        for (int r = 0; r < 4; ++r) {
            float v = fmaxf(fmaxf(sc[0][r], sc[1][r]), fmaxf(sc[2][r], sc[3][r]));
            v = fmaxf(v, __shfl_xor(v, 1));
            v = fmaxf(v, __shfl_xor(v, 2));
            v = fmaxf(v, __shfl_xor(v, 4));
            v = fmaxf(v, __shfl_xor(v, 8));
            float m_new = fmaxf(m_run[r], v);
            scale[r] = __expf(m_run[r] - m_new);
            m_run[r] = m_new;
#pragma unroll
            for (int kyb = 0; kyb < 4; ++kyb)
                p[kyb][r] = __expf(sc[kyb][r] - m_new);
        }

        // O + L rescale once per tile
#pragma unroll
        for (int r = 0; r < 4; ++r) {
#pragma unroll
            for (int db = 0; db < 4; ++db)
                O[db][r] *= scale[r];
            Lacc[r] *= scale[r];
        }

        // --- two PV half-phases over key halves (reuse small Pbuf)
#pragma unroll
        for (int ph2 = 0; ph2 < 2; ++ph2) {
#pragma unroll
            for (int kyb2 = 0; kyb2 < 2; ++kyb2)
#pragma unroll
                for (int r = 0; r < 4; ++r)
                    pw[(fg * 4 + r) * 36 + kyb2 * 16 + fr] = p[ph2 * 2 + kyb2][r];

            asm volatile("s_waitcnt lgkmcnt(0)" ::: "memory");
            __builtin_amdgcn_sched_barrier(0);

            bf16x8 ph8, pl8;
            {
                const float* prd = &pw[fr * 36 + fg * 8];
                float4 p0 = *(const float4*)&prd[0];
                float4 p1 = *(const float4*)&prd[4];
                float vals[8] = {p0.x, p0.y, p0.z, p0.w, p1.x, p1.y, p1.z, p1.w};
                u32x4 wh, wl;
#pragma unroll
                for (int i = 0; i < 4; ++i) {
                    unsigned w = pk2(vals[2 * i], vals[2 * i + 1]);
                    wh[i] = w;
                    float h0 = __uint_as_float(w << 16);
                    float h1 = __uint_as_float(w & 0xFFFF0000u);
                    wl[i] = pk2(vals[2 * i] - h0, vals[2 * i + 1] - h1);
                }
                ph8 = *(bf16x8*)&wh;
                pl8 = *(bf16x8*)&wl;
            }

            const int sl = ((ph2 * 4 + fg) ^ (fr & 7)) * 8;
            __builtin_amdgcn_s_setprio(1);
            Lacc = __builtin_amdgcn_mfma_f32_16x16x32_bf16(ph8, ONESB, Lacc, 0, 0, 0);
            Lacc = __builtin_amdgcn_mfma_f32_16x16x32_bf16(pl8, ONESB, Lacc, 0, 0, 0);
#pragma unroll
            for (int db = 0; db < 4; ++db) {
                const int rb = (db * 16 + fr) * 64;
                bf16x8 vh = *(const bf16x8*)&VsH[rb + sl];
                bf16x8 vl = *(const bf16x8*)&VsL[rb + sl];
                O[db] = __builtin_amdgcn_mfma_f32_16x16x32_bf16(ph8, vh, O[db], 0, 0, 0);
                O[db] = __builtin_amdgcn_mfma_f32_16x16x32_bf16(ph8, vl, O[db], 0, 0, 0);
                O[db] = __builtin_amdgcn_mfma_f32_16x16x32_bf16(pl8, vh, O[db], 0, 0, 0);
            }
            __builtin_amdgcn_s_setprio(0);

            // WAR fence: this half's Pbuf reads retired before next writes
            asm volatile("s_waitcnt lgkmcnt(0)" ::: "memory");
            __builtin_amdgcn_sched_barrier(0);
        }
    }

    // --- epilogue: write O directly as split bf16 in tiled-swizzled layout
#pragma unroll
    for (int r = 0; r < 4; ++r) {
        float inv = 1.0f / Lacc[r];
        int m  = b * SS + q0 + wq0 + fg * 4 + r;
        int rt = m & 127;
        int mt = m >> 7;
        int rx = (rt & 3) ^ ((rt >> 2) & 3);
#pragma unroll
        for (int db = 0; db < 4; ++db) {
            float val = O[db][r] * inv;
            int kcol = h * 64 + db * 16 + fr;
            int tile = mt * 32 + (kcol >> 5);
            int slot = (((kcol >> 3) & 3)) ^ rx;
            size_t doff = (size_t)tile * 4096 + rt * 32 + slot * 8 + (kcol & 7);
            unsigned short hv = f2bf(val);
            Ach[doff] = hv;
            Acl[doff] = f2bf(val - bf2f(hv));
        }
    }
}

// ---------------------------------------------------------------------------
// fp32 GEMM + old attention (fallback path, unchanged/validated)
// ---------------------------------------------------------------------------
template <int MODE>
__global__ __launch_bounds__(256) void gemm_xwT(const float* __restrict__ A,
                                                const float* __restrict__ W,
                                                const float* __restrict__ bias,
                                                float* __restrict__ C,
                                                unsigned short* __restrict__ Chi,
                                                unsigned short* __restrict__ Clo,
                                                int M, int N, int K) {
    __shared__ float As[8][132];
    __shared__ float Bs[8][132];

    const int tid = threadIdx.x;
    const int tx  = tid & 15;
    const int ty  = tid >> 4;
    const int m0  = blockIdx.y * 128;
    const int n0  = blockIdx.x * 128;

    const int lr = tid >> 1;
    const int lk = (tid & 1) * 4;

    float acc[8][8];
#pragma unroll
    for (int i = 0; i < 8; ++i)
#pragma unroll
        for (int j = 0; j < 8; ++j) acc[i][j] = 0.f;

    for (int kt = 0; kt < K; kt += 8) {
        float4 av = *(const float4*)&A[(size_t)(m0 + lr) * K + kt + lk];
        float4 wv = *(const float4*)&W[(size_t)(n0 + lr) * K + kt + lk];
        __syncthreads();
        As[lk + 0][lr] = av.x; As[lk + 1][lr] = av.y;
        As[lk + 2][lr] = av.z; As[lk + 3][lr] = av.w;
        Bs[lk + 0][lr] = wv.x; Bs[lk + 1][lr] = wv.y;
        Bs[lk + 2][lr] = wv.z; Bs[lk + 3][lr] = wv.w;
        __syncthreads();
#pragma unroll
        for (int k = 0; k < 8; ++k) {
            float4 a0 = *(const float4*)&As[k][ty * 8];
            float4 a1 = *(const float4*)&As[k][ty * 8 + 4];
            float4 b0 = *(const float4*)&Bs[k][tx * 8];
            float4 b1 = *(const float4*)&Bs[k][tx * 8 + 4];
            float a[8] = {a0.x, a0.y, a0.z, a0.w, a1.x, a1.y, a1.z, a1.w};
            float b[8] = {b0.x, b0.y, b0.z, b0.w, b1.x, b1.y, b1.z, b1.w};
#pragma unroll
            for (int i = 0; i < 8; ++i)
#pragma unroll
                for (int j = 0; j < 8; ++j) acc[i][j] += a[i] * b[j];
        }
    }

    float bb[8];
#pragma unroll
    for (int j = 0; j < 8; ++j) bb[j] = bias[n0 + tx * 8 + j];

#pragma unroll
    for (int i = 0; i < 8; ++i) {
        int m = m0 + ty * 8 + i;
        int n = n0 + tx * 8;
        float cv[8];
#pragma unroll
        for (int j = 0; j < 8; ++j) cv[j] = acc[i][j] + bb[j];

        if (MODE == 0) {
            float* dst = &C[(size_t)m * N + n];
            *(float4*)&dst[0] = {cv[0], cv[1], cv[2], cv[3]};
            *(float4*)&dst[4] = {cv[4], cv[5], cv[6], cv[7]};
        } else {
            int bq = m >> 11;
            int s  = m & (SS - 1);
            int h  = n >> 6;
            int d  = n & 63;
            size_t base = (((size_t)(bq * NHEAD + h) * SS + s) << 6) + d;
            if (MODE == 1) {
                float* dst = &C[base];
                *(float4*)&dst[0] = {cv[0], cv[1], cv[2], cv[3]};
                *(float4*)&dst[4] = {cv[4], cv[5], cv[6], cv[7]};
            } else {
                u16x8 h8, l8;
#pragma unroll
                for (int j = 0; j < 8; ++j) {
                    unsigned short hv = f2bf(cv[j]);
                    h8[j] = hv;
                    l8[j] = f2bf(cv[j] - bf2f(hv));
                }
                *(u16x8*)&Chi[base] = h8;
                *(u16x8*)&Clo[base] = l8;
            }
        }
    }
}

__global__ __launch_bounds__(256) void attn_mfma(const float* __restrict__ Qp,
                                                 const unsigned short* __restrict__ Khig,
                                                 const unsigned short* __restrict__ Klog,
                                                 const unsigned short* __restrict__ Vhig,
                                                 const unsigned short* __restrict__ Vlog,
                                                 const int* __restrict__ mask,
                                                 float* __restrict__ ctx) {
    __shared__ short Khi[32 * 72], Klo[32 * 72];
    __shared__ short Vhi[64 * 40], Vlo[64 * 40];
    __shared__ float Pbuf[4][16 * 36];
    __shared__ int   msk[32];

    const int tid  = threadIdx.x;
    const int lane = tid & 63;
    const int wid  = tid >> 6;

    const int bid = blockIdx.x;
    const int swz = (bid & 7) * 256 + (bid >> 3);
    const int qt  = swz & 31;
    const int bh  = swz >> 5;
    const int b   = bh >> 4;
    const int h   = bh & 15;

    const int q0  = qt * 64;
    const int wq0 = wid * 16;

    const int fr = lane & 15;
    const int fg = lane >> 4;

    const float* qbase = Qp + ((size_t)bh * SS + q0 + wq0) * DK;
    const unsigned short* khbase = Khig + (size_t)bh * SS * DK;
    const unsigned short* klbase = Klog + (size_t)bh * SS * DK;
    const unsigned short* vhbase = Vhig + (size_t)bh * SS * DK;
    const unsigned short* vlbase = Vlog + (size_t)bh * SS * DK;
    const int* mrow = mask + b * SS;

    bf16x8 qh[2], ql[2];
#pragma unroll
    for (int kb = 0; kb < 2; ++kb) {
        const float* p = qbase + (size_t)fr * DK + kb * 32 + fg * 8;
        float4 a  = *(const float4*)p;
        float4 b4 = *(const float4*)(p + 4);
        float vals[8] = {a.x, a.y, a.z, a.w, b4.x, b4.y, b4.z, b4.w};
#pragma unroll
        for (int i = 0; i < 8; ++i) {
            float s = vals[i] * 0.125f;
            unsigned short hi = f2bf(s);
            qh[kb][i] = (short)hi;
            ql[kb][i] = (short)f2bf(s - bf2f(hi));
        }
    }

    f32x4 O[4] = {};
    float m_run[4], l_run[4];
#pragma unroll
    for (int r = 0; r < 4; ++r) { m_run[r] = -3.0e38f; l_run[r] = 0.f; }

    const int sk_k = tid >> 3;
    const int sk_d = (tid & 7) * 8;
    const int sv_d = tid & 63;
    const int sv_k = (tid >> 6) * 8;

    for (int t = 0; t < SS / 32; ++t) {
        const int kv0 = t * 32;

        size_t koff = (size_t)(kv0 + sk_k) * DK + sk_d;
        u16x8 kh8 = *(const u16x8*)&khbase[koff];
        u16x8 kl8 = *(const u16x8*)&klbase[koff];
        unsigned short vh[8], vl[8];
#pragma unroll
        for (int j = 0; j < 8; ++j) {
            size_t voff = (size_t)(kv0 + sv_k + j) * DK + sv_d;
            vh[j] = vhbase[voff];
            vl[j] = vlbase[voff];
        }
        int mval = (tid < 32) ? mrow[kv0 + tid] : 0;

        __syncthreads();
        *(u16x8*)&Khi[sk_k * 72 + sk_d] = kh8;
        *(u16x8*)&Klo[sk_k * 72 + sk_d] = kl8;
        {
            u16x8 h8, l8;
#pragma unroll
            for (int j = 0; j < 8; ++j) { h8[j] = vh[j]; l8[j] = vl[j]; }
            *(u16x8*)&Vhi[sv_d * 40 + sv_k] = h8;
            *(u16x8*)&Vlo[sv_d * 40 + sv_k] = l8;
        }
        if (tid < 32) msk[tid] = mval;
        __syncthreads();

        f32x4 acc[2] = {};
#pragma unroll
        for (int kyb = 0; kyb < 2; ++kyb) {
#pragma unroll
            for (int kb = 0; kb < 2; ++kb) {
                int idx = (kyb * 16 + fr) * 72 + kb * 32 + fg * 8;
                bf16x8 kh = *(const bf16x8*)&Khi[idx];
                bf16x8 kl = *(const bf16x8*)&Klo[idx];
                acc[kyb] = __builtin_amdgcn_mfma_f32_16x16x32_bf16(qh[kb], kh, acc[kyb], 0, 0, 0);
                acc[kyb] = __builtin_amdgcn_mfma_f32_16x16x32_bf16(qh[kb], kl, acc[kyb], 0, 0, 0);
                acc[kyb] = __builtin_amdgcn_mfma_f32_16x16x32_bf16(ql[kb], kh, acc[kyb], 0, 0, 0);
            }
        }

        float sc[2][4];
#pragma unroll
        for (int kyb = 0; kyb < 2; ++kyb) {
            int mv = msk[kyb * 16 + fr];
#pragma unroll
            for (int r = 0; r < 4; ++r)
                sc[kyb][r] = mv ? acc[kyb][r] : -1.0e9f;
        }
        float scale[4], p[2][4];
#pragma unroll
        for (int r = 0; r < 4; ++r) {
            float v = fmaxf(sc[0][r], sc[1][r]);
            v = fmaxf(v, __shfl_xor(v, 1));
            v = fmaxf(v, __shfl_xor(v, 2));
            v = fmaxf(v, __shfl_xor(v, 4));
            v = fmaxf(v, __shfl_xor(v, 8));
            float m_new = fmaxf(m_run[r], v);
            scale[r] = __expf(m_run[r] - m_new);
            m_run[r] = m_new;
            p[0][r] = __expf(sc[0][r] - m_new);
            p[1][r] = __expf(sc[1][r] - m_new);
            float s = p[0][r] + p[1][r];
            s += __shfl_xor(s, 1);
            s += __shfl_xor(s, 2);
            s += __shfl_xor(s, 4);
            s += __shfl_xor(s, 8);
            l_run[r] = l_run[r] * scale[r] + s;
        }

        float* pw = Pbuf[wid];
#pragma unroll
        for (int r = 0; r < 4; ++r) {
            pw[(fg * 4 + r) * 36 + fr]      = p[0][r];
            pw[(fg * 4 + r) * 36 + 16 + fr] = p[1][r];
        }
#pragma unroll
        for (int db = 0; db < 4; ++db)
#pragma unroll
            for (int r = 0; r < 4; ++r)
                O[db][r] *= scale[r];

        __syncthreads();

        float pr[8];
        {
            const float* prd = &pw[fr * 36 + fg * 8];
            *(float4*)&pr[0] = *(const float4*)&prd[0];
            *(float4*)&pr[4] = *(const float4*)&prd[4];
        }
        bf16x8 ph8, pl8;
#pragma unroll
        for (int i = 0; i < 8; ++i) {
            unsigned short hi = f2bf(pr[i]);
            ph8[i] = (short)hi;
            pl8[i] = (short)f2bf(pr[i] - bf2f(hi));
        }

#pragma unroll
        for (int db = 0; db < 4; ++db) {
            int idx = (db * 16 + fr) * 40 + fg * 8;
            bf16x8 vh8 = *(const bf16x8*)&Vhi[idx];
            bf16x8 vl8 = *(const bf16x8*)&Vlo[idx];
            O[db] = __builtin_amdgcn_mfma_f32_16x16x32_bf16(ph8, vh8, O[db], 0, 0, 0);
            O[db] = __builtin_amdgcn_mfma_f32_16x16x32_bf16(ph8, vl8, O[db], 0, 0, 0);
            O[db] = __builtin_amdgcn_mfma_f32_16x16x32_bf16(pl8, vh8, O[db], 0, 0, 0);
        }
    }

    float* cbase = ctx + ((size_t)b * SS + q0 + wq0) * D_MODEL + h * DK;
#pragma unroll
    for (int r = 0; r < 4; ++r) {
        float inv = 1.0f / l_run[r];
        int q = fg * 4 + r;
#pragma unroll
        for (int db = 0; db < 4; ++db)
            cbase[(size_t)q * D_MODEL + db * 16 + fr] = O[db][r] * inv;
    }
}

// ---------------------------------------------------------------------------
extern "C" void kernel_launch(void* const* d_in, const int* in_sizes, int n_in,
                              void* d_out, int out_size, void* d_ws, size_t ws_size,
                              hipStream_t stream) {
    const float* q    = (const float*)d_in[0];
    const float* k    = (const float*)d_in[1];
    const float* v    = (const float*)d_in[2];
    const int*   mask = (const int*)d_in[3];
    const float* w_q  = (const float*)d_in[4];
    const float* b_q  = (const float*)d_in[5];
    const float* w_k  = (const float*)d_in[6];
    const float* b_k  = (const float*)d_in[7];
    const float* w_v  = (const float*)d_in[8];
    const float* b_v  = (const float*)d_in[9];
    const float* w_o  = (const float*)d_in[10];
    const float* b_o  = (const float*)d_in[11];
    float* out = (float*)d_out;

    const int M = BB * SS;
    const size_t PSZ = (size_t)M * D_MODEL;
    const size_t NEED = (size_t)208 << 20;
    char* w = (char*)d_ws;
    dim3 block(256);

    if (ws_size >= NEED) {
        float* qp            = (float*)(w);
        unsigned short* khi  = (unsigned short*)(w + ((size_t)32 << 20));
        unsigned short* klo  = (unsigned short*)(w + ((size_t)48 << 20));
        unsigned short* vhi  = (unsigned short*)(w + ((size_t)64 << 20));
        unsigned short* vlo  = (unsigned short*)(w + ((size_t)80 << 20));
        unsigned short* Aq_h = (unsigned short*)(w + ((size_t)96 << 20));
        unsigned short* Aq_l = (unsigned short*)(w + ((size_t)112 << 20));
        unsigned short* Ak_h = (unsigned short*)(w + ((size_t)128 << 20));
        unsigned short* Ak_l = (unsigned short*)(w + ((size_t)144 << 20));
        unsigned short* Av_h = (unsigned short*)(w + ((size_t)160 << 20));
        unsigned short* Av_l = (unsigned short*)(w + ((size_t)176 << 20));
        unsigned short* vthi = (unsigned short*)(w + ((size_t)160 << 20)); // alias Av_h
        unsigned short* vtlo = (unsigned short*)(w + ((size_t)176 << 20)); // alias Av_l
        unsigned short* Wq_h = (unsigned short*)(w + ((size_t)192 << 20));
        unsigned short* Wq_l = (unsigned short*)(w + ((size_t)194 << 20));
        unsigned short* Wk_h = (unsigned short*)(w + ((size_t)196 << 20));
        unsigned short* Wk_l = (unsigned short*)(w + ((size_t)198 << 20));
        unsigned short* Wv_h = (unsigned short*)(w + ((size_t)200 << 20));
        unsigned short* Wv_l = (unsigned short*)(w + ((size_t)202 << 20));
        unsigned short* Wo_h = (unsigned short*)(w + ((size_t)204 << 20));
        unsigned short* Wo_l = (unsigned short*)(w + ((size_t)206 << 20));
        unsigned short* Ac_h = Ak_h;
        unsigned short* Ac_l = Ak_l;

        const int ACT_CHUNKS = M * 128;
        const int W_CHUNKS   = 1024 * 128;

        SplitJobs8 J{};
        J.j[0] = {q,   Aq_h, Aq_l, ACT_CHUNKS};
        J.j[1] = {k,   Ak_h, Ak_l, ACT_CHUNKS};
        J.j[2] = {v,   Av_h, Av_l, ACT_CHUNKS};
        J.j[3] = {w_q, Wq_h, Wq_l, W_CHUNKS};
        J.j[4] = {w_k, Wk_h, Wk_l, W_CHUNKS};
        J.j[5] = {w_v, Wv_h, Wv_l, W_CHUNKS};
        J.j[6] = {w_o, Wo_h, Wo_l, W_CHUNKS};
        presplit<<<dim3(4096, 7), block, 0, stream>>>(J);

        dim3 ggrid(D_MODEL / 128, M / 128);
        gemm_mfma<1><<<ggrid, block, 0, stream>>>(Aq_h, Aq_l, Wq_h, Wq_l, b_q, qp, nullptr, nullptr);
        gemm_mfma<2><<<ggrid, block, 0, stream>>>(Ak_h, Ak_l, Wk_h, Wk_l, b_k, nullptr, khi, klo);
        gemm_mfma<2><<<ggrid, block, 0, stream>>>(Av_h, Av_l, Wv_h, Wv_l, b_v, nullptr, vhi, vlo);

        vtrans<<<dim3(SS / 64, BB * NHEAD), block, 0, stream>>>(vhi, vlo, vthi, vtlo);

        attn_mfma4<<<dim3(BB * NHEAD * (SS / 128)), dim3(512), 0, stream>>>(
            qp, khi, klo, vthi, vtlo, mask, Ac_h, Ac_l);

        gemm_mfma<0><<<ggrid, block, 0, stream>>>(Ac_h, Ac_l, Wo_h, Wo_l, b_o, out, nullptr, nullptr);
    } else {
        float* qp           = (float*)d_ws;
        unsigned short* khi = (unsigned short*)(qp + PSZ);
        unsigned short* klo = khi + PSZ;
        unsigned short* vhi = klo + PSZ;
        unsigned short* vlo = vhi + PSZ;
        float* ctx          = (float*)(vlo + PSZ);

        dim3 grid(D_MODEL / 128, M / 128);
        gemm_xwT<1><<<grid, block, 0, stream>>>(q, w_q, b_q, qp, nullptr, nullptr, M, D_MODEL, D_MODEL);
        gemm_xwT<2><<<grid, block, 0, stream>>>(k, w_k, b_k, nullptr, khi, klo, M, D_MODEL, D_MODEL);
        gemm_xwT<2><<<grid, block, 0, stream>>>(v, w_v, b_v, nullptr, vhi, vlo, M, D_MODEL, D_MODEL);
        attn_mfma<<<dim3(BB * NHEAD * (SS / 64)), block, 0, stream>>>(qp, khi, klo, vhi, vlo, mask, ctx);
        gemm_xwT<0><<<grid, block, 0, stream>>>(ctx, w_o, b_o, out, nullptr, nullptr, M, D_MODEL, D_MODEL);
    }
}

// Round 10
// 502.972 us; speedup vs baseline: 5.7532x; 1.0213x over previous
//
#include <hip/hip_runtime.h>
#include <stdint.h>

#define D_MODEL 1024
#define NHEAD   16
#define DK      64
#define SS      2048
#define BB      4

typedef short bf16x8 __attribute__((ext_vector_type(8)));
typedef unsigned short u16x8 __attribute__((ext_vector_type(8)));
typedef float f32x4  __attribute__((ext_vector_type(4)));
typedef unsigned int u32x4 __attribute__((ext_vector_type(4)));

#if __has_builtin(__builtin_amdgcn_exp2f)
#define EXP2(x) __builtin_amdgcn_exp2f(x)
#else
#define EXP2(x) __expf((x) * 0.6931471805599453f)
#endif

__device__ inline unsigned short f2bf(float x) {
    unsigned u = __float_as_uint(x);
    return (unsigned short)((u + 0x7fff + ((u >> 16) & 1)) >> 16);
}
__device__ inline float bf2f(unsigned short h) {
    return __uint_as_float(((unsigned)h) << 16);
}
// packed bf16 convert: low16 = cvt(a), high16 = cvt(b)  (RNE, same as f2bf)
__device__ inline unsigned pk2(float a, float b) {
    unsigned r;
    asm("v_cvt_pk_bf16_f32 %0, %1, %2" : "=v"(r) : "v"(a), "v"(b));
    return r;
}

__device__ inline void gll16(const void* g, void* l) {
    __builtin_amdgcn_global_load_lds(
        (const __attribute__((address_space(1))) unsigned int*)(g),
        (__attribute__((address_space(3))) unsigned int*)(l),
        16, 0, 0);
}

// ---------------------------------------------------------------------------
// Pre-split: fp32 row-major [R][1024] -> bf16 hi/lo tiled-swizzled (unchanged)
// ---------------------------------------------------------------------------
struct SplitJob { const float* src; unsigned short* hi; unsigned short* lo; int nchunks; };
struct SplitJobs8 { SplitJob j[8]; };

__global__ __launch_bounds__(256) void presplit(SplitJobs8 jobs) {
    const SplitJob J = jobs.j[blockIdx.y];
    int g = blockIdx.x * 256 + threadIdx.x;
    if (g >= J.nchunks) return;
    int tile = g >> 9;
    int w    = g & 511;
    int r    = w >> 2;
    int cc   = w & 3;
    int mt   = tile >> 5;
    int kt   = tile & 31;
    int m    = mt * 128 + r;
    int k0   = kt * 32 + cc * 8;

    const float* s = J.src + (size_t)m * 1024 + k0;
    float4 f0 = *(const float4*)s;
    float4 f1 = *(const float4*)(s + 4);
    float vals[8] = {f0.x, f0.y, f0.z, f0.w, f1.x, f1.y, f1.z, f1.w};
    u16x8 h8, l8;
#pragma unroll
    for (int i = 0; i < 8; ++i) {
        unsigned short hv = f2bf(vals[i]);
        h8[i] = hv;
        l8[i] = f2bf(vals[i] - bf2f(hv));
    }
    int slot = cc ^ (r & 3) ^ ((r >> 2) & 3);
    size_t doff = (size_t)tile * 4096 + r * 32 + slot * 8;
    *(u16x8*)(J.hi + doff) = h8;
    *(u16x8*)(J.lo + doff) = l8;
}

// ---------------------------------------------------------------------------
// Split-bf16 MFMA GEMM (unchanged from R6, validated)
// ---------------------------------------------------------------------------
template <int MODE>
__global__ __launch_bounds__(256) void gemm_mfma(const unsigned short* __restrict__ Ahi,
                                                 const unsigned short* __restrict__ Alo,
                                                 const unsigned short* __restrict__ Bhi,
                                                 const unsigned short* __restrict__ Blo,
                                                 const float* __restrict__ bias,
                                                 float* __restrict__ C,
                                                 unsigned short* __restrict__ Chi,
                                                 unsigned short* __restrict__ Clo) {
    __shared__ unsigned short As_hi[4096], As_lo[4096], Bs_hi[4096], Bs_lo[4096];

    const int tid  = threadIdx.x;
    const int lane = tid & 63;
    const int wid  = tid >> 6;
    const int bx   = blockIdx.x;
    const int by   = blockIdx.y;
    const int wr   = wid >> 1;
    const int wc   = wid & 1;
    const int fr   = lane & 15;
    const int fg   = lane >> 4;
    const int chunk = fg ^ (fr & 3) ^ ((fr >> 2) & 3);

    f32x4 acc[4][4] = {};

    const size_t aT = (size_t)by * 32;
    const size_t bT = (size_t)bx * 32;
    const int soff  = wid * 2048 + lane * 16;

    for (int kt = 0; kt < 32; ++kt) {
        const char* at_h = (const char*)Ahi + ((aT + kt) << 13);
        const char* at_l = (const char*)Alo + ((aT + kt) << 13);
        const char* bt_h = (const char*)Bhi + ((bT + kt) << 13);
        const char* bt_l = (const char*)Blo + ((bT + kt) << 13);
        gll16(at_h + soff,        (char*)As_hi + soff);
        gll16(at_h + soff + 1024, (char*)As_hi + soff + 1024);
        gll16(at_l + soff,        (char*)As_lo + soff);
        gll16(at_l + soff + 1024, (char*)As_lo + soff + 1024);
        gll16(bt_h + soff,        (char*)Bs_hi + soff);
        gll16(bt_h + soff + 1024, (char*)Bs_hi + soff + 1024);
        gll16(bt_l + soff,        (char*)Bs_lo + soff);
        gll16(bt_l + soff + 1024, (char*)Bs_lo + soff + 1024);
        __syncthreads();

        bf16x8 ah[4], al[4], bh[4], bl[4];
#pragma unroll
        for (int mi = 0; mi < 4; ++mi) {
            int ro = (wr * 64 + mi * 16 + fr) * 64 + chunk * 16;
            ah[mi] = *(const bf16x8*)((const char*)As_hi + ro);
            al[mi] = *(const bf16x8*)((const char*)As_lo + ro);
        }
#pragma unroll
        for (int ni = 0; ni < 4; ++ni) {
            int ro = (wc * 64 + ni * 16 + fr) * 64 + chunk * 16;
            bh[ni] = *(const bf16x8*)((const char*)Bs_hi + ro);
            bl[ni] = *(const bf16x8*)((const char*)Bs_lo + ro);
        }
#pragma unroll
        for (int mi = 0; mi < 4; ++mi)
#pragma unroll
            for (int ni = 0; ni < 4; ++ni) {
                acc[mi][ni] = __builtin_amdgcn_mfma_f32_16x16x32_bf16(ah[mi], bh[ni], acc[mi][ni], 0, 0, 0);
                acc[mi][ni] = __builtin_amdgcn_mfma_f32_16x16x32_bf16(ah[mi], bl[ni], acc[mi][ni], 0, 0, 0);
                acc[mi][ni] = __builtin_amdgcn_mfma_f32_16x16x32_bf16(al[mi], bh[ni], acc[mi][ni], 0, 0, 0);
            }
        __syncthreads();
    }

#pragma unroll
    for (int ni = 0; ni < 4; ++ni) {
        int col = bx * 128 + wc * 64 + ni * 16 + fr;
        float bb = bias[col];
#pragma unroll
        for (int mi = 0; mi < 4; ++mi)
#pragma unroll
            for (int r2 = 0; r2 < 4; ++r2) {
                int row = by * 128 + wr * 64 + mi * 16 + fg * 4 + r2;
                float cv = acc[mi][ni][r2] + bb;
                if (MODE == 0) {
                    C[(size_t)row * D_MODEL + col] = cv;
                } else {
                    int bq = row >> 11, s = row & (SS - 1), h = col >> 6, d = col & 63;
                    size_t base = (((size_t)(bq * NHEAD + h) * SS + s) << 6) + d;
                    if (MODE == 1) {
                        C[base] = cv;
                    } else {
                        unsigned short hv = f2bf(cv);
                        Chi[base] = hv;
                        Clo[base] = f2bf(cv - bf2f(hv));
                    }
                }
            }
    }
}

// ---------------------------------------------------------------------------
// V transpose: vhi/vlo [bh][S][64] -> vthi/vtlo [bh][64][S]  (unchanged)
// ---------------------------------------------------------------------------
__global__ __launch_bounds__(256) void vtrans(const unsigned short* __restrict__ vhi,
                                              const unsigned short* __restrict__ vlo,
                                              unsigned short* __restrict__ vthi,
                                              unsigned short* __restrict__ vtlo) {
    __shared__ unsigned short T0[64][72], T1[64][72];
    const int tid = threadIdx.x;
    const int st  = blockIdx.x;
    const int bh  = blockIdx.y;

    {
        int row = tid >> 2;
        int c2  = (tid & 3) * 2;
        size_t src = ((size_t)bh * SS + st * 64 + row) * 64 + c2 * 8;
        u16x8 a0 = *(const u16x8*)&vhi[src];
        u16x8 a1 = *(const u16x8*)&vhi[src + 8];
        u16x8 b0 = *(const u16x8*)&vlo[src];
        u16x8 b1 = *(const u16x8*)&vlo[src + 8];
        *(u16x8*)&T0[row][c2 * 8]     = a0;
        *(u16x8*)&T0[row][c2 * 8 + 8] = a1;
        *(u16x8*)&T1[row][c2 * 8]     = b0;
        *(u16x8*)&T1[row][c2 * 8 + 8] = b1;
    }
    __syncthreads();
    {
        int d   = tid >> 2;
        int sch = tid & 3;
        u16x8 h0, h1, l0, l1;
#pragma unroll
        for (int j = 0; j < 8; ++j) {
            h0[j] = T0[sch * 16 + j][d];
            h1[j] = T0[sch * 16 + 8 + j][d];
            l0[j] = T1[sch * 16 + j][d];
            l1[j] = T1[sch * 16 + 8 + j][d];
        }
        size_t ob = ((size_t)bh * 64 + d) * SS + st * 64 + sch * 16;
        *(u16x8*)&vthi[ob]     = h0;
        *(u16x8*)&vthi[ob + 8] = h1;
        *(u16x8*)&vtlo[ob]     = l0;
        *(u16x8*)&vtlo[ob + 8] = l1;
    }
}

// ---------------------------------------------------------------------------
// MFMA flash attention v5 (from validated v4):
// - exp2-domain softmax: Q pre-scaled by 0.125*log2(e); p = exp2(sc - m)
//   via v_exp_f32 directly (deletes the mul inside every __expf).
// - EXACT skip-rescale: when this tile's max doesn't exceed m_run for any
//   row (wave-uniform), scale==1 -> skip the exp2 + 20 rescale mults.
//   Identical math on both paths (scale path only runs when it matters).
// ---------------------------------------------------------------------------
__global__ __launch_bounds__(512) void attn_mfma5(const float* __restrict__ Qp,
                                                  const unsigned short* __restrict__ Khig,
                                                  const unsigned short* __restrict__ Klog,
                                                  const unsigned short* __restrict__ VThig,
                                                  const unsigned short* __restrict__ VTlog,
                                                  const int* __restrict__ mask,
                                                  unsigned short* __restrict__ Ach,
                                                  unsigned short* __restrict__ Acl) {
    __shared__ unsigned short KsH[4096], KsL[4096];   // [64 key][64 d], slot-swz
    __shared__ unsigned short VsH[4096], VsL[4096];   // [64 d][64 key], slot-swz
    __shared__ float Pbuf[8][16 * 36];

    const int tid  = threadIdx.x;
    const int lane = tid & 63;
    const int wid  = tid >> 6;

    const int bid = blockIdx.x;
    const int swz = (bid & 7) * 128 + (bid >> 3);
    const int qt  = swz & 15;
    const int bh  = swz >> 4;
    const int b   = bh >> 4;
    const int h   = bh & 15;

    const int q0  = qt * 128;
    const int wq0 = wid * 16;

    const int fr = lane & 15;
    const int fg = lane >> 4;

    const float* qbase = Qp + ((size_t)bh * SS + q0 + wq0) * DK;
    const unsigned short* khb = Khig + (size_t)bh * SS * DK;
    const unsigned short* klb = Klog + (size_t)bh * SS * DK;
    const unsigned short* vhb = VThig + (size_t)bh * DK * SS;
    const unsigned short* vlb = VTlog + (size_t)bh * DK * SS;
    const int* mrow = mask + b * SS;

    // Q fragments, pre-scaled by (1/8)*log2(e) -> scores in log2 units
    const float QSCALE = 0.125f * 1.44269504088896f;
    bf16x8 qh[2], ql[2];
#pragma unroll
    for (int kb = 0; kb < 2; ++kb) {
        const float* p = qbase + (size_t)fr * DK + kb * 32 + fg * 8;
        float4 a  = *(const float4*)p;
        float4 b4 = *(const float4*)(p + 4);
        float vals[8] = {a.x, a.y, a.z, a.w, b4.x, b4.y, b4.z, b4.w};
#pragma unroll
        for (int i = 0; i < 8; ++i) {
            float s = vals[i] * QSCALE;
            unsigned short hi = f2bf(s);
            qh[kb][i] = (short)hi;
            ql[kb][i] = (short)f2bf(s - bf2f(hi));
        }
    }

    bf16x8 ONESB;
#pragma unroll
    for (int i = 0; i < 8; ++i) ONESB[i] = (short)0x3F80;   // bf16 1.0

    f32x4 O[4] = {};
    f32x4 Lacc = {};
    float m_run[4];
#pragma unroll
    for (int r = 0; r < 4; ++r) m_run[r] = -3.0e38f;

    const int srow = tid >> 3;
    const int ssl  = tid & 7;
    const int sch  = ssl ^ (srow & 7);
    const int ldsb = tid * 8;

    const int sl0 = ((0 + fg) ^ (fr & 7)) * 8;
    const int sl1 = ((4 + fg) ^ (fr & 7)) * 8;

    float* pw = Pbuf[wid];

    // prologue: stage tile 0 into regs
    u16x8 rKh = *(const u16x8*)&khb[(size_t)srow * 64 + sch * 8];
    u16x8 rKl = *(const u16x8*)&klb[(size_t)srow * 64 + sch * 8];
    u16x8 rVh = *(const u16x8*)&vhb[(size_t)srow * SS + sch * 8];
    u16x8 rVl = *(const u16x8*)&vlb[(size_t)srow * SS + sch * 8];

    for (int t = 0; t < SS / 64; ++t) {
        const int kv0 = t * 64;

        __syncthreads();   // previous tile's LDS reads complete
        *(u16x8*)&KsH[ldsb] = rKh;
        *(u16x8*)&KsL[ldsb] = rKl;
        *(u16x8*)&VsH[ldsb] = rVh;
        *(u16x8*)&VsL[ldsb] = rVl;
        __syncthreads();   // tile t visible to all waves

        // issue tile t+1 loads now (latency hides under this tile's compute)
        if (t + 1 < SS / 64) {
            const int kn = kv0 + 64;
            rKh = *(const u16x8*)&khb[(size_t)(kn + srow) * 64 + sch * 8];
            rKl = *(const u16x8*)&klb[(size_t)(kn + srow) * 64 + sch * 8];
            rVh = *(const u16x8*)&vhb[(size_t)srow * SS + kn + sch * 8];
            rVl = *(const u16x8*)&vlb[(size_t)srow * SS + kn + sch * 8];
        }
        int mv[4];
#pragma unroll
        for (int kyb = 0; kyb < 4; ++kyb) mv[kyb] = mrow[kv0 + kyb * 16 + fr];

        // --- QK^T
        f32x4 acc[4] = {};
        __builtin_amdgcn_s_setprio(1);
#pragma unroll
        for (int kyb = 0; kyb < 4; ++kyb) {
            const int rb = (kyb * 16 + fr) * 64;
            {
                bf16x8 kh = *(const bf16x8*)&KsH[rb + sl0];
                bf16x8 kl = *(const bf16x8*)&KsL[rb + sl0];
                acc[kyb] = __builtin_amdgcn_mfma_f32_16x16x32_bf16(qh[0], kh, acc[kyb], 0, 0, 0);
                acc[kyb] = __builtin_amdgcn_mfma_f32_16x16x32_bf16(qh[0], kl, acc[kyb], 0, 0, 0);
                acc[kyb] = __builtin_amdgcn_mfma_f32_16x16x32_bf16(ql[0], kh, acc[kyb], 0, 0, 0);
            }
            {
                bf16x8 kh = *(const bf16x8*)&KsH[rb + sl1];
                bf16x8 kl = *(const bf16x8*)&KsL[rb + sl1];
                acc[kyb] = __builtin_amdgcn_mfma_f32_16x16x32_bf16(qh[1], kh, acc[kyb], 0, 0, 0);
                acc[kyb] = __builtin_amdgcn_mfma_f32_16x16x32_bf16(qh[1], kl, acc[kyb], 0, 0, 0);
                acc[kyb] = __builtin_amdgcn_mfma_f32_16x16x32_bf16(ql[1], kh, acc[kyb], 0, 0, 0);
            }
        }
        __builtin_amdgcn_s_setprio(0);

        // --- mask + online softmax (log2 domain)
        float sc[4][4];
#pragma unroll
        for (int kyb = 0; kyb < 4; ++kyb)
#pragma unroll
            for (int r = 0; r < 4; ++r)
                sc[kyb][r] = mv[kyb] ? acc[kyb][r] : -1.0e9f;

        float tmax[4];
#pragma unroll
        for (int r = 0; r < 4; ++r) {
            float v = fmaxf(fmaxf(sc[0][r], sc[1][r]), fmaxf(sc[2][r], sc[3][r]));
            v = fmaxf(v, __shfl_xor(v, 1));
            v = fmaxf(v, __shfl_xor(v, 2));
            v = fmaxf(v, __shfl_xor(v, 4));
            v = fmaxf(v, __shfl_xor(v, 8));
            tmax[r] = v;
        }

        // EXACT skip-rescale: only rescale when some row's max actually grew
        int grew = (tmax[0] > m_run[0]) | (tmax[1] > m_run[1]) |
                   (tmax[2] > m_run[2]) | (tmax[3] > m_run[3]);
        if (__any(grew)) {
#pragma unroll
            for (int r = 0; r < 4; ++r) {
                float m_new = fmaxf(m_run[r], tmax[r]);
                float scale = EXP2(m_run[r] - m_new);
                m_run[r] = m_new;
#pragma unroll
                for (int db = 0; db < 4; ++db)
                    O[db][r] *= scale;
                Lacc[r] *= scale;
            }
        }

        float p[4][4];
#pragma unroll
        for (int r = 0; r < 4; ++r)
#pragma unroll
            for (int kyb = 0; kyb < 4; ++kyb)
                p[kyb][r] = EXP2(sc[kyb][r] - m_run[r]);

        // --- two PV half-phases over key halves (reuse small Pbuf)
#pragma unroll
        for (int ph2 = 0; ph2 < 2; ++ph2) {
#pragma unroll
            for (int kyb2 = 0; kyb2 < 2; ++kyb2)
#pragma unroll
                for (int r = 0; r < 4; ++r)
                    pw[(fg * 4 + r) * 36 + kyb2 * 16 + fr] = p[ph2 * 2 + kyb2][r];

            asm volatile("s_waitcnt lgkmcnt(0)" ::: "memory");
            __builtin_amdgcn_sched_barrier(0);

            bf16x8 ph8, pl8;
            {
                const float* prd = &pw[fr * 36 + fg * 8];
                float4 p0 = *(const float4*)&prd[0];
                float4 p1 = *(const float4*)&prd[4];
                float vals[8] = {p0.x, p0.y, p0.z, p0.w, p1.x, p1.y, p1.z, p1.w};
                u32x4 wh, wl;
#pragma unroll
                for (int i = 0; i < 4; ++i) {
                    unsigned w = pk2(vals[2 * i], vals[2 * i + 1]);
                    wh[i] = w;
                    float h0 = __uint_as_float(w << 16);
                    float h1 = __uint_as_float(w & 0xFFFF0000u);
                    wl[i] = pk2(vals[2 * i] - h0, vals[2 * i + 1] - h1);
                }
                ph8 = *(bf16x8*)&wh;
                pl8 = *(bf16x8*)&wl;
            }

            const int sl = ((ph2 * 4 + fg) ^ (fr & 7)) * 8;
            __builtin_amdgcn_s_setprio(1);
            Lacc = __builtin_amdgcn_mfma_f32_16x16x32_bf16(ph8, ONESB, Lacc, 0, 0, 0);
            Lacc = __builtin_amdgcn_mfma_f32_16x16x32_bf16(pl8, ONESB, Lacc, 0, 0, 0);
#pragma unroll
            for (int db = 0; db < 4; ++db) {
                const int rb = (db * 16 + fr) * 64;
                bf16x8 vh = *(const bf16x8*)&VsH[rb + sl];
                bf16x8 vl = *(const bf16x8*)&VsL[rb + sl];
                O[db] = __builtin_amdgcn_mfma_f32_16x16x32_bf16(ph8, vh, O[db], 0, 0, 0);
                O[db] = __builtin_amdgcn_mfma_f32_16x16x32_bf16(ph8, vl, O[db], 0, 0, 0);
                O[db] = __builtin_amdgcn_mfma_f32_16x16x32_bf16(pl8, vh, O[db], 0, 0, 0);
            }
            __builtin_amdgcn_s_setprio(0);

            // WAR fence: this half's Pbuf reads retired before next writes
            asm volatile("s_waitcnt lgkmcnt(0)" ::: "memory");
            __builtin_amdgcn_sched_barrier(0);
        }
    }

    // --- epilogue: write O directly as split bf16 in tiled-swizzled layout
#pragma unroll
    for (int r = 0; r < 4; ++r) {
        float inv = 1.0f / Lacc[r];
        int m  = b * SS + q0 + wq0 + fg * 4 + r;
        int rt = m & 127;
        int mt = m >> 7;
        int rx = (rt & 3) ^ ((rt >> 2) & 3);
#pragma unroll
        for (int db = 0; db < 4; ++db) {
            float val = O[db][r] * inv;
            int kcol = h * 64 + db * 16 + fr;
            int tile = mt * 32 + (kcol >> 5);
            int slot = (((kcol >> 3) & 3)) ^ rx;
            size_t doff = (size_t)tile * 4096 + rt * 32 + slot * 8 + (kcol & 7);
            unsigned short hv = f2bf(val);
            Ach[doff] = hv;
            Acl[doff] = f2bf(val - bf2f(hv));
        }
    }
}

// ---------------------------------------------------------------------------
// fp32 GEMM + old attention (fallback path, unchanged/validated)
// ---------------------------------------------------------------------------
template <int MODE>
__global__ __launch_bounds__(256) void gemm_xwT(const float* __restrict__ A,
                                                const float* __restrict__ W,
                                                const float* __restrict__ bias,
                                                float* __restrict__ C,
                                                unsigned short* __restrict__ Chi,
                                                unsigned short* __restrict__ Clo,
                                                int M, int N, int K) {
    __shared__ float As[8][132];
    __shared__ float Bs[8][132];

    const int tid = threadIdx.x;
    const int tx  = tid & 15;
    const int ty  = tid >> 4;
    const int m0  = blockIdx.y * 128;
    const int n0  = blockIdx.x * 128;

    const int lr = tid >> 1;
    const int lk = (tid & 1) * 4;

    float acc[8][8];
#pragma unroll
    for (int i = 0; i < 8; ++i)
#pragma unroll
        for (int j = 0; j < 8; ++j) acc[i][j] = 0.f;

    for (int kt = 0; kt < K; kt += 8) {
        float4 av = *(const float4*)&A[(size_t)(m0 + lr) * K + kt + lk];
        float4 wv = *(const float4*)&W[(size_t)(n0 + lr) * K + kt + lk];
        __syncthreads();
        As[lk + 0][lr] = av.x; As[lk + 1][lr] = av.y;
        As[lk + 2][lr] = av.z; As[lk + 3][lr] = av.w;
        Bs[lk + 0][lr] = wv.x; Bs[lk + 1][lr] = wv.y;
        Bs[lk + 2][lr] = wv.z; Bs[lk + 3][lr] = wv.w;
        __syncthreads();
#pragma unroll
        for (int k = 0; k < 8; ++k) {
            float4 a0 = *(const float4*)&As[k][ty * 8];
            float4 a1 = *(const float4*)&As[k][ty * 8 + 4];
            float4 b0 = *(const float4*)&Bs[k][tx * 8];
            float4 b1 = *(const float4*)&Bs[k][tx * 8 + 4];
            float a[8] = {a0.x, a0.y, a0.z, a0.w, a1.x, a1.y, a1.z, a1.w};
            float b[8] = {b0.x, b0.y, b0.z, b0.w, b1.x, b1.y, b1.z, b1.w};
#pragma unroll
            for (int i = 0; i < 8; ++i)
#pragma unroll
                for (int j = 0; j < 8; ++j) acc[i][j] += a[i] * b[j];
        }
    }

    float bb[8];
#pragma unroll
    for (int j = 0; j < 8; ++j) bb[j] = bias[n0 + tx * 8 + j];

#pragma unroll
    for (int i = 0; i < 8; ++i) {
        int m = m0 + ty * 8 + i;
        int n = n0 + tx * 8;
        float cv[8];
#pragma unroll
        for (int j = 0; j < 8; ++j) cv[j] = acc[i][j] + bb[j];

        if (MODE == 0) {
            float* dst = &C[(size_t)m * N + n];
            *(float4*)&dst[0] = {cv[0], cv[1], cv[2], cv[3]};
            *(float4*)&dst[4] = {cv[4], cv[5], cv[6], cv[7]};
        } else {
            int bq = m >> 11;
            int s  = m & (SS - 1);
            int h  = n >> 6;
            int d  = n & 63;
            size_t base = (((size_t)(bq * NHEAD + h) * SS + s) << 6) + d;
            if (MODE == 1) {
                float* dst = &C[base];
                *(float4*)&dst[0] = {cv[0], cv[1], cv[2], cv[3]};
                *(float4*)&dst[4] = {cv[4], cv[5], cv[6], cv[7]};
            } else {
                u16x8 h8, l8;
#pragma unroll
                for (int j = 0; j < 8; ++j) {
                    unsigned short hv = f2bf(cv[j]);
                    h8[j] = hv;
                    l8[j] = f2bf(cv[j] - bf2f(hv));
                }
                *(u16x8*)&Chi[base] = h8;
                *(u16x8*)&Clo[base] = l8;
            }
        }
    }
}

__global__ __launch_bounds__(256) void attn_mfma(const float* __restrict__ Qp,
                                                 const unsigned short* __restrict__ Khig,
                                                 const unsigned short* __restrict__ Klog,
                                                 const unsigned short* __restrict__ Vhig,
                                                 const unsigned short* __restrict__ Vlog,
                                                 const int* __restrict__ mask,
                                                 float* __restrict__ ctx) {
    __shared__ short Khi[32 * 72], Klo[32 * 72];
    __shared__ short Vhi[64 * 40], Vlo[64 * 40];
    __shared__ float Pbuf[4][16 * 36];
    __shared__ int   msk[32];

    const int tid  = threadIdx.x;
    const int lane = tid & 63;
    const int wid  = tid >> 6;

    const int bid = blockIdx.x;
    const int swz = (bid & 7) * 256 + (bid >> 3);
    const int qt  = swz & 31;
    const int bh  = swz >> 5;
    const int b   = bh >> 4;
    const int h   = bh & 15;

    const int q0  = qt * 64;
    const int wq0 = wid * 16;

    const int fr = lane & 15;
    const int fg = lane >> 4;

    const float* qbase = Qp + ((size_t)bh * SS + q0 + wq0) * DK;
    const unsigned short* khbase = Khig + (size_t)bh * SS * DK;
    const unsigned short* klbase = Klog + (size_t)bh * SS * DK;
    const unsigned short* vhbase = Vhig + (size_t)bh * SS * DK;
    const unsigned short* vlbase = Vlog + (size_t)bh * SS * DK;
    const int* mrow = mask + b * SS;

    bf16x8 qh[2], ql[2];
#pragma unroll
    for (int kb = 0; kb < 2; ++kb) {
        const float* p = qbase + (size_t)fr * DK + kb * 32 + fg * 8;
        float4 a  = *(const float4*)p;
        float4 b4 = *(const float4*)(p + 4);
        float vals[8] = {a.x, a.y, a.z, a.w, b4.x, b4.y, b4.z, b4.w};
#pragma unroll
        for (int i = 0; i < 8; ++i) {
            float s = vals[i] * 0.125f;
            unsigned short hi = f2bf(s);
            qh[kb][i] = (short)hi;
            ql[kb][i] = (short)f2bf(s - bf2f(hi));
        }
    }

    f32x4 O[4] = {};
    float m_run[4], l_run[4];
#pragma unroll
    for (int r = 0; r < 4; ++r) { m_run[r] = -3.0e38f; l_run[r] = 0.f; }

    const int sk_k = tid >> 3;
    const int sk_d = (tid & 7) * 8;
    const int sv_d = tid & 63;
    const int sv_k = (tid >> 6) * 8;

    for (int t = 0; t < SS / 32; ++t) {
        const int kv0 = t * 32;

        size_t koff = (size_t)(kv0 + sk_k) * DK + sk_d;
        u16x8 kh8 = *(const u16x8*)&khbase[koff];
        u16x8 kl8 = *(const u16x8*)&klbase[koff];
        unsigned short vh[8], vl[8];
#pragma unroll
        for (int j = 0; j < 8; ++j) {
            size_t voff = (size_t)(kv0 + sv_k + j) * DK + sv_d;
            vh[j] = vhbase[voff];
            vl[j] = vlbase[voff];
        }
        int mval = (tid < 32) ? mrow[kv0 + tid] : 0;

        __syncthreads();
        *(u16x8*)&Khi[sk_k * 72 + sk_d] = kh8;
        *(u16x8*)&Klo[sk_k * 72 + sk_d] = kl8;
        {
            u16x8 h8, l8;
#pragma unroll
            for (int j = 0; j < 8; ++j) { h8[j] = vh[j]; l8[j] = vl[j]; }
            *(u16x8*)&Vhi[sv_d * 40 + sv_k] = h8;
            *(u16x8*)&Vlo[sv_d * 40 + sv_k] = l8;
        }
        if (tid < 32) msk[tid] = mval;
        __syncthreads();

        f32x4 acc[2] = {};
#pragma unroll
        for (int kyb = 0; kyb < 2; ++kyb) {
#pragma unroll
            for (int kb = 0; kb < 2; ++kb) {
                int idx = (kyb * 16 + fr) * 72 + kb * 32 + fg * 8;
                bf16x8 kh = *(const bf16x8*)&Khi[idx];
                bf16x8 kl = *(const bf16x8*)&Klo[idx];
                acc[kyb] = __builtin_amdgcn_mfma_f32_16x16x32_bf16(qh[kb], kh, acc[kyb], 0, 0, 0);
                acc[kyb] = __builtin_amdgcn_mfma_f32_16x16x32_bf16(qh[kb], kl, acc[kyb], 0, 0, 0);
                acc[kyb] = __builtin_amdgcn_mfma_f32_16x16x32_bf16(ql[kb], kh, acc[kyb], 0, 0, 0);
            }
        }

        float sc[2][4];
#pragma unroll
        for (int kyb = 0; kyb < 2; ++kyb) {
            int mv = msk[kyb * 16 + fr];
#pragma unroll
            for (int r = 0; r < 4; ++r)
                sc[kyb][r] = mv ? acc[kyb][r] : -1.0e9f;
        }
        float scale[4], p[2][4];
#pragma unroll
        for (int r = 0; r < 4; ++r) {
            float v = fmaxf(sc[0][r], sc[1][r]);
            v = fmaxf(v, __shfl_xor(v, 1));
            v = fmaxf(v, __shfl_xor(v, 2));
            v = fmaxf(v, __shfl_xor(v, 4));
            v = fmaxf(v, __shfl_xor(v, 8));
            float m_new = fmaxf(m_run[r], v);
            scale[r] = __expf(m_run[r] - m_new);
            m_run[r] = m_new;
            p[0][r] = __expf(sc[0][r] - m_new);
            p[1][r] = __expf(sc[1][r] - m_new);
            float s = p[0][r] + p[1][r];
            s += __shfl_xor(s, 1);
            s += __shfl_xor(s, 2);
            s += __shfl_xor(s, 4);
            s += __shfl_xor(s, 8);
            l_run[r] = l_run[r] * scale[r] + s;
        }

        float* pw = Pbuf[wid];
#pragma unroll
        for (int r = 0; r < 4; ++r) {
            pw[(fg * 4 + r) * 36 + fr]      = p[0][r];
            pw[(fg * 4 + r) * 36 + 16 + fr] = p[1][r];
        }
#pragma unroll
        for (int db = 0; db < 4; ++db)
#pragma unroll
            for (int r = 0; r < 4; ++r)
                O[db][r] *= scale[r];

        __syncthreads();

        float pr[8];
        {
            const float* prd = &pw[fr * 36 + fg * 8];
            *(float4*)&pr[0] = *(const float4*)&prd[0];
            *(float4*)&pr[4] = *(const float4*)&prd[4];
        }
        bf16x8 ph8, pl8;
#pragma unroll
        for (int i = 0; i < 8; ++i) {
            unsigned short hi = f2bf(pr[i]);
            ph8[i] = (short)hi;
            pl8[i] = (short)f2bf(pr[i] - bf2f(hi));
        }

#pragma unroll
        for (int db = 0; db < 4; ++db) {
            int idx = (db * 16 + fr) * 40 + fg * 8;
            bf16x8 vh8 = *(const bf16x8*)&Vhi[idx];
            bf16x8 vl8 = *(const bf16x8*)&Vlo[idx];
            O[db] = __builtin_amdgcn_mfma_f32_16x16x32_bf16(ph8, vh8, O[db], 0, 0, 0);
            O[db] = __builtin_amdgcn_mfma_f32_16x16x32_bf16(ph8, vl8, O[db], 0, 0, 0);
            O[db] = __builtin_amdgcn_mfma_f32_16x16x32_bf16(pl8, vh8, O[db], 0, 0, 0);
        }
    }

    float* cbase = ctx + ((size_t)b * SS + q0 + wq0) * D_MODEL + h * DK;
#pragma unroll
    for (int r = 0; r < 4; ++r) {
        float inv = 1.0f / l_run[r];
        int q = fg * 4 + r;
#pragma unroll
        for (int db = 0; db < 4; ++db)
            cbase[(size_t)q * D_MODEL + db * 16 + fr] = O[db][r] * inv;
    }
}

// ---------------------------------------------------------------------------
extern "C" void kernel_launch(void* const* d_in, const int* in_sizes, int n_in,
                              void* d_out, int out_size, void* d_ws, size_t ws_size,
                              hipStream_t stream) {
    const float* q    = (const float*)d_in[0];
    const float* k    = (const float*)d_in[1];
    const float* v    = (const float*)d_in[2];
    const int*   mask = (const int*)d_in[3];
    const float* w_q  = (const float*)d_in[4];
    const float* b_q  = (const float*)d_in[5];
    const float* w_k  = (const float*)d_in[6];
    const float* b_k  = (const float*)d_in[7];
    const float* w_v  = (const float*)d_in[8];
    const float* b_v  = (const float*)d_in[9];
    const float* w_o  = (const float*)d_in[10];
    const float* b_o  = (const float*)d_in[11];
    float* out = (float*)d_out;

    const int M = BB * SS;
    const size_t PSZ = (size_t)M * D_MODEL;
    const size_t NEED = (size_t)208 << 20;
    char* w = (char*)d_ws;
    dim3 block(256);

    if (ws_size >= NEED) {
        float* qp            = (float*)(w);
        unsigned short* khi  = (unsigned short*)(w + ((size_t)32 << 20));
        unsigned short* klo  = (unsigned short*)(w + ((size_t)48 << 20));
        unsigned short* vhi  = (unsigned short*)(w + ((size_t)64 << 20));
        unsigned short* vlo  = (unsigned short*)(w + ((size_t)80 << 20));
        unsigned short* Aq_h = (unsigned short*)(w + ((size_t)96 << 20));
        unsigned short* Aq_l = (unsigned short*)(w + ((size_t)112 << 20));
        unsigned short* Ak_h = (unsigned short*)(w + ((size_t)128 << 20));
        unsigned short* Ak_l = (unsigned short*)(w + ((size_t)144 << 20));
        unsigned short* Av_h = (unsigned short*)(w + ((size_t)160 << 20));
        unsigned short* Av_l = (unsigned short*)(w + ((size_t)176 << 20));
        unsigned short* vthi = (unsigned short*)(w + ((size_t)160 << 20)); // alias Av_h
        unsigned short* vtlo = (unsigned short*)(w + ((size_t)176 << 20)); // alias Av_l
        unsigned short* Wq_h = (unsigned short*)(w + ((size_t)192 << 20));
        unsigned short* Wq_l = (unsigned short*)(w + ((size_t)194 << 20));
        unsigned short* Wk_h = (unsigned short*)(w + ((size_t)196 << 20));
        unsigned short* Wk_l = (unsigned short*)(w + ((size_t)198 << 20));
        unsigned short* Wv_h = (unsigned short*)(w + ((size_t)200 << 20));
        unsigned short* Wv_l = (unsigned short*)(w + ((size_t)202 << 20));
        unsigned short* Wo_h = (unsigned short*)(w + ((size_t)204 << 20));
        unsigned short* Wo_l = (unsigned short*)(w + ((size_t)206 << 20));
        unsigned short* Ac_h = Ak_h;
        unsigned short* Ac_l = Ak_l;

        const int ACT_CHUNKS = M * 128;
        const int W_CHUNKS   = 1024 * 128;

        SplitJobs8 J{};
        J.j[0] = {q,   Aq_h, Aq_l, ACT_CHUNKS};
        J.j[1] = {k,   Ak_h, Ak_l, ACT_CHUNKS};
        J.j[2] = {v,   Av_h, Av_l, ACT_CHUNKS};
        J.j[3] = {w_q, Wq_h, Wq_l, W_CHUNKS};
        J.j[4] = {w_k, Wk_h, Wk_l, W_CHUNKS};
        J.j[5] = {w_v, Wv_h, Wv_l, W_CHUNKS};
        J.j[6] = {w_o, Wo_h, Wo_l, W_CHUNKS};
        presplit<<<dim3(4096, 7), block, 0, stream>>>(J);

        dim3 ggrid(D_MODEL / 128, M / 128);
        gemm_mfma<1><<<ggrid, block, 0, stream>>>(Aq_h, Aq_l, Wq_h, Wq_l, b_q, qp, nullptr, nullptr);
        gemm_mfma<2><<<ggrid, block, 0, stream>>>(Ak_h, Ak_l, Wk_h, Wk_l, b_k, nullptr, khi, klo);
        gemm_mfma<2><<<ggrid, block, 0, stream>>>(Av_h, Av_l, Wv_h, Wv_l, b_v, nullptr, vhi, vlo);

        vtrans<<<dim3(SS / 64, BB * NHEAD), block, 0, stream>>>(vhi, vlo, vthi, vtlo);

        attn_mfma5<<<dim3(BB * NHEAD * (SS / 128)), dim3(512), 0, stream>>>(
            qp, khi, klo, vthi, vtlo, mask, Ac_h, Ac_l);

        gemm_mfma<0><<<ggrid, block, 0, stream>>>(Ac_h, Ac_l, Wo_h, Wo_l, b_o, out, nullptr, nullptr);
    } else {
        float* qp           = (float*)d_ws;
        unsigned short* khi = (unsigned short*)(qp + PSZ);
        unsigned short* klo = khi + PSZ;
        unsigned short* vhi = klo + PSZ;
        unsigned short* vlo = vhi + PSZ;
        float* ctx          = (float*)(vlo + PSZ);

        dim3 grid(D_MODEL / 128, M / 128);
        gemm_xwT<1><<<grid, block, 0, stream>>>(q, w_q, b_q, qp, nullptr, nullptr, M, D_MODEL, D_MODEL);
        gemm_xwT<2><<<grid, block, 0, stream>>>(k, w_k, b_k, nullptr, khi, klo, M, D_MODEL, D_MODEL);
        gemm_xwT<2><<<grid, block, 0, stream>>>(v, w_v, b_v, nullptr, vhi, vlo, M, D_MODEL, D_MODEL);
        attn_mfma<<<dim3(BB * NHEAD * (SS / 64)), block, 0, stream>>>(qp, khi, klo, vhi, vlo, mask, ctx);
        gemm_xwT<0><<<grid, block, 0, stream>>>(ctx, w_o, b_o, out, nullptr, nullptr, M, D_MODEL, D_MODEL);
    }
}